// Round 1
// baseline (1123.905 us; speedup 1.0000x reference)
//
#include <hip/hip_runtime.h>
#include <hip/hip_bf16.h>
#include <stdint.h>

#define B_    4
#define N_    256
#define C_    256
#define FH_   100
#define FW_   152
#define P_HW  (FH_*FW_)      // 15200
#define NCLS  91
#define CAND  23040          // N_*90
#define R_    1024
#define DIN   12544
#define PRE   1024

typedef unsigned long long u64;
typedef unsigned int u32;

// ---------------- feature transpose (B,C,H,W) -> (B,H,W,C) ----------------
__global__ void k_transpose(const float* __restrict__ in, float* __restrict__ out) {
  __shared__ float t[32][33];
  int b  = blockIdx.z;
  int c0 = blockIdx.y * 32;
  int p0 = blockIdx.x * 32;
  int tx = threadIdx.x & 31, ty = threadIdx.x >> 5;  // ty 0..7
  const float* inb = in  + (size_t)b * C_ * P_HW;
  float*       ob  = out + (size_t)b * P_HW * C_;
  #pragma unroll
  for (int q = 0; q < 4; q++)
    t[ty + q*8][tx] = inb[(size_t)(c0 + ty + q*8) * P_HW + p0 + tx];
  __syncthreads();
  #pragma unroll
  for (int q = 0; q < 4; q++)
    ob[(size_t)(p0 + ty + q*8) * C_ + c0 + tx] = t[tx][ty + q*8];
}

// ---------------- roi align -> X (1024 x 12544), X[r][c*49+cell] ----------
__global__ void k_roialign(const float* __restrict__ featT,
                           const float* __restrict__ props,
                           float* __restrict__ X) {
  int r = blockIdx.x;
  int c = threadIdx.x;             // 256 channels
  int b = r >> 8;
  float x1 = props[r*4+0], y1 = props[r*4+1];
  float x2 = props[r*4+2], y2 = props[r*4+3];
  float x1s = x1 * 0.125f, y1s = y1 * 0.125f;
  float x2s = x2 * 0.125f, y2s = y2 * 0.125f;
  float rw = fmaxf(x2s - x1s, 1.0f);
  float rh = fmaxf(y2s - y1s, 1.0f);
  float rwd = rw / 7.0f, rhd = rh / 7.0f;
  const float* fb = featT + (size_t)b * P_HW * C_ + c;
  float* xr = X + (size_t)r * DIN + c * 49;
  for (int py = 0; py < 7; py++) {
    for (int px = 0; px < 7; px++) {
      float acc = 0.f;
      #pragma unroll
      for (int s = 0; s < 4; s++) {
        int sy = s >> 1, sx = s & 1;
        float gqy = (float)py + 0.25f + 0.5f * (float)sy;
        float gqx = (float)px + 0.25f + 0.5f * (float)sx;
        float gy = fminf(fmaxf(y1s + rhd * gqy, 0.0f), 99.0f);
        float gx = fminf(fmaxf(x1s + rwd * gqx, 0.0f), 151.0f);
        float y0f = floorf(gy), x0f = floorf(gx);
        float ly = gy - y0f, lx = gx - x0f;
        int y0i = (int)y0f;
        int y1i = (int)fminf(y0f + 1.0f, 99.0f);
        int x0i = (int)x0f;
        int x1i = (int)fminf(x0f + 1.0f, 151.0f);
        float v00 = fb[((size_t)(y0i * FW_ + x0i)) * C_];
        float v01 = fb[((size_t)(y0i * FW_ + x1i)) * C_];
        float v10 = fb[((size_t)(y1i * FW_ + x0i)) * C_];
        float v11 = fb[((size_t)(y1i * FW_ + x1i)) * C_];
        acc += (1.f-ly)*(1.f-lx)*v00 + (1.f-ly)*lx*v01
             + ly*(1.f-lx)*v10 + ly*lx*v11;
      }
      xr[py*7+px] = acc * 0.25f;
    }
  }
}

// -------- big fp32 GEMM: 128x128 tile, 8x8/thread, split-K partials -------
__global__ __launch_bounds__(256) void k_gemm128(
    const float* __restrict__ A, int lda,
    const float* __restrict__ Bm, int ldb,
    float* __restrict__ part, int Kslice) {
  __shared__ float As[16][132];
  __shared__ float Bs[16][128];
  int tid = threadIdx.x;
  int tx = tid & 15, ty = tid >> 4;
  int row0 = blockIdx.y * 128, col0 = blockIdx.x * 128;
  int kbase = blockIdx.z * Kslice;
  float acc[8][8] = {};
  float ar[8], br[8];
  #pragma unroll
  for (int q = 0; q < 8; q++) {
    int e = tid + q*256;
    ar[q] = A [(size_t)(row0 + (e>>4)) * lda + kbase + (e&15)];
    br[q] = Bm[(size_t)(kbase + (e>>7)) * ldb + col0 + (e&127)];
  }
  for (int k0 = 0; k0 < Kslice; k0 += 16) {
    #pragma unroll
    for (int q = 0; q < 8; q++) {
      int e = tid + q*256;
      As[e&15][e>>4]  = ar[q];
      Bs[e>>7][e&127] = br[q];
    }
    __syncthreads();
    if (k0 + 16 < Kslice) {
      int kn = kbase + k0 + 16;
      #pragma unroll
      for (int q = 0; q < 8; q++) {
        int e = tid + q*256;
        ar[q] = A [(size_t)(row0 + (e>>4)) * lda + kn + (e&15)];
        br[q] = Bm[(size_t)(kn + (e>>7)) * ldb + col0 + (e&127)];
      }
    }
    #pragma unroll
    for (int kk = 0; kk < 16; kk++) {
      float4 a0 = *(const float4*)&As[kk][ty*8];
      float4 a1 = *(const float4*)&As[kk][ty*8+4];
      float4 b0 = *(const float4*)&Bs[kk][tx*8];
      float4 b1 = *(const float4*)&Bs[kk][tx*8+4];
      float av[8] = {a0.x,a0.y,a0.z,a0.w,a1.x,a1.y,a1.z,a1.w};
      float bv[8] = {b0.x,b0.y,b0.z,b0.w,b1.x,b1.y,b1.z,b1.w};
      #pragma unroll
      for (int i = 0; i < 8; i++)
        #pragma unroll
        for (int j = 0; j < 8; j++)
          acc[i][j] = fmaf(av[i], bv[j], acc[i][j]);
    }
    __syncthreads();
  }
  float* pp = part + (size_t)blockIdx.z * 1024 * 1024;
  #pragma unroll
  for (int i = 0; i < 8; i++) {
    int row = row0 + ty*8 + i;
    #pragma unroll
    for (int j = 0; j < 8; j++)
      pp[(size_t)row*1024 + col0 + tx*8 + j] = acc[i][j];
  }
}

__global__ void k_reduce4(const float* __restrict__ part,
                          const float* __restrict__ bias,
                          float* __restrict__ Cm, int relu) {
  int idx = blockIdx.x * 256 + threadIdx.x;   // 1024*1024 elems
  int col = idx & 1023;
  float v = part[idx] + part[idx + 1048576] + part[idx + 2097152]
          + part[idx + 3145728] + bias[col];
  if (relu) v = fmaxf(v, 0.f);
  Cm[idx] = v;
}

// -------- small GEMM (heads): 64x64 tile, 4x4/thread, bias, N-guard -------
__global__ __launch_bounds__(256) void k_gemm64(
    const float* __restrict__ A, int lda,
    const float* __restrict__ Bm, int ldb,
    const float* __restrict__ bias,
    float* __restrict__ Cm, int ldc, int N, int K) {
  __shared__ float As[16][65];
  __shared__ float Bs[16][64];
  int tid = threadIdx.x;
  int tx = tid & 15, ty = tid >> 4;
  int row0 = blockIdx.y * 64, col0 = blockIdx.x * 64;
  float acc[4][4] = {};
  for (int k0 = 0; k0 < K; k0 += 16) {
    #pragma unroll
    for (int q = 0; q < 4; q++) {
      int e = tid + q*256;
      As[e&15][e>>4] = A[(size_t)(row0 + (e>>4)) * lda + k0 + (e&15)];
    }
    #pragma unroll
    for (int q = 0; q < 4; q++) {
      int e = tid + q*256;
      int col = col0 + (e&63);
      Bs[e>>6][e&63] = (col < N) ? Bm[(size_t)(k0 + (e>>6)) * ldb + col] : 0.f;
    }
    __syncthreads();
    #pragma unroll
    for (int kk = 0; kk < 16; kk++) {
      float a_[4], b_[4];
      #pragma unroll
      for (int i = 0; i < 4; i++) a_[i] = As[kk][ty*4+i];
      #pragma unroll
      for (int j = 0; j < 4; j++) b_[j] = Bs[kk][tx*4+j];
      #pragma unroll
      for (int i = 0; i < 4; i++)
        #pragma unroll
        for (int j = 0; j < 4; j++)
          acc[i][j] = fmaf(a_[i], b_[j], acc[i][j]);
    }
    __syncthreads();
  }
  #pragma unroll
  for (int i = 0; i < 4; i++) {
    int row = row0 + ty*4 + i;
    #pragma unroll
    for (int j = 0; j < 4; j++) {
      int col = col0 + tx*4 + j;
      if (col < N)
        Cm[(size_t)row*ldc + col] = acc[i][j] + bias[col];
    }
  }
}

// -------- softmax + box decode + candidate keys ----------------------------
__global__ void k_decode(const float* __restrict__ logits,
                         const float* __restrict__ deltas,
                         const float* __restrict__ props,
                         float* __restrict__ cboxes,
                         u64* __restrict__ keys) {
  int r = blockIdx.x;
  int j = threadIdx.x;   // 128
  __shared__ float red[128];
  float lg = (j < NCLS) ? logits[r*NCLS + j] : -3.4e38f;
  red[j] = lg;
  __syncthreads();
  for (int s = 64; s > 0; s >>= 1) {
    if (j < s) red[j] = fmaxf(red[j], red[j+s]);
    __syncthreads();
  }
  float mx = red[0];
  __syncthreads();
  float e = (j < NCLS) ? expf(lg - mx) : 0.f;
  red[j] = e;
  __syncthreads();
  for (int s = 64; s > 0; s >>= 1) {
    if (j < s) red[j] += red[j+s];
    __syncthreads();
  }
  float p = e / red[0];
  if (j >= 1 && j < NCLS) {
    float px1 = props[r*4+0], py1 = props[r*4+1];
    float px2 = props[r*4+2], py2 = props[r*4+3];
    float w = px2 - px1, h = py2 - py1;
    float cx = px1 + 0.5f*w, cy = py1 + 0.5f*h;
    float d0 = deltas[r*364 + j*4 + 0];
    float d1 = deltas[r*364 + j*4 + 1];
    float d2 = deltas[r*364 + j*4 + 2];
    float d3 = deltas[r*364 + j*4 + 3];
    float dx = d0 / 10.0f, dy = d1 / 10.0f;
    float dw = fminf(d2 / 5.0f, 4.135166556742356f);
    float dh = fminf(d3 / 5.0f, 4.135166556742356f);
    float pcx = dx*w + cx, pcy = dy*h + cy;
    float pw = expf(dw)*w, ph = expf(dh)*h;
    float bx1 = fminf(fmaxf(pcx - 0.5f*pw, 0.f), 1216.f);
    float by1 = fminf(fmaxf(pcy - 0.5f*ph, 0.f),  800.f);
    float bx2 = fminf(fmaxf(pcx + 0.5f*pw, 0.f), 1216.f);
    float by2 = fminf(fmaxf(pcy + 0.5f*ph, 0.f),  800.f);
    bool valid = (p > 0.05f) && ((bx2 - bx1) >= 0.01f) && ((by2 - by1) >= 0.01f);
    int b = r >> 8, n = r & 255;
    int cidx = n*90 + (j-1);
    size_t cb = (size_t)b*CAND + cidx;
    cboxes[cb*4+0] = bx1; cboxes[cb*4+1] = by1;
    cboxes[cb*4+2] = bx2; cboxes[cb*4+3] = by2;
    u64 key = 0ull;
    if (valid)
      key = (((u64)__float_as_uint(p)) << 32) | (u32)(~(u32)cidx);
    keys[cb] = key;
  }
}

// -------- per (batch,half): compact valid + bitonic sort desc, emit top1024
#define SORTN 4096
__global__ __launch_bounds__(1024) void k_sort(const u64* __restrict__ keys,
                                               u64* __restrict__ sorted) {
  __shared__ u64 sk[SORTN];
  __shared__ int cnt;
  int t = threadIdx.x;
  int b = blockIdx.x >> 1, h = blockIdx.x & 1;
  if (t == 0) cnt = 0;
  __syncthreads();
  const u64* kb = keys + (size_t)b*CAND + (size_t)h*(CAND/2);
  for (int q = 0; q < 12; q++) {
    int idx = t + q*1024;
    if (idx < CAND/2) {
      u64 k = kb[idx];
      if (k) { int pos = atomicAdd(&cnt, 1); sk[pos] = k; }
    }
  }
  __syncthreads();
  int total = cnt;
  for (int s = t; s < SORTN; s += 1024)
    if (s >= total) sk[s] = 0ull;
  __syncthreads();
  for (int k = 2; k <= SORTN; k <<= 1) {
    for (int jj = k >> 1; jj > 0; jj >>= 1) {
      for (int i = t; i < SORTN; i += 1024) {
        int ixj = i ^ jj;
        if (ixj > i) {
          u64 a = sk[i], bb = sk[ixj];
          bool up = ((i & k) == 0);
          if (up ? (a < bb) : (a > bb)) { sk[i] = bb; sk[ixj] = a; }
        }
      }
      __syncthreads();
    }
  }
  sorted[((size_t)b*2 + h)*1024 + t] = sk[t];
}

// -------- per batch: merge halves, greedy NMS, emit final 100 --------------
__global__ __launch_bounds__(1024) void k_nms(const u64* __restrict__ sorted,
                                              const float* __restrict__ cboxes,
                                              float* __restrict__ out) {
  __shared__ u64 m[2048];
  __shared__ float X1[1024], Y1a[1024], X2[1024], Y2a[1024], AR[1024];
  __shared__ int keepL[1024];
  __shared__ int wsum[16];
  int t = threadIdx.x;
  int b = blockIdx.x;
  m[t]        = sorted[((size_t)b*2 + 0)*1024 + t];
  m[2047 - t] = sorted[((size_t)b*2 + 1)*1024 + t];   // reversed -> ascending
  __syncthreads();
  for (int lg = 10; lg >= 0; lg--) {                  // bitonic merge, desc
    int jj = 1 << lg;
    int pos = ((t >> lg) << (lg+1)) + (t & (jj-1));
    u64 a = m[pos], bb = m[pos + jj];
    if (a < bb) { m[pos] = bb; m[pos + jj] = a; }
    __syncthreads();
  }
  u64 key = m[t];
  bool valid = key != 0ull;
  float score = __uint_as_float((u32)(key >> 32));
  u32 cidx = ~((u32)(key & 0xFFFFFFFFu));
  int label = valid ? (int)(cidx % 90u) + 1 : 0;
  float cb0 = 0.f, cb1 = 0.f, cb2 = 0.f, cb3 = 0.f;
  if (valid) {
    size_t cb = ((size_t)b*CAND + cidx) * 4;
    cb0 = cboxes[cb+0]; cb1 = cboxes[cb+1];
    cb2 = cboxes[cb+2]; cb3 = cboxes[cb+3];
  }
  float off = (float)label * 1218.0f;                 // max(800,1216)+2
  float ox1 = cb0 + off, oy1 = cb1 + off;
  float ox2 = cb2 + off, oy2 = cb3 + off;
  float area = (ox2 - ox1) * (oy2 - oy1);
  X1[t] = ox1; Y1a[t] = oy1; X2[t] = ox2; Y2a[t] = oy2; AR[t] = area;
  bool keep = valid;
  keepL[t] = keep ? 1 : 0;
  __syncthreads();
  for (int i = 0; i < PRE - 1; i++) {
    if (keepL[i] && keep && t > i) {
      float ltx = fmaxf(X1[i], ox1), lty = fmaxf(Y1a[i], oy1);
      float rbx = fminf(X2[i], ox2), rby = fminf(Y2a[i], oy2);
      float wv = fmaxf(rbx - ltx, 0.f), hv = fmaxf(rby - lty, 0.f);
      float inter = wv * hv;
      float iou = inter / (AR[i] + area - inter + 1e-9f);
      if (iou > 0.5f) { keep = false; keepL[t] = 0; }
    }
    __syncthreads();
  }
  u64 bal = __ballot(keep);
  int lane = t & 63, wv_ = t >> 6;
  int wpre = __popcll(bal & ((1ull << lane) - 1ull));
  if (lane == 0) wsum[wv_] = __popcll(bal);
  __syncthreads();
  int offn = 0, KT = 0;
  for (int q = 0; q < 16; q++) {
    int v = wsum[q];
    if (q < wv_) offn += v;
    KT += v;
  }
  int rank = offn + wpre;
  float* outB = out;
  float* outS = out + 1600;
  float* outL = out + 2000;
  if (keep && rank < 100) {
    size_t s = (size_t)b*100 + rank;
    outB[s*4+0] = cb0; outB[s*4+1] = cb1;
    outB[s*4+2] = cb2; outB[s*4+3] = cb3;
    outS[s] = score; outL[s] = (float)label;
  }
  if (t < 100 && t >= KT) {
    size_t s = (size_t)b*100 + t;
    outB[s*4+0] = 0.f; outB[s*4+1] = 0.f; outB[s*4+2] = 0.f; outB[s*4+3] = 0.f;
    outS[s] = 0.f; outL[s] = 0.f;
  }
}

extern "C" void kernel_launch(void* const* d_in, const int* in_sizes, int n_in,
                              void* d_out, int out_size, void* d_ws, size_t ws_size,
                              hipStream_t stream) {
  (void)in_sizes; (void)n_in; (void)out_size; (void)ws_size;
  const float* feat  = (const float*)d_in[0];
  const float* props = (const float*)d_in[1];
  const float* W6 = (const float*)d_in[2];
  const float* b6 = (const float*)d_in[3];
  const float* W7 = (const float*)d_in[4];
  const float* b7 = (const float*)d_in[5];
  const float* Wc = (const float*)d_in[6];
  const float* bc = (const float*)d_in[7];
  const float* Wb = (const float*)d_in[8];
  const float* bb = (const float*)d_in[9];
  float* out = (float*)d_out;
  char* ws = (char*)d_ws;

  // workspace layout (bytes). featT region is reused after roi_align.
  float* featT   = (float*)(ws);                       // 62,259,200 B
  float* X       = (float*)(ws + 62259200);            // 51,380,224 B
  float* Y1      = (float*)(ws + 0);                   //  4 MiB (featT dead)
  float* Y2      = (float*)(ws + (4u<<20));            //  4 MiB
  float* logitsP = (float*)(ws + (8u<<20));            //  ~0.36 MiB
  float* deltasP = (float*)(ws + (12u<<20));           //  ~1.42 MiB
  float* cboxes  = (float*)(ws + (16u<<20));           //  ~1.41 MiB
  float* part    = (float*)(ws + (28u<<20));           //  16 MiB split-K
  u64*   keys    = (u64*)  (ws + (45u<<20));           //  ~1.41 MiB
  u64*   sorted  = (u64*)  (ws + (47u<<20));           //  64 KiB

  dim3 g0(475, 8, 4);
  k_transpose<<<g0, 256, 0, stream>>>(feat, featT);
  k_roialign<<<1024, 256, 0, stream>>>(featT, props, X);

  // FC6: (1024 x 12544) @ (12544 x 1024), split-K=4
  dim3 g6(8, 8, 4);
  k_gemm128<<<g6, 256, 0, stream>>>(X, DIN, W6, 1024, part, DIN/4);
  k_reduce4<<<4096, 256, 0, stream>>>(part, b6, Y1, 1);
  // FC7
  k_gemm128<<<g6, 256, 0, stream>>>(Y1, 1024, W7, 1024, part, 1024/4);
  k_reduce4<<<4096, 256, 0, stream>>>(part, b7, Y2, 1);
  // heads
  dim3 gc(2, 16), gb(6, 16);
  k_gemm64<<<gc, 256, 0, stream>>>(Y2, 1024, Wc,  91, bc, logitsP,  91,  91, 1024);
  k_gemm64<<<gb, 256, 0, stream>>>(Y2, 1024, Wb, 364, bb, deltasP, 364, 364, 1024);

  k_decode<<<1024, 128, 0, stream>>>(logitsP, deltasP, props, cboxes, keys);
  k_sort<<<8, 1024, 0, stream>>>(keys, sorted);
  k_nms<<<4, 1024, 0, stream>>>(sorted, cboxes, out);
}

// Round 2
// 610.090 us; speedup vs baseline: 1.8422x; 1.8422x over previous
//
#include <hip/hip_runtime.h>
#include <hip/hip_bf16.h>
#include <stdint.h>

#define B_    4
#define N_    256
#define C_    256
#define FH_   100
#define FW_   152
#define P_HW  (FH_*FW_)      // 15200
#define NCLS  91
#define CAND  23040          // N_*90
#define DIN   12544
#define PRE   1024

typedef unsigned long long u64;
typedef unsigned int u32;
typedef unsigned short u16;
typedef __attribute__((ext_vector_type(8))) short short8;
typedef __attribute__((ext_vector_type(8))) __bf16 bf16x8;
typedef __attribute__((ext_vector_type(4))) float f32x4;

union frag_u { short8 s; bf16x8 b; };

__device__ inline u16 f2bf(float f) {
  __hip_bfloat16 h = __float2bfloat16(f);
  return *reinterpret_cast<u16*>(&h);
}
__device__ inline float bf2f(u16 b) {
  u32 x = ((u32)b) << 16;
  return __uint_as_float(x);
}
__device__ inline void split3(float v, u16& h0, u16& h1, u16& h2) {
  h0 = f2bf(v);
  float r = v - bf2f(h0);
  h1 = f2bf(r);
  float r2 = r - bf2f(h1);
  h2 = f2bf(r2);
}

__device__ inline void gload_lds16(const void* g, void* l) {
  __builtin_amdgcn_global_load_lds(
      (const __attribute__((address_space(1))) void*)g,
      (__attribute__((address_space(3))) void*)l, 16, 0, 0);
}

// ---------------- feature transpose (2 batches) (C,H,W) -> (H,W,C) --------
__global__ void k_transpose(const float* __restrict__ in, float* __restrict__ out,
                            int bBase) {
  __shared__ float t[32][33];
  int b  = bBase + blockIdx.z;
  int c0 = blockIdx.y * 32;
  int p0 = blockIdx.x * 32;
  int tx = threadIdx.x & 31, ty = threadIdx.x >> 5;
  const float* inb = in  + (size_t)b * C_ * P_HW;
  float*       ob  = out + (size_t)blockIdx.z * P_HW * C_;
  #pragma unroll
  for (int q = 0; q < 4; q++)
    t[ty + q*8][tx] = inb[(size_t)(c0 + ty + q*8) * P_HW + p0 + tx];
  __syncthreads();
  #pragma unroll
  for (int q = 0; q < 4; q++)
    ob[(size_t)(p0 + ty + q*8) * C_ + c0 + tx] = t[tx][ty + q*8];
}

// ------- roi align -> X_split [3][1024][12544] bf16 planes (fused split) ---
__global__ __launch_bounds__(256) void k_roialign(const float* __restrict__ featT,
                                                  const float* __restrict__ props,
                                                  u16* __restrict__ Xs, int roiBase) {
  __shared__ float cellv[49*256];
  int r  = roiBase + blockIdx.x;     // global roi
  int lb = blockIdx.x >> 8;          // local batch 0/1
  int c  = threadIdx.x;
  float x1 = props[r*4+0], y1 = props[r*4+1];
  float x2 = props[r*4+2], y2 = props[r*4+3];
  float x1s = x1 * 0.125f, y1s = y1 * 0.125f;
  float x2s = x2 * 0.125f, y2s = y2 * 0.125f;
  float rw = fmaxf(x2s - x1s, 1.0f);
  float rh = fmaxf(y2s - y1s, 1.0f);
  float rwd = rw / 7.0f, rhd = rh / 7.0f;
  const float* fb = featT + (size_t)lb * P_HW * C_ + c;
  for (int py = 0; py < 7; py++) {
    for (int px = 0; px < 7; px++) {
      float acc = 0.f;
      #pragma unroll
      for (int s = 0; s < 4; s++) {
        int sy = s >> 1, sx = s & 1;
        float gqy = (float)py + 0.25f + 0.5f * (float)sy;
        float gqx = (float)px + 0.25f + 0.5f * (float)sx;
        float gy = fminf(fmaxf(y1s + rhd * gqy, 0.0f), 99.0f);
        float gx = fminf(fmaxf(x1s + rwd * gqx, 0.0f), 151.0f);
        float y0f = floorf(gy), x0f = floorf(gx);
        float ly = gy - y0f, lx = gx - x0f;
        int y0i = (int)y0f;
        int y1i = (int)fminf(y0f + 1.0f, 99.0f);
        int x0i = (int)x0f;
        int x1i = (int)fminf(x0f + 1.0f, 151.0f);
        float v00 = fb[((size_t)(y0i * FW_ + x0i)) * C_];
        float v01 = fb[((size_t)(y0i * FW_ + x1i)) * C_];
        float v10 = fb[((size_t)(y1i * FW_ + x0i)) * C_];
        float v11 = fb[((size_t)(y1i * FW_ + x1i)) * C_];
        acc += (1.f-ly)*(1.f-lx)*v00 + (1.f-ly)*lx*v01
             + ly*(1.f-lx)*v10 + ly*lx*v11;
      }
      cellv[(py*7+px)*256 + c] = acc * 0.25f;
    }
  }
  __syncthreads();
  // store phase: 1568 chunks of 8 elems, split into 3 bf16 planes, coalesced
  const size_t MK = (size_t)1024 * DIN;
  for (int it = 0; it < 7; it++) {
    int cid = threadIdx.x + it*256;
    if (cid < 1568) {
      int k0 = cid * 8;
      short8 v0, v1, v2;
      #pragma unroll
      for (int e = 0; e < 8; e++) {
        int k = k0 + e;
        int ch = k / 49;
        int cell = k - ch*49;
        float v = cellv[cell*256 + ch];
        u16 h0, h1, h2;
        split3(v, h0, h1, h2);
        v0[e] = (short)h0; v1[e] = (short)h1; v2[e] = (short)h2;
      }
      size_t base = (size_t)r * DIN + k0;
      *reinterpret_cast<short8*>(Xs + base)        = v0;
      *reinterpret_cast<short8*>(Xs + MK + base)   = v1;
      *reinterpret_cast<short8*>(Xs + 2*MK + base) = v2;
    }
  }
}

// -------- MFMA GEMM, fp32-via-3xbf16 (6 passes), 128x128 tile, split-K -----
// As: [3][1024][K] bf16 planes (row-major, k contiguous)
// Bw: [K][1024] fp32 row-major (split done in-kernel)
// part: [gridDim.z][1024][1024] fp32 partials
__global__ __launch_bounds__(256) void k_gemm_mfma(
    const u16* __restrict__ As, const float* __restrict__ Bw,
    float* __restrict__ part, int K, int nsteps) {
  __shared__ __align__(16) char ldsbuf[40960];   // A: 24KB (3 planes), B: 16KB fp32
  u16*   Alds = (u16*)ldsbuf;
  float* Blds = (float*)(ldsbuf + 24576);
  int tid = threadIdx.x;
  int wid = tid >> 6, lane = tid & 63;
  int l15 = lane & 15, lq = lane >> 4;
  int row0 = blockIdx.y * 128, col0 = blockIdx.x * 128;
  int wr = wid >> 1, wc = wid & 1;          // wave tile 64x64
  int kbase0 = blockIdx.z * nsteps * 32;

  f32x4 acc[4][4];
  #pragma unroll
  for (int i = 0; i < 4; i++)
    #pragma unroll
    for (int j = 0; j < 4; j++)
      #pragma unroll
      for (int q = 0; q < 4; q++) acc[i][j][q] = 0.f;

  for (int s = 0; s < nsteps; s++) {
    int kb = kbase0 + s * 32;
    __syncthreads();                         // LDS free
    // stage 2560 16B-chunks: A = [0,1536), B = [1536,2560)
    #pragma unroll
    for (int j = 0; j < 10; j++) {
      int cbase = (j*4 + wid) * 64;
      int cid = cbase + lane;
      const char* src;
      if (cbase < 1536) {
        int p = cid >> 9, kc = (cid >> 7) & 3, row = cid & 127;
        src = (const char*)(As + ((size_t)p*1024 + row0 + row)*K + kb + kc*8);
      } else {
        int bid = cid - 1536;
        int kk = bid >> 5, c4 = bid & 31;
        int col = (c4*4) ^ (((kk >> 3) & 1) << 4);
        src = (const char*)(Bw + (size_t)(kb + kk)*1024 + col0 + col);
      }
      gload_lds16(src, ldsbuf + cbase*16);
    }
    __syncthreads();                         // waits vmcnt(0)

    // A fragments: 3 planes x 4 row-frags
    frag_u af[3][4];
    #pragma unroll
    for (int p = 0; p < 3; p++)
      #pragma unroll
      for (int fr = 0; fr < 4; fr++) {
        int idx = (p*4 + lq)*128 + wr*64 + fr*16 + l15;
        af[p][fr].s = *reinterpret_cast<const short8*>(&Alds[idx*8]);
      }
    // B per col-frag: read fp32, split in-register, 6 MFMA passes
    int cxor = (lq & 1) << 4;
    #pragma unroll
    for (int fc = 0; fc < 4; fc++) {
      int colx = (wc*64 + fc*16 + l15) ^ cxor;
      frag_u b0, b1, b2;
      #pragma unroll
      for (int j = 0; j < 8; j++) {
        float w = Blds[(lq*8 + j)*128 + colx];
        u16 h0, h1, h2;
        split3(w, h0, h1, h2);
        b0.s[j] = (short)h0; b1.s[j] = (short)h1; b2.s[j] = (short)h2;
      }
      #pragma unroll
      for (int fr = 0; fr < 4; fr++) {
        acc[fr][fc] = __builtin_amdgcn_mfma_f32_16x16x32_bf16(af[0][fr].b, b0.b, acc[fr][fc], 0, 0, 0);
        acc[fr][fc] = __builtin_amdgcn_mfma_f32_16x16x32_bf16(af[1][fr].b, b0.b, acc[fr][fc], 0, 0, 0);
        acc[fr][fc] = __builtin_amdgcn_mfma_f32_16x16x32_bf16(af[2][fr].b, b0.b, acc[fr][fc], 0, 0, 0);
        acc[fr][fc] = __builtin_amdgcn_mfma_f32_16x16x32_bf16(af[0][fr].b, b1.b, acc[fr][fc], 0, 0, 0);
        acc[fr][fc] = __builtin_amdgcn_mfma_f32_16x16x32_bf16(af[1][fr].b, b1.b, acc[fr][fc], 0, 0, 0);
        acc[fr][fc] = __builtin_amdgcn_mfma_f32_16x16x32_bf16(af[0][fr].b, b2.b, acc[fr][fc], 0, 0, 0);
      }
    }
  }
  // epilogue: D row=(lane>>4)*4+r, col=lane&15
  float* pp = part + (size_t)blockIdx.z * 1024 * 1024;
  #pragma unroll
  for (int fr = 0; fr < 4; fr++)
    #pragma unroll
    for (int fc = 0; fc < 4; fc++) {
      int col = col0 + wc*64 + fc*16 + l15;
      #pragma unroll
      for (int rr = 0; rr < 4; rr++) {
        int row = row0 + wr*64 + fr*16 + lq*4 + rr;
        pp[(size_t)row*1024 + col] = acc[fr][fc][rr];
      }
    }
}

// -------- reduce split-K partials: FC6 -> Y1 bf16 splits, FC7 -> Y2 fp32 ---
__global__ void k_reduce_split(const float* __restrict__ part,
                               const float* __restrict__ bias,
                               u16* __restrict__ ys, int nsl) {
  int idx = blockIdx.x * 256 + threadIdx.x;   // 1M
  float v = bias[idx & 1023];
  for (int s = 0; s < nsl; s++) v += part[idx + (size_t)s*1048576];
  v = fmaxf(v, 0.f);
  u16 h0, h1, h2;
  split3(v, h0, h1, h2);
  ys[idx] = h0; ys[idx + 1048576] = h1; ys[idx + 2097152] = h2;
}

__global__ void k_reduce_f32(const float* __restrict__ part,
                             const float* __restrict__ bias,
                             float* __restrict__ y, int nsl) {
  int idx = blockIdx.x * 256 + threadIdx.x;
  float v = bias[idx & 1023];
  for (int s = 0; s < nsl; s++) v += part[idx + (size_t)s*1048576];
  y[idx] = fmaxf(v, 0.f);
}

// -------- small GEMM (heads): fp32, 64x64 tile ------------------------------
__global__ __launch_bounds__(256) void k_gemm64(
    const float* __restrict__ A, int lda,
    const float* __restrict__ Bm, int ldb,
    const float* __restrict__ bias,
    float* __restrict__ Cm, int ldc, int N, int K) {
  __shared__ float As[16][65];
  __shared__ float Bs[16][64];
  int tid = threadIdx.x;
  int tx = tid & 15, ty = tid >> 4;
  int row0 = blockIdx.y * 64, col0 = blockIdx.x * 64;
  float acc[4][4] = {};
  for (int k0 = 0; k0 < K; k0 += 16) {
    #pragma unroll
    for (int q = 0; q < 4; q++) {
      int e = tid + q*256;
      As[e&15][e>>4] = A[(size_t)(row0 + (e>>4)) * lda + k0 + (e&15)];
    }
    #pragma unroll
    for (int q = 0; q < 4; q++) {
      int e = tid + q*256;
      int col = col0 + (e&63);
      Bs[e>>6][e&63] = (col < N) ? Bm[(size_t)(k0 + (e>>6)) * ldb + col] : 0.f;
    }
    __syncthreads();
    #pragma unroll
    for (int kk = 0; kk < 16; kk++) {
      float a_[4], b_[4];
      #pragma unroll
      for (int i = 0; i < 4; i++) a_[i] = As[kk][ty*4+i];
      #pragma unroll
      for (int j = 0; j < 4; j++) b_[j] = Bs[kk][tx*4+j];
      #pragma unroll
      for (int i = 0; i < 4; i++)
        #pragma unroll
        for (int j = 0; j < 4; j++)
          acc[i][j] = fmaf(a_[i], b_[j], acc[i][j]);
    }
    __syncthreads();
  }
  #pragma unroll
  for (int i = 0; i < 4; i++) {
    int row = row0 + ty*4 + i;
    #pragma unroll
    for (int j = 0; j < 4; j++) {
      int col = col0 + tx*4 + j;
      if (col < N)
        Cm[(size_t)row*ldc + col] = acc[i][j] + bias[col];
    }
  }
}

// -------- softmax + box decode + candidate keys ----------------------------
__global__ void k_decode(const float* __restrict__ logits,
                         const float* __restrict__ deltas,
                         const float* __restrict__ props,
                         float* __restrict__ cboxes,
                         u64* __restrict__ keys) {
  int r = blockIdx.x;
  int j = threadIdx.x;   // 128
  __shared__ float red[128];
  float lg = (j < NCLS) ? logits[r*NCLS + j] : -3.4e38f;
  red[j] = lg;
  __syncthreads();
  for (int s = 64; s > 0; s >>= 1) {
    if (j < s) red[j] = fmaxf(red[j], red[j+s]);
    __syncthreads();
  }
  float mx = red[0];
  __syncthreads();
  float e = (j < NCLS) ? expf(lg - mx) : 0.f;
  red[j] = e;
  __syncthreads();
  for (int s = 64; s > 0; s >>= 1) {
    if (j < s) red[j] += red[j+s];
    __syncthreads();
  }
  float p = e / red[0];
  if (j >= 1 && j < NCLS) {
    float px1 = props[r*4+0], py1 = props[r*4+1];
    float px2 = props[r*4+2], py2 = props[r*4+3];
    float w = px2 - px1, h = py2 - py1;
    float cx = px1 + 0.5f*w, cy = py1 + 0.5f*h;
    float d0 = deltas[r*364 + j*4 + 0];
    float d1 = deltas[r*364 + j*4 + 1];
    float d2 = deltas[r*364 + j*4 + 2];
    float d3 = deltas[r*364 + j*4 + 3];
    float dx = d0 / 10.0f, dy = d1 / 10.0f;
    float dw = fminf(d2 / 5.0f, 4.135166556742356f);
    float dh = fminf(d3 / 5.0f, 4.135166556742356f);
    float pcx = dx*w + cx, pcy = dy*h + cy;
    float pw = expf(dw)*w, ph = expf(dh)*h;
    float bx1 = fminf(fmaxf(pcx - 0.5f*pw, 0.f), 1216.f);
    float by1 = fminf(fmaxf(pcy - 0.5f*ph, 0.f),  800.f);
    float bx2 = fminf(fmaxf(pcx + 0.5f*pw, 0.f), 1216.f);
    float by2 = fminf(fmaxf(pcy + 0.5f*ph, 0.f),  800.f);
    bool valid = (p > 0.05f) && ((bx2 - bx1) >= 0.01f) && ((by2 - by1) >= 0.01f);
    int b = r >> 8, n = r & 255;
    int cidx = n*90 + (j-1);
    size_t cb = (size_t)b*CAND + cidx;
    cboxes[cb*4+0] = bx1; cboxes[cb*4+1] = by1;
    cboxes[cb*4+2] = bx2; cboxes[cb*4+3] = by2;
    u64 key = 0ull;
    if (valid)
      key = (((u64)__float_as_uint(p)) << 32) | (u32)(~(u32)cidx);
    keys[cb] = key;
  }
}

// -------- per (batch,half): compact valid + bitonic sort desc, top1024 -----
#define SORTN 4096
__global__ __launch_bounds__(1024) void k_sort(const u64* __restrict__ keys,
                                               u64* __restrict__ sorted) {
  __shared__ u64 sk[SORTN];
  __shared__ int cnt;
  int t = threadIdx.x;
  int b = blockIdx.x >> 1, h = blockIdx.x & 1;
  if (t == 0) cnt = 0;
  __syncthreads();
  const u64* kb = keys + (size_t)b*CAND + (size_t)h*(CAND/2);
  for (int q = 0; q < 12; q++) {
    int idx = t + q*1024;
    if (idx < CAND/2) {
      u64 k = kb[idx];
      if (k) { int pos = atomicAdd(&cnt, 1); sk[pos] = k; }
    }
  }
  __syncthreads();
  int total = cnt;
  for (int s = t; s < SORTN; s += 1024)
    if (s >= total) sk[s] = 0ull;
  __syncthreads();
  for (int k = 2; k <= SORTN; k <<= 1) {
    for (int jj = k >> 1; jj > 0; jj >>= 1) {
      for (int i = t; i < SORTN; i += 1024) {
        int ixj = i ^ jj;
        if (ixj > i) {
          u64 a = sk[i], bb = sk[ixj];
          bool up = ((i & k) == 0);
          if (up ? (a < bb) : (a > bb)) { sk[i] = bb; sk[ixj] = a; }
        }
      }
      __syncthreads();
    }
  }
  sorted[((size_t)b*2 + h)*1024 + t] = sk[t];
}

// -------- per batch: merge halves, tiled greedy NMS, emit final 100 --------
__global__ __launch_bounds__(1024) void k_nms(const u64* __restrict__ sorted,
                                              const float* __restrict__ cboxes,
                                              float* __restrict__ out) {
  __shared__ u64 m[2048];
  __shared__ float sX1[1024], sY1[1024], sX2[1024], sY2[1024], sAR[1024];
  __shared__ int keepL[1024];
  __shared__ int wsum[16];
  int t = threadIdx.x;
  int b = blockIdx.x;
  m[t]        = sorted[((size_t)b*2 + 0)*1024 + t];
  m[2047 - t] = sorted[((size_t)b*2 + 1)*1024 + t];
  __syncthreads();
  for (int lg = 10; lg >= 0; lg--) {                  // bitonic merge, desc
    int jj = 1 << lg;
    int pos = ((t >> lg) << (lg+1)) + (t & (jj-1));
    u64 a = m[pos], bb = m[pos + jj];
    if (a < bb) { m[pos] = bb; m[pos + jj] = a; }
    __syncthreads();
  }
  u64 key = m[t];
  bool valid = key != 0ull;
  float score = __uint_as_float((u32)(key >> 32));
  u32 cidx = ~((u32)(key & 0xFFFFFFFFu));
  int label = valid ? (int)(cidx % 90u) + 1 : 0;
  float cb0 = 0.f, cb1 = 0.f, cb2 = 0.f, cb3 = 0.f;
  if (valid) {
    size_t cb = ((size_t)b*CAND + cidx) * 4;
    cb0 = cboxes[cb+0]; cb1 = cboxes[cb+1];
    cb2 = cboxes[cb+2]; cb3 = cboxes[cb+3];
  }
  float off = (float)label * 1218.0f;
  float ox1 = cb0 + off, oy1 = cb1 + off;
  float ox2 = cb2 + off, oy2 = cb3 + off;
  float area = (ox2 - ox1) * (oy2 - oy1);
  sX1[t] = ox1; sY1[t] = oy1; sX2[t] = ox2; sY2[t] = oy2; sAR[t] = area;
  keepL[t] = valid ? 1 : 0;
  __syncthreads();

  int wid = t >> 6, lane = t & 63;
  for (int tile = 0; tile < 16; tile++) {
    // step A: wave 0 serializes this tile (exact greedy order)
    if (wid == 0) {
      int idx = tile*64 + lane;
      bool kp = keepL[idx] != 0;
      float bx1 = sX1[idx], by1 = sY1[idx], bx2 = sX2[idx], by2 = sY2[idx], ba = sAR[idx];
      u64 alive = __ballot(kp);
      #pragma unroll 1
      for (int i = 0; i < 63; i++) {
        if ((alive >> i) & 1ull) {
          int ii = tile*64 + i;
          float x1i = sX1[ii], y1i = sY1[ii], x2i = sX2[ii], y2i = sY2[ii], ai = sAR[ii];
          float ltx = fmaxf(x1i, bx1), lty = fmaxf(y1i, by1);
          float rbx = fminf(x2i, bx2), rby = fminf(y2i, by2);
          float iw = fmaxf(rbx - ltx, 0.f), ih = fmaxf(rby - lty, 0.f);
          float inter = iw * ih;
          float iou = inter / (ai + ba - inter + 1e-9f);
          if (lane > i && iou > 0.5f) kp = false;
        }
        alive = __ballot(kp);
      }
      keepL[idx] = kp ? 1 : 0;
    }
    __syncthreads();
    // step B: later boxes sweep against finalized alive boxes of this tile
    if (t >= (tile+1)*64) {
      bool kp = keepL[t] != 0;
      if (kp) {
        #pragma unroll 1
        for (int i = tile*64; i < tile*64 + 64; i++) {
          if (keepL[i]) {
            float ltx = fmaxf(sX1[i], ox1), lty = fmaxf(sY1[i], oy1);
            float rbx = fminf(sX2[i], ox2), rby = fminf(sY2[i], oy2);
            float iw = fmaxf(rbx - ltx, 0.f), ih = fmaxf(rby - lty, 0.f);
            float inter = iw * ih;
            float iou = inter / (sAR[i] + area - inter + 1e-9f);
            if (iou > 0.5f) { kp = false; }
          }
        }
        if (!kp) keepL[t] = 0;
      }
    }
    __syncthreads();
  }

  bool keep = keepL[t] != 0;
  u64 bal = __ballot(keep);
  int wpre = __popcll(bal & ((1ull << lane) - 1ull));
  if (lane == 0) wsum[wid] = __popcll(bal);
  __syncthreads();
  int offn = 0, KT = 0;
  for (int q = 0; q < 16; q++) {
    int v = wsum[q];
    if (q < wid) offn += v;
    KT += v;
  }
  int rank = offn + wpre;
  float* outB = out;
  float* outS = out + 1600;
  float* outL = out + 2000;
  if (keep && rank < 100) {
    size_t s = (size_t)b*100 + rank;
    outB[s*4+0] = cb0; outB[s*4+1] = cb1;
    outB[s*4+2] = cb2; outB[s*4+3] = cb3;
    outS[s] = score; outL[s] = (float)label;
  }
  if (t < 100 && t >= KT) {
    size_t s = (size_t)b*100 + t;
    outB[s*4+0] = 0.f; outB[s*4+1] = 0.f; outB[s*4+2] = 0.f; outB[s*4+3] = 0.f;
    outS[s] = 0.f; outL[s] = 0.f;
  }
}

extern "C" void kernel_launch(void* const* d_in, const int* in_sizes, int n_in,
                              void* d_out, int out_size, void* d_ws, size_t ws_size,
                              hipStream_t stream) {
  (void)in_sizes; (void)n_in; (void)out_size; (void)ws_size;
  const float* feat  = (const float*)d_in[0];
  const float* props = (const float*)d_in[1];
  const float* W6 = (const float*)d_in[2];
  const float* b6 = (const float*)d_in[3];
  const float* W7 = (const float*)d_in[4];
  const float* b7 = (const float*)d_in[5];
  const float* Wc = (const float*)d_in[6];
  const float* bc = (const float*)d_in[7];
  const float* Wb = (const float*)d_in[8];
  const float* bb = (const float*)d_in[9];
  float* out = (float*)d_out;
  char* ws = (char*)d_ws;

  // workspace layout (peak 108.2MB, proven budget 113.6MB):
  //   [0, 31.1MB): featT (2 batches)  -> later: part (split-K partials)
  //   [31.1MB, 108.2MB): X_split      -> later: Y1_split, Y2, logits, ...
  float* featT  = (float*)(ws);                        // 31,129,600 B
  float* part   = (float*)(ws);                        // 29,360,128 B (7 slices)
  u16*   Xs     = (u16*)  (ws + 31129600);             // 77,070,336 B
  u16*   Y1s    = (u16*)  (ws + 31129600);             //  6,291,456 B (X_split dead)
  float* Y2     = (float*)(ws + 37748736);             //  4 MiB
  float* logitsP= (float*)(ws + 41943040);
  float* deltasP= (float*)(ws + 42991616);
  float* cboxes = (float*)(ws + 44564480);
  u64*   keys   = (u64*)  (ws + 46137344);
  u64*   sorted = (u64*)  (ws + 47185920);

  dim3 gT(475, 8, 2);
  // batches 0,1
  k_transpose<<<gT, 256, 0, stream>>>(feat, featT, 0);
  k_roialign<<<512, 256, 0, stream>>>(featT, props, Xs, 0);
  // batches 2,3
  k_transpose<<<gT, 256, 0, stream>>>(feat, featT, 2);
  k_roialign<<<512, 256, 0, stream>>>(featT, props, Xs, 512);

  // FC6: (1024 x 12544) @ (12544 x 1024), split-K=7 (56 steps each)
  dim3 g6(8, 8, 7);
  k_gemm_mfma<<<g6, 256, 0, stream>>>(Xs, W6, part, DIN, 56);
  k_reduce_split<<<4096, 256, 0, stream>>>(part, b6, Y1s, 7);
  // FC7: split-K=4 (8 steps each)
  dim3 g7(8, 8, 4);
  k_gemm_mfma<<<g7, 256, 0, stream>>>(Y1s, W7, part, 1024, 8);
  k_reduce_f32<<<4096, 256, 0, stream>>>(part, b7, Y2, 4);

  // heads (fp32 vector)
  dim3 gc(2, 16), gb(6, 16);
  k_gemm64<<<gc, 256, 0, stream>>>(Y2, 1024, Wc,  91, bc, logitsP,  91,  91, 1024);
  k_gemm64<<<gb, 256, 0, stream>>>(Y2, 1024, Wb, 364, bb, deltasP, 364, 364, 1024);

  k_decode<<<1024, 128, 0, stream>>>(logitsP, deltasP, props, cboxes, keys);
  k_sort<<<8, 1024, 0, stream>>>(keys, sorted);
  k_nms<<<4, 1024, 0, stream>>>(sorted, cboxes, out);
}

// Round 3
// 607.067 us; speedup vs baseline: 1.8514x; 1.0050x over previous
//
#include <hip/hip_runtime.h>
#include <hip/hip_bf16.h>
#include <stdint.h>

#define B_    4
#define N_    256
#define C_    256
#define FH_   100
#define FW_   152
#define P_HW  (FH_*FW_)      // 15200
#define NCLS  91
#define CAND  23040          // N_*90
#define DIN   12544
#define PRE   1024

typedef unsigned long long u64;
typedef unsigned int u32;
typedef unsigned short u16;
typedef __attribute__((ext_vector_type(8))) _Float16 half8;
typedef __attribute__((ext_vector_type(8))) short short8;
typedef __attribute__((ext_vector_type(4))) float f32x4;

__device__ inline u16 h2bits(_Float16 h) { return *reinterpret_cast<u16*>(&h); }

// split v (already prescaled) into fp16 h0 + h1, exact-residual style
__device__ inline void split2(float v, u16& b0, u16& b1) {
  _Float16 h0 = (_Float16)v;
  float r = v - (float)h0;
  _Float16 h1 = (_Float16)r;
  b0 = h2bits(h0); b1 = h2bits(h1);
}

__device__ inline void gload_lds16(const void* g, void* l) {
  __builtin_amdgcn_global_load_lds(
      (const __attribute__((address_space(1))) void*)g,
      (__attribute__((address_space(3))) void*)l, 16, 0, 0);
}

// ---------------- feature transpose (B,C,H,W) -> (B,H,W,C) ----------------
__global__ void k_transpose(const float* __restrict__ in, float* __restrict__ out) {
  __shared__ float t[32][33];
  int b  = blockIdx.z;
  int c0 = blockIdx.y * 32;
  int p0 = blockIdx.x * 32;
  int tx = threadIdx.x & 31, ty = threadIdx.x >> 5;
  const float* inb = in  + (size_t)b * C_ * P_HW;
  float*       ob  = out + (size_t)b * P_HW * C_;
  #pragma unroll
  for (int q = 0; q < 4; q++)
    t[ty + q*8][tx] = inb[(size_t)(c0 + ty + q*8) * P_HW + p0 + tx];
  __syncthreads();
  #pragma unroll
  for (int q = 0; q < 4; q++)
    ob[(size_t)(p0 + ty + q*8) * C_ + c0 + tx] = t[tx][ty + q*8];
}

// ------- roi align -> Xs2 [2][1024][12544] fp16 planes of (X * 16) --------
__global__ __launch_bounds__(256) void k_roialign(const float* __restrict__ featT,
                                                  const float* __restrict__ props,
                                                  u16* __restrict__ Xs) {
  __shared__ float cellv[49*256];
  int r = blockIdx.x;
  int b = r >> 8;
  int c = threadIdx.x;
  float x1 = props[r*4+0], y1 = props[r*4+1];
  float x2 = props[r*4+2], y2 = props[r*4+3];
  float x1s = x1 * 0.125f, y1s = y1 * 0.125f;
  float x2s = x2 * 0.125f, y2s = y2 * 0.125f;
  float rw = fmaxf(x2s - x1s, 1.0f);
  float rh = fmaxf(y2s - y1s, 1.0f);
  float rwd = rw / 7.0f, rhd = rh / 7.0f;
  const float* fb = featT + (size_t)b * P_HW * C_ + c;
  for (int py = 0; py < 7; py++) {
    for (int px = 0; px < 7; px++) {
      float acc = 0.f;
      #pragma unroll
      for (int s = 0; s < 4; s++) {
        int sy = s >> 1, sx = s & 1;
        float gqy = (float)py + 0.25f + 0.5f * (float)sy;
        float gqx = (float)px + 0.25f + 0.5f * (float)sx;
        float gy = fminf(fmaxf(y1s + rhd * gqy, 0.0f), 99.0f);
        float gx = fminf(fmaxf(x1s + rwd * gqx, 0.0f), 151.0f);
        float y0f = floorf(gy), x0f = floorf(gx);
        float ly = gy - y0f, lx = gx - x0f;
        int y0i = (int)y0f;
        int y1i = (int)fminf(y0f + 1.0f, 99.0f);
        int x0i = (int)x0f;
        int x1i = (int)fminf(x0f + 1.0f, 151.0f);
        float v00 = fb[((size_t)(y0i * FW_ + x0i)) * C_];
        float v01 = fb[((size_t)(y0i * FW_ + x1i)) * C_];
        float v10 = fb[((size_t)(y1i * FW_ + x0i)) * C_];
        float v11 = fb[((size_t)(y1i * FW_ + x1i)) * C_];
        acc += (1.f-ly)*(1.f-lx)*v00 + (1.f-ly)*lx*v01
             + ly*(1.f-lx)*v10 + ly*lx*v11;
      }
      cellv[(py*7+px)*256 + c] = acc * 4.0f;   // 0.25 (avg) * 16 (prescale)
    }
  }
  __syncthreads();
  const size_t MK = (size_t)1024 * DIN;
  for (int it = 0; it < 7; it++) {
    int cid = threadIdx.x + it*256;
    if (cid < 1568) {
      int k0 = cid * 8;
      short8 v0, v1;
      #pragma unroll
      for (int e = 0; e < 8; e++) {
        int k = k0 + e;
        int ch = k / 49;
        int cell = k - ch*49;
        float v = cellv[cell*256 + ch];
        u16 h0, h1;
        split2(v, h0, h1);
        v0[e] = (short)h0; v1[e] = (short)h1;
      }
      size_t base = (size_t)r * DIN + k0;
      *reinterpret_cast<short8*>(Xs + base)      = v0;
      *reinterpret_cast<short8*>(Xs + MK + base) = v1;
    }
  }
}

// -------- MFMA GEMM, fp32 via fp16 2-plane exact 4-pass, 256x128 tile -----
// As: [2][1024][K] fp16 planes of (A*16). Bw: [K][1024] fp32 (scaled x128
// in-kernel). part: [8][1024][1024] fp32 partials of (A@B)*2048.
__global__ __launch_bounds__(512) void k_gemm_f16(
    const u16* __restrict__ As, const float* __restrict__ Bw,
    float* __restrict__ part, int K, int nsteps) {
  __shared__ __align__(16) char lds[49152];   // A 32KB (2 planes), B 16KB fp32
  u16*   Alds = (u16*)lds;
  float* Blds = (float*)(lds + 32768);
  int tid = threadIdx.x;
  int wid = tid >> 6, lane = tid & 63;
  int l15 = lane & 15, lq = lane >> 4;
  int bid = blockIdx.x;
  int z = bid & 7, xy = bid >> 3;              // z-slice per XCD (swizzle)
  int col0 = (xy & 7) * 128, row0 = (xy >> 3) * 256;
  int wr = wid >> 1, wc = wid & 1;             // 8 waves: 4 row x 2 col, 64x64
  int kbase0 = z * nsteps * 32;

  f32x4 acc[4][4];
  #pragma unroll
  for (int i = 0; i < 4; i++)
    #pragma unroll
    for (int j = 0; j < 4; j++)
      #pragma unroll
      for (int q = 0; q < 4; q++) acc[i][j][q] = 0.f;

  for (int s = 0; s < nsteps; s++) {
    int kb = kbase0 + s * 32;
    __syncthreads();
    // stage 3072 16B chunks: A = [0,2048), B = [2048,3072)
    #pragma unroll
    for (int j = 0; j < 6; j++) {
      int cid = (j*8 + wid)*64 + lane;
      const char* src;
      if (cid < 2048) {
        int pl = cid >> 10, rem = cid & 1023;
        int kc = rem >> 8, row = rem & 255;
        src = (const char*)(As + ((size_t)(pl*1024 + row0 + row))*K + kb + kc*8);
      } else {
        int bidc = cid - 2048;
        int kk = bidc >> 5, c4 = bidc & 31;
        int col = (c4*4) ^ (((kk >> 3) & 1) << 4);
        src = (const char*)(Bw + (size_t)(kb + kk)*1024 + col0 + col);
      }
      gload_lds16(src, lds + (size_t)cid*16);
    }
    __syncthreads();

    // A fragments: 2 planes x 4 row-frags
    half8 af[2][4];
    #pragma unroll
    for (int pl = 0; pl < 2; pl++)
      #pragma unroll
      for (int fr = 0; fr < 4; fr++) {
        int chunk = (pl*4 + lq)*256 + wr*64 + fr*16 + l15;
        af[pl][fr] = *reinterpret_cast<const half8*>(&Alds[(size_t)chunk*8]);
      }
    int cxor = (lq & 1) << 4;
    #pragma unroll
    for (int fc = 0; fc < 4; fc++) {
      int colx = (wc*64 + fc*16 + l15) ^ cxor;
      half8 b0, b1;
      #pragma unroll
      for (int j = 0; j < 8; j++) {
        float w = Blds[(lq*8 + j)*128 + colx] * 128.0f;
        _Float16 h0 = (_Float16)w;
        float r = w - (float)h0;
        b0[j] = h0; b1[j] = (_Float16)r;
      }
      #pragma unroll
      for (int fr = 0; fr < 4; fr++) {
        acc[fr][fc] = __builtin_amdgcn_mfma_f32_16x16x32_f16(af[0][fr], b0, acc[fr][fc], 0, 0, 0);
        acc[fr][fc] = __builtin_amdgcn_mfma_f32_16x16x32_f16(af[1][fr], b0, acc[fr][fc], 0, 0, 0);
        acc[fr][fc] = __builtin_amdgcn_mfma_f32_16x16x32_f16(af[0][fr], b1, acc[fr][fc], 0, 0, 0);
        acc[fr][fc] = __builtin_amdgcn_mfma_f32_16x16x32_f16(af[1][fr], b1, acc[fr][fc], 0, 0, 0);
      }
    }
  }
  float* pp = part + (size_t)z * 1024 * 1024;
  #pragma unroll
  for (int fr = 0; fr < 4; fr++)
    #pragma unroll
    for (int fc = 0; fc < 4; fc++) {
      int col = col0 + wc*64 + fc*16 + l15;
      #pragma unroll
      for (int rr = 0; rr < 4; rr++) {
        int row = row0 + wr*64 + fr*16 + lq*4 + rr;
        pp[(size_t)row*1024 + col] = acc[fr][fc][rr];
      }
    }
}

// -------- reduce split-K (scale 1/2048 + bias + relu) ----------------------
__global__ void k_reduce_split(const float* __restrict__ part,
                               const float* __restrict__ bias,
                               u16* __restrict__ ys) {
  int idx = blockIdx.x * 256 + threadIdx.x;   // 1M
  float v = 0.f;
  #pragma unroll
  for (int s = 0; s < 8; s++) v += part[idx + (size_t)s*1048576];
  v = v * (1.0f/2048.0f) + bias[idx & 1023];
  v = fmaxf(v, 0.f) * 16.0f;                  // prescale for next layer
  u16 h0, h1;
  split2(v, h0, h1);
  ys[idx] = h0; ys[idx + 1048576] = h1;
}

__global__ void k_reduce_f32(const float* __restrict__ part,
                             const float* __restrict__ bias,
                             float* __restrict__ y) {
  int idx = blockIdx.x * 256 + threadIdx.x;
  float v = 0.f;
  #pragma unroll
  for (int s = 0; s < 8; s++) v += part[idx + (size_t)s*1048576];
  v = v * (1.0f/2048.0f) + bias[idx & 1023];
  y[idx] = fmaxf(v, 0.f);
}

// -------- small GEMM (heads): fp32, 64x64 tile ------------------------------
__global__ __launch_bounds__(256) void k_gemm64(
    const float* __restrict__ A, int lda,
    const float* __restrict__ Bm, int ldb,
    const float* __restrict__ bias,
    float* __restrict__ Cm, int ldc, int N, int K) {
  __shared__ float As[16][65];
  __shared__ float Bs[16][64];
  int tid = threadIdx.x;
  int tx = tid & 15, ty = tid >> 4;
  int row0 = blockIdx.y * 64, col0 = blockIdx.x * 64;
  float acc[4][4] = {};
  for (int k0 = 0; k0 < K; k0 += 16) {
    #pragma unroll
    for (int q = 0; q < 4; q++) {
      int e = tid + q*256;
      As[e&15][e>>4] = A[(size_t)(row0 + (e>>4)) * lda + k0 + (e&15)];
    }
    #pragma unroll
    for (int q = 0; q < 4; q++) {
      int e = tid + q*256;
      int col = col0 + (e&63);
      Bs[e>>6][e&63] = (col < N) ? Bm[(size_t)(k0 + (e>>6)) * ldb + col] : 0.f;
    }
    __syncthreads();
    #pragma unroll
    for (int kk = 0; kk < 16; kk++) {
      float a_[4], b_[4];
      #pragma unroll
      for (int i = 0; i < 4; i++) a_[i] = As[kk][ty*4+i];
      #pragma unroll
      for (int j = 0; j < 4; j++) b_[j] = Bs[kk][tx*4+j];
      #pragma unroll
      for (int i = 0; i < 4; i++)
        #pragma unroll
        for (int j = 0; j < 4; j++)
          acc[i][j] = fmaf(a_[i], b_[j], acc[i][j]);
    }
    __syncthreads();
  }
  #pragma unroll
  for (int i = 0; i < 4; i++) {
    int row = row0 + ty*4 + i;
    #pragma unroll
    for (int j = 0; j < 4; j++) {
      int col = col0 + tx*4 + j;
      if (col < N)
        Cm[(size_t)row*ldc + col] = acc[i][j] + bias[col];
    }
  }
}

// -------- softmax + box decode + candidate keys ----------------------------
__global__ void k_decode(const float* __restrict__ logits,
                         const float* __restrict__ deltas,
                         const float* __restrict__ props,
                         float* __restrict__ cboxes,
                         u64* __restrict__ keys) {
  int r = blockIdx.x;
  int j = threadIdx.x;   // 128
  __shared__ float red[128];
  float lg = (j < NCLS) ? logits[r*NCLS + j] : -3.4e38f;
  red[j] = lg;
  __syncthreads();
  for (int s = 64; s > 0; s >>= 1) {
    if (j < s) red[j] = fmaxf(red[j], red[j+s]);
    __syncthreads();
  }
  float mx = red[0];
  __syncthreads();
  float e = (j < NCLS) ? expf(lg - mx) : 0.f;
  red[j] = e;
  __syncthreads();
  for (int s = 64; s > 0; s >>= 1) {
    if (j < s) red[j] += red[j+s];
    __syncthreads();
  }
  float p = e / red[0];
  if (j >= 1 && j < NCLS) {
    float px1 = props[r*4+0], py1 = props[r*4+1];
    float px2 = props[r*4+2], py2 = props[r*4+3];
    float w = px2 - px1, h = py2 - py1;
    float cx = px1 + 0.5f*w, cy = py1 + 0.5f*h;
    float d0 = deltas[r*364 + j*4 + 0];
    float d1 = deltas[r*364 + j*4 + 1];
    float d2 = deltas[r*364 + j*4 + 2];
    float d3 = deltas[r*364 + j*4 + 3];
    float dx = d0 / 10.0f, dy = d1 / 10.0f;
    float dw = fminf(d2 / 5.0f, 4.135166556742356f);
    float dh = fminf(d3 / 5.0f, 4.135166556742356f);
    float pcx = dx*w + cx, pcy = dy*h + cy;
    float pw = expf(dw)*w, ph = expf(dh)*h;
    float bx1 = fminf(fmaxf(pcx - 0.5f*pw, 0.f), 1216.f);
    float by1 = fminf(fmaxf(pcy - 0.5f*ph, 0.f),  800.f);
    float bx2 = fminf(fmaxf(pcx + 0.5f*pw, 0.f), 1216.f);
    float by2 = fminf(fmaxf(pcy + 0.5f*ph, 0.f),  800.f);
    bool valid = (p > 0.05f) && ((bx2 - bx1) >= 0.01f) && ((by2 - by1) >= 0.01f);
    int b = r >> 8, n = r & 255;
    int cidx = n*90 + (j-1);
    size_t cb = (size_t)b*CAND + cidx;
    cboxes[cb*4+0] = bx1; cboxes[cb*4+1] = by1;
    cboxes[cb*4+2] = bx2; cboxes[cb*4+3] = by2;
    u64 key = 0ull;
    if (valid)
      key = (((u64)__float_as_uint(p)) << 32) | (u32)(~(u32)cidx);
    keys[cb] = key;
  }
}

// -------- per (batch,half): compact valid + bitonic sort desc, top1024 -----
#define SORTN 4096
__global__ __launch_bounds__(1024) void k_sort(const u64* __restrict__ keys,
                                               u64* __restrict__ sorted) {
  __shared__ u64 sk[SORTN];
  __shared__ int cnt;
  int t = threadIdx.x;
  int b = blockIdx.x >> 1, h = blockIdx.x & 1;
  if (t == 0) cnt = 0;
  __syncthreads();
  const u64* kb = keys + (size_t)b*CAND + (size_t)h*(CAND/2);
  for (int q = 0; q < 12; q++) {
    int idx = t + q*1024;
    if (idx < CAND/2) {
      u64 k = kb[idx];
      if (k) { int pos = atomicAdd(&cnt, 1); sk[pos] = k; }
    }
  }
  __syncthreads();
  int total = cnt;
  for (int s = t; s < SORTN; s += 1024)
    if (s >= total) sk[s] = 0ull;
  __syncthreads();
  for (int k = 2; k <= SORTN; k <<= 1) {
    for (int jj = k >> 1; jj > 0; jj >>= 1) {
      for (int i = t; i < SORTN; i += 1024) {
        int ixj = i ^ jj;
        if (ixj > i) {
          u64 a = sk[i], bb = sk[ixj];
          bool up = ((i & k) == 0);
          if (up ? (a < bb) : (a > bb)) { sk[i] = bb; sk[ixj] = a; }
        }
      }
      __syncthreads();
    }
  }
  sorted[((size_t)b*2 + h)*1024 + t] = sk[t];
}

// -------- per batch: merge halves, tiled greedy NMS, emit final 100 --------
__global__ __launch_bounds__(1024) void k_nms(const u64* __restrict__ sorted,
                                              const float* __restrict__ cboxes,
                                              float* __restrict__ out) {
  __shared__ u64 m[2048];
  __shared__ float sX1[1024], sY1[1024], sX2[1024], sY2[1024], sAR[1024];
  __shared__ int keepL[1024];
  __shared__ int wsum[16];
  int t = threadIdx.x;
  int b = blockIdx.x;
  m[t]        = sorted[((size_t)b*2 + 0)*1024 + t];
  m[2047 - t] = sorted[((size_t)b*2 + 1)*1024 + t];
  __syncthreads();
  for (int lg = 10; lg >= 0; lg--) {
    int jj = 1 << lg;
    int pos = ((t >> lg) << (lg+1)) + (t & (jj-1));
    u64 a = m[pos], bb = m[pos + jj];
    if (a < bb) { m[pos] = bb; m[pos + jj] = a; }
    __syncthreads();
  }
  u64 key = m[t];
  bool valid = key != 0ull;
  float score = __uint_as_float((u32)(key >> 32));
  u32 cidx = ~((u32)(key & 0xFFFFFFFFu));
  int label = valid ? (int)(cidx % 90u) + 1 : 0;
  float cb0 = 0.f, cb1 = 0.f, cb2 = 0.f, cb3 = 0.f;
  if (valid) {
    size_t cb = ((size_t)b*CAND + cidx) * 4;
    cb0 = cboxes[cb+0]; cb1 = cboxes[cb+1];
    cb2 = cboxes[cb+2]; cb3 = cboxes[cb+3];
  }
  float off = (float)label * 1218.0f;
  float ox1 = cb0 + off, oy1 = cb1 + off;
  float ox2 = cb2 + off, oy2 = cb3 + off;
  float area = (ox2 - ox1) * (oy2 - oy1);
  sX1[t] = ox1; sY1[t] = oy1; sX2[t] = ox2; sY2[t] = oy2; sAR[t] = area;
  keepL[t] = valid ? 1 : 0;
  __syncthreads();

  int wid = t >> 6, lane = t & 63;
  for (int tile = 0; tile < 16; tile++) {
    if (wid == 0) {
      int idx = tile*64 + lane;
      bool kp = keepL[idx] != 0;
      float bx1 = sX1[idx], by1 = sY1[idx], bx2 = sX2[idx], by2 = sY2[idx], ba = sAR[idx];
      u64 alive = __ballot(kp);
      #pragma unroll 1
      for (int i = 0; i < 63; i++) {
        if ((alive >> i) & 1ull) {
          int ii = tile*64 + i;
          float ltx = fmaxf(sX1[ii], bx1), lty = fmaxf(sY1[ii], by1);
          float rbx = fminf(sX2[ii], bx2), rby = fminf(sY2[ii], by2);
          float iw = fmaxf(rbx - ltx, 0.f), ih = fmaxf(rby - lty, 0.f);
          float inter = iw * ih;
          float iou = inter / (sAR[ii] + ba - inter + 1e-9f);
          if (lane > i && iou > 0.5f) kp = false;
        }
        alive = __ballot(kp);
      }
      keepL[idx] = kp ? 1 : 0;
    }
    __syncthreads();
    if (t >= (tile+1)*64) {
      bool kp = keepL[t] != 0;
      if (kp) {
        #pragma unroll 1
        for (int i = tile*64; i < tile*64 + 64; i++) {
          if (keepL[i]) {
            float ltx = fmaxf(sX1[i], ox1), lty = fmaxf(sY1[i], oy1);
            float rbx = fminf(sX2[i], ox2), rby = fminf(sY2[i], oy2);
            float iw = fmaxf(rbx - ltx, 0.f), ih = fmaxf(rby - lty, 0.f);
            float inter = iw * ih;
            float iou = inter / (sAR[i] + area - inter + 1e-9f);
            if (iou > 0.5f) { kp = false; }
          }
        }
        if (!kp) keepL[t] = 0;
      }
    }
    __syncthreads();
  }

  bool keep = keepL[t] != 0;
  u64 bal = __ballot(keep);
  int wpre = __popcll(bal & ((1ull << lane) - 1ull));
  if (lane == 0) wsum[wid] = __popcll(bal);
  __syncthreads();
  int offn = 0, KT = 0;
  for (int q = 0; q < 16; q++) {
    int v = wsum[q];
    if (q < wid) offn += v;
    KT += v;
  }
  int rank = offn + wpre;
  float* outB = out;
  float* outS = out + 1600;
  float* outL = out + 2000;
  if (keep && rank < 100) {
    size_t s = (size_t)b*100 + rank;
    outB[s*4+0] = cb0; outB[s*4+1] = cb1;
    outB[s*4+2] = cb2; outB[s*4+3] = cb3;
    outS[s] = score; outL[s] = (float)label;
  }
  if (t < 100 && t >= KT) {
    size_t s = (size_t)b*100 + t;
    outB[s*4+0] = 0.f; outB[s*4+1] = 0.f; outB[s*4+2] = 0.f; outB[s*4+3] = 0.f;
    outS[s] = 0.f; outL[s] = 0.f;
  }
}

extern "C" void kernel_launch(void* const* d_in, const int* in_sizes, int n_in,
                              void* d_out, int out_size, void* d_ws, size_t ws_size,
                              hipStream_t stream) {
  (void)in_sizes; (void)n_in; (void)out_size; (void)ws_size;
  const float* feat  = (const float*)d_in[0];
  const float* props = (const float*)d_in[1];
  const float* W6 = (const float*)d_in[2];
  const float* b6 = (const float*)d_in[3];
  const float* W7 = (const float*)d_in[4];
  const float* b7 = (const float*)d_in[5];
  const float* Wc = (const float*)d_in[6];
  const float* bc = (const float*)d_in[7];
  const float* Wb = (const float*)d_in[8];
  const float* bb = (const float*)d_in[9];
  float* out = (float*)d_out;
  char* ws = (char*)d_ws;

  // workspace (peak 113,639,424 B == round-1-proven budget):
  //   phase A: featT [0, 62.26MB) + Xs2 [62.26MB, 113.64MB)
  //   phase B: part [0, 32MB) (featT dead) + Y1s2/Y2/... in [32MB, 47MB)
  float* featT  = (float*)(ws);                        // 62,259,200 B
  u16*   Xs2    = (u16*)  (ws + 62259200);             // 51,380,224 B
  float* part   = (float*)(ws);                        // 33,554,432 B
  u16*   Y1s2   = (u16*)  (ws + 33554432);             //  4,194,304 B
  float* Y2     = (float*)(ws + 37748736);             //  4,194,304 B
  float* logitsP= (float*)(ws + 41943040);
  float* deltasP= (float*)(ws + 42467328);
  float* cboxes = (float*)(ws + 44040192);
  u64*   keys   = (u64*)  (ws + 45613056);
  u64*   sorted = (u64*)  (ws + 46399488);

  dim3 gT(475, 8, 4);
  k_transpose<<<gT, 256, 0, stream>>>(feat, featT);
  k_roialign<<<1024, 256, 0, stream>>>(featT, props, Xs2);

  // FC6: K=12544, split-K=8 (1568 each = 49 steps)
  k_gemm_f16<<<256, 512, 0, stream>>>(Xs2, W6, part, DIN, 49);
  k_reduce_split<<<4096, 256, 0, stream>>>(part, b6, Y1s2);
  // FC7: K=1024, split-K=8 (128 each = 4 steps)
  k_gemm_f16<<<256, 512, 0, stream>>>(Y1s2, W7, part, 1024, 4);
  k_reduce_f32<<<4096, 256, 0, stream>>>(part, b7, Y2);

  dim3 gc(2, 16), gb(6, 16);
  k_gemm64<<<gc, 256, 0, stream>>>(Y2, 1024, Wc,  91, bc, logitsP,  91,  91, 1024);
  k_gemm64<<<gb, 256, 0, stream>>>(Y2, 1024, Wb, 364, bb, deltasP, 364, 364, 1024);

  k_decode<<<1024, 128, 0, stream>>>(logitsP, deltasP, props, cboxes, keys);
  k_sort<<<8, 1024, 0, stream>>>(keys, sorted);
  k_nms<<<4, 1024, 0, stream>>>(sorted, cboxes, out);
}

// Round 4
// 543.351 us; speedup vs baseline: 2.0685x; 1.1173x over previous
//
#include <hip/hip_runtime.h>
#include <hip/hip_bf16.h>
#include <stdint.h>

#define B_    4
#define N_    256
#define C_    256
#define FH_   100
#define FW_   152
#define P_HW  (FH_*FW_)      // 15200
#define NCLS  91
#define CAND  23040          // N_*90
#define DIN   12544
#define PRE   1024

typedef unsigned long long u64;
typedef unsigned int u32;
typedef unsigned short u16;
typedef __attribute__((ext_vector_type(8))) _Float16 half8;
typedef __attribute__((ext_vector_type(8))) short short8;
typedef __attribute__((ext_vector_type(4))) float f32x4;

__device__ inline u16 h2bits(_Float16 h) { return *reinterpret_cast<u16*>(&h); }

// split v (already prescaled) into fp16 h0 + h1, exact-residual style
__device__ inline void split2(float v, u16& b0, u16& b1) {
  _Float16 h0 = (_Float16)v;
  float r = v - (float)h0;
  _Float16 h1 = (_Float16)r;
  b0 = h2bits(h0); b1 = h2bits(h1);
}

__device__ inline void gload_lds16(const void* g, void* l) {
  __builtin_amdgcn_global_load_lds(
      (const __attribute__((address_space(1))) void*)g,
      (__attribute__((address_space(3))) void*)l, 16, 0, 0);
}

// ---------------- feature transpose (B,C,H,W) -> (B,H,W,C) ----------------
__global__ void k_transpose(const float* __restrict__ in, float* __restrict__ out) {
  __shared__ float t[32][33];
  int b  = blockIdx.z;
  int c0 = blockIdx.y * 32;
  int p0 = blockIdx.x * 32;
  int tx = threadIdx.x & 31, ty = threadIdx.x >> 5;
  const float* inb = in  + (size_t)b * C_ * P_HW;
  float*       ob  = out + (size_t)b * P_HW * C_;
  #pragma unroll
  for (int q = 0; q < 4; q++)
    t[ty + q*8][tx] = inb[(size_t)(c0 + ty + q*8) * P_HW + p0 + tx];
  __syncthreads();
  #pragma unroll
  for (int q = 0; q < 4; q++)
    ob[(size_t)(p0 + ty + q*8) * C_ + c0 + tx] = t[tx][ty + q*8];
}

// ------- roi align -> Xt [2 planes][DIN/8][1024 rows][8] fp16 of (X*16) ----
// Tiled layout: chunk (pl, cg, r) at elem offset ((pl*KG + cg)*1024 + r)*8.
// This is exactly GEMM LDS-staging order -> coalesced global_load_lds.
__global__ __launch_bounds__(256) void k_roialign(const float* __restrict__ featT,
                                                  const float* __restrict__ props,
                                                  u16* __restrict__ Xs) {
  __shared__ float cellv[49*256];
  int r = blockIdx.x;
  int b = r >> 8;
  int c = threadIdx.x;
  float x1 = props[r*4+0], y1 = props[r*4+1];
  float x2 = props[r*4+2], y2 = props[r*4+3];
  float x1s = x1 * 0.125f, y1s = y1 * 0.125f;
  float x2s = x2 * 0.125f, y2s = y2 * 0.125f;
  float rw = fmaxf(x2s - x1s, 1.0f);
  float rh = fmaxf(y2s - y1s, 1.0f);
  float rwd = rw / 7.0f, rhd = rh / 7.0f;
  const float* fb = featT + (size_t)b * P_HW * C_ + c;
  for (int py = 0; py < 7; py++) {
    for (int px = 0; px < 7; px++) {
      float acc = 0.f;
      #pragma unroll
      for (int s = 0; s < 4; s++) {
        int sy = s >> 1, sx = s & 1;
        float gqy = (float)py + 0.25f + 0.5f * (float)sy;
        float gqx = (float)px + 0.25f + 0.5f * (float)sx;
        float gy = fminf(fmaxf(y1s + rhd * gqy, 0.0f), 99.0f);
        float gx = fminf(fmaxf(x1s + rwd * gqx, 0.0f), 151.0f);
        float y0f = floorf(gy), x0f = floorf(gx);
        float ly = gy - y0f, lx = gx - x0f;
        int y0i = (int)y0f;
        int y1i = (int)fminf(y0f + 1.0f, 99.0f);
        int x0i = (int)x0f;
        int x1i = (int)fminf(x0f + 1.0f, 151.0f);
        float v00 = fb[((size_t)(y0i * FW_ + x0i)) * C_];
        float v01 = fb[((size_t)(y0i * FW_ + x1i)) * C_];
        float v10 = fb[((size_t)(y1i * FW_ + x0i)) * C_];
        float v11 = fb[((size_t)(y1i * FW_ + x1i)) * C_];
        acc += (1.f-ly)*(1.f-lx)*v00 + (1.f-ly)*lx*v01
             + ly*(1.f-lx)*v10 + ly*lx*v11;
      }
      cellv[(py*7+px)*256 + c] = acc * 4.0f;   // 0.25 (avg) * 16 (prescale)
    }
  }
  __syncthreads();
  const int KG = DIN/8;                       // 1568 chunk-groups
  const size_t PLS = (size_t)KG * 1024 * 8;   // plane stride in elems
  for (int it = 0; it < 7; it++) {
    int cg = threadIdx.x + it*256;
    if (cg < KG) {
      int k0 = cg * 8;
      short8 v0, v1;
      #pragma unroll
      for (int e = 0; e < 8; e++) {
        int k = k0 + e;
        int ch = k / 49;
        int cell = k - ch*49;
        float v = cellv[cell*256 + ch];
        u16 h0, h1;
        split2(v, h0, h1);
        v0[e] = (short)h0; v1[e] = (short)h1;
      }
      size_t base = ((size_t)cg * 1024 + r) * 8;
      *reinterpret_cast<short8*>(Xs + base)       = v0;
      *reinterpret_cast<short8*>(Xs + PLS + base) = v1;
    }
  }
}

// -------- MFMA GEMM, fp32 via fp16 2-plane exact 4-pass, 128x128 tile ------
// As: tiled [2][kg][1024][8] fp16 of (A*16). Bw: [K][1024] fp32 (x128 split
// in-kernel). part: [8][1024][1024] fp32 partials of (A@B)*2048.
// grid = 512: z = bid&7 (K-slice, locked to XCD), xy = bid>>3 (8 col x 4... 8x8 tiles)
__global__ __launch_bounds__(256) void k_gemm_f16(
    const u16* __restrict__ As, const float* __restrict__ Bw,
    float* __restrict__ part, int kg, int nsteps) {
  __shared__ __align__(16) char lds[32768];   // A 16KB (2 planes), B 16KB fp32
  u16*   Alds = (u16*)lds;
  float* Blds = (float*)(lds + 16384);
  int tid = threadIdx.x;
  int wid = tid >> 6, lane = tid & 63;
  int l15 = lane & 15, lq = lane >> 4;
  int bid = blockIdx.x;
  int z = bid & 7, xy = bid >> 3;              // one K-slice per XCD
  int col0 = (xy & 7) * 128, row0 = (xy >> 3) * 128;
  int wr = wid >> 1, wc = wid & 1;             // 4 waves: 2x2, wave tile 64x64
  int kbase0 = z * nsteps * 32;

  f32x4 acc[4][4];
  #pragma unroll
  for (int i = 0; i < 4; i++)
    #pragma unroll
    for (int j = 0; j < 4; j++)
      #pragma unroll
      for (int q = 0; q < 4; q++) acc[i][j][q] = 0.f;

  for (int s = 0; s < nsteps; s++) {
    int kb = kbase0 + s * 32;
    __syncthreads();
    // stage 2048 16B chunks: A = [0,1024) coalesced, B = [1024,2048)
    #pragma unroll
    for (int j = 0; j < 8; j++) {
      int cid = tid + j*256;
      const char* src;
      if (j < 4) {
        int pl = cid >> 9;
        int kc = (cid >> 7) & 3, r = cid & 127;
        src = (const char*)(As + ((size_t)(pl*kg + (kb>>3) + kc)*1024 + row0 + r)*8);
      } else {
        int cid2 = cid - 1024;
        int kk = cid2 >> 5, c4 = cid2 & 31;
        int col = (c4*4) ^ (((kk >> 3) & 1) << 4);
        src = (const char*)(Bw + (size_t)(kb + kk)*1024 + col0 + col);
      }
      gload_lds16(src, lds + (size_t)cid*16);
    }
    __syncthreads();

    // A fragments: 2 planes x 4 row-frags
    half8 af[2][4];
    #pragma unroll
    for (int pl = 0; pl < 2; pl++)
      #pragma unroll
      for (int fr = 0; fr < 4; fr++) {
        int chunk = (pl*4 + lq)*128 + wr*64 + fr*16 + l15;
        af[pl][fr] = *reinterpret_cast<const half8*>(&Alds[(size_t)chunk*8]);
      }
    int cxor = (lq & 1) << 4;
    #pragma unroll
    for (int fc = 0; fc < 4; fc++) {
      int colx = (wc*64 + fc*16 + l15) ^ cxor;
      half8 b0, b1;
      #pragma unroll
      for (int j = 0; j < 8; j++) {
        float w = Blds[(lq*8 + j)*128 + colx] * 128.0f;
        _Float16 h0 = (_Float16)w;
        float r = w - (float)h0;
        b0[j] = h0; b1[j] = (_Float16)r;
      }
      #pragma unroll
      for (int fr = 0; fr < 4; fr++) {
        acc[fr][fc] = __builtin_amdgcn_mfma_f32_16x16x32_f16(af[0][fr], b0, acc[fr][fc], 0, 0, 0);
        acc[fr][fc] = __builtin_amdgcn_mfma_f32_16x16x32_f16(af[1][fr], b0, acc[fr][fc], 0, 0, 0);
        acc[fr][fc] = __builtin_amdgcn_mfma_f32_16x16x32_f16(af[0][fr], b1, acc[fr][fc], 0, 0, 0);
        acc[fr][fc] = __builtin_amdgcn_mfma_f32_16x16x32_f16(af[1][fr], b1, acc[fr][fc], 0, 0, 0);
      }
    }
  }
  float* pp = part + (size_t)z * 1024 * 1024;
  #pragma unroll
  for (int fr = 0; fr < 4; fr++)
    #pragma unroll
    for (int fc = 0; fc < 4; fc++) {
      int col = col0 + wc*64 + fc*16 + l15;
      #pragma unroll
      for (int rr = 0; rr < 4; rr++) {
        int row = row0 + wr*64 + fr*16 + lq*4 + rr;
        pp[(size_t)row*1024 + col] = acc[fr][fc][rr];
      }
    }
}

// -------- reduce split-K -> Y1 tiled fp16 planes (coalesced reads) ---------
// thread handles one (row, colgroup-of-8): reads 8 slices x 32B coalesced,
// writes one 16B chunk per plane at tiled [pl][cg][row][8].
__global__ void k_reduce_split(const float* __restrict__ part,
                               const float* __restrict__ bias,
                               u16* __restrict__ ys) {
  int idx = blockIdx.x * 256 + threadIdx.x;   // 131072 = 1024 rows * 128 cg
  int row = idx >> 7, cg = idx & 127;
  float4 s0 = {0,0,0,0}, s1 = {0,0,0,0};
  #pragma unroll
  for (int s = 0; s < 8; s++) {
    const float4* p = (const float4*)(part + (size_t)s*1048576 + (size_t)row*1024 + cg*8);
    float4 a = p[0], b = p[1];
    s0.x += a.x; s0.y += a.y; s0.z += a.z; s0.w += a.w;
    s1.x += b.x; s1.y += b.y; s1.z += b.z; s1.w += b.w;
  }
  float v[8] = {s0.x, s0.y, s0.z, s0.w, s1.x, s1.y, s1.z, s1.w};
  short8 o0, o1;
  #pragma unroll
  for (int e = 0; e < 8; e++) {
    float x = v[e] * (1.0f/2048.0f) + bias[cg*8 + e];
    x = fmaxf(x, 0.f) * 16.0f;                // prescale for next layer
    u16 h0, h1;
    split2(x, h0, h1);
    o0[e] = (short)h0; o1[e] = (short)h1;
  }
  size_t base = ((size_t)cg * 1024 + row) * 8;   // kg = 128 for K=1024
  *reinterpret_cast<short8*>(ys + base)               = o0;
  *reinterpret_cast<short8*>(ys + (size_t)1048576 + base) = o1;
}

__global__ void k_reduce_f32(const float* __restrict__ part,
                             const float* __restrict__ bias,
                             float* __restrict__ y) {
  int idx = blockIdx.x * 256 + threadIdx.x;
  float v = 0.f;
  #pragma unroll
  for (int s = 0; s < 8; s++) v += part[idx + (size_t)s*1048576];
  v = v * (1.0f/2048.0f) + bias[idx & 1023];
  y[idx] = fmaxf(v, 0.f);
}

// -------- small GEMM (heads): fp32, 64x64 tile ------------------------------
__global__ __launch_bounds__(256) void k_gemm64(
    const float* __restrict__ A, int lda,
    const float* __restrict__ Bm, int ldb,
    const float* __restrict__ bias,
    float* __restrict__ Cm, int ldc, int N, int K) {
  __shared__ float As[16][65];
  __shared__ float Bs[16][64];
  int tid = threadIdx.x;
  int tx = tid & 15, ty = tid >> 4;
  int row0 = blockIdx.y * 64, col0 = blockIdx.x * 64;
  float acc[4][4] = {};
  for (int k0 = 0; k0 < K; k0 += 16) {
    #pragma unroll
    for (int q = 0; q < 4; q++) {
      int e = tid + q*256;
      As[e&15][e>>4] = A[(size_t)(row0 + (e>>4)) * lda + k0 + (e&15)];
    }
    #pragma unroll
    for (int q = 0; q < 4; q++) {
      int e = tid + q*256;
      int col = col0 + (e&63);
      Bs[e>>6][e&63] = (col < N) ? Bm[(size_t)(k0 + (e>>6)) * ldb + col] : 0.f;
    }
    __syncthreads();
    #pragma unroll
    for (int kk = 0; kk < 16; kk++) {
      float a_[4], b_[4];
      #pragma unroll
      for (int i = 0; i < 4; i++) a_[i] = As[kk][ty*4+i];
      #pragma unroll
      for (int j = 0; j < 4; j++) b_[j] = Bs[kk][tx*4+j];
      #pragma unroll
      for (int i = 0; i < 4; i++)
        #pragma unroll
        for (int j = 0; j < 4; j++)
          acc[i][j] = fmaf(a_[i], b_[j], acc[i][j]);
    }
    __syncthreads();
  }
  #pragma unroll
  for (int i = 0; i < 4; i++) {
    int row = row0 + ty*4 + i;
    #pragma unroll
    for (int j = 0; j < 4; j++) {
      int col = col0 + tx*4 + j;
      if (col < N)
        Cm[(size_t)row*ldc + col] = acc[i][j] + bias[col];
    }
  }
}

// -------- softmax + box decode + candidate keys ----------------------------
__global__ void k_decode(const float* __restrict__ logits,
                         const float* __restrict__ deltas,
                         const float* __restrict__ props,
                         float* __restrict__ cboxes,
                         u64* __restrict__ keys) {
  int r = blockIdx.x;
  int j = threadIdx.x;   // 128
  __shared__ float red[128];
  float lg = (j < NCLS) ? logits[r*NCLS + j] : -3.4e38f;
  red[j] = lg;
  __syncthreads();
  for (int s = 64; s > 0; s >>= 1) {
    if (j < s) red[j] = fmaxf(red[j], red[j+s]);
    __syncthreads();
  }
  float mx = red[0];
  __syncthreads();
  float e = (j < NCLS) ? expf(lg - mx) : 0.f;
  red[j] = e;
  __syncthreads();
  for (int s = 64; s > 0; s >>= 1) {
    if (j < s) red[j] += red[j+s];
    __syncthreads();
  }
  float p = e / red[0];
  if (j >= 1 && j < NCLS) {
    float px1 = props[r*4+0], py1 = props[r*4+1];
    float px2 = props[r*4+2], py2 = props[r*4+3];
    float w = px2 - px1, h = py2 - py1;
    float cx = px1 + 0.5f*w, cy = py1 + 0.5f*h;
    float d0 = deltas[r*364 + j*4 + 0];
    float d1 = deltas[r*364 + j*4 + 1];
    float d2 = deltas[r*364 + j*4 + 2];
    float d3 = deltas[r*364 + j*4 + 3];
    float dx = d0 / 10.0f, dy = d1 / 10.0f;
    float dw = fminf(d2 / 5.0f, 4.135166556742356f);
    float dh = fminf(d3 / 5.0f, 4.135166556742356f);
    float pcx = dx*w + cx, pcy = dy*h + cy;
    float pw = expf(dw)*w, ph = expf(dh)*h;
    float bx1 = fminf(fmaxf(pcx - 0.5f*pw, 0.f), 1216.f);
    float by1 = fminf(fmaxf(pcy - 0.5f*ph, 0.f),  800.f);
    float bx2 = fminf(fmaxf(pcx + 0.5f*pw, 0.f), 1216.f);
    float by2 = fminf(fmaxf(pcy + 0.5f*ph, 0.f),  800.f);
    bool valid = (p > 0.05f) && ((bx2 - bx1) >= 0.01f) && ((by2 - by1) >= 0.01f);
    int b = r >> 8, n = r & 255;
    int cidx = n*90 + (j-1);
    size_t cb = (size_t)b*CAND + cidx;
    cboxes[cb*4+0] = bx1; cboxes[cb*4+1] = by1;
    cboxes[cb*4+2] = bx2; cboxes[cb*4+3] = by2;
    u64 key = 0ull;
    if (valid)
      key = (((u64)__float_as_uint(p)) << 32) | (u32)(~(u32)cidx);
    keys[cb] = key;
  }
}

// -------- per (batch,half): compact valid + bitonic sort desc, top1024 -----
#define SORTN 4096
__global__ __launch_bounds__(1024) void k_sort(const u64* __restrict__ keys,
                                               u64* __restrict__ sorted) {
  __shared__ u64 sk[SORTN];
  __shared__ int cnt;
  int t = threadIdx.x;
  int b = blockIdx.x >> 1, h = blockIdx.x & 1;
  if (t == 0) cnt = 0;
  __syncthreads();
  const u64* kb = keys + (size_t)b*CAND + (size_t)h*(CAND/2);
  for (int q = 0; q < 12; q++) {
    int idx = t + q*1024;
    if (idx < CAND/2) {
      u64 k = kb[idx];
      if (k) { int pos = atomicAdd(&cnt, 1); sk[pos] = k; }
    }
  }
  __syncthreads();
  int total = cnt;
  for (int s = t; s < SORTN; s += 1024)
    if (s >= total) sk[s] = 0ull;
  __syncthreads();
  for (int k = 2; k <= SORTN; k <<= 1) {
    for (int jj = k >> 1; jj > 0; jj >>= 1) {
      for (int i = t; i < SORTN; i += 1024) {
        int ixj = i ^ jj;
        if (ixj > i) {
          u64 a = sk[i], bb = sk[ixj];
          bool up = ((i & k) == 0);
          if (up ? (a < bb) : (a > bb)) { sk[i] = bb; sk[ixj] = a; }
        }
      }
      __syncthreads();
    }
  }
  sorted[((size_t)b*2 + h)*1024 + t] = sk[t];
}

// -------- per batch: merge halves, tiled greedy NMS, emit final 100 --------
__global__ __launch_bounds__(1024) void k_nms(const u64* __restrict__ sorted,
                                              const float* __restrict__ cboxes,
                                              float* __restrict__ out) {
  __shared__ u64 m[2048];
  __shared__ float sX1[1024], sY1[1024], sX2[1024], sY2[1024], sAR[1024];
  __shared__ int keepL[1024];
  __shared__ int wsum[16];
  int t = threadIdx.x;
  int b = blockIdx.x;
  m[t]        = sorted[((size_t)b*2 + 0)*1024 + t];
  m[2047 - t] = sorted[((size_t)b*2 + 1)*1024 + t];
  __syncthreads();
  for (int lg = 10; lg >= 0; lg--) {
    int jj = 1 << lg;
    int pos = ((t >> lg) << (lg+1)) + (t & (jj-1));
    u64 a = m[pos], bb = m[pos + jj];
    if (a < bb) { m[pos] = bb; m[pos + jj] = a; }
    __syncthreads();
  }
  u64 key = m[t];
  bool valid = key != 0ull;
  float score = __uint_as_float((u32)(key >> 32));
  u32 cidx = ~((u32)(key & 0xFFFFFFFFu));
  int label = valid ? (int)(cidx % 90u) + 1 : 0;
  float cb0 = 0.f, cb1 = 0.f, cb2 = 0.f, cb3 = 0.f;
  if (valid) {
    size_t cb = ((size_t)b*CAND + cidx) * 4;
    cb0 = cboxes[cb+0]; cb1 = cboxes[cb+1];
    cb2 = cboxes[cb+2]; cb3 = cboxes[cb+3];
  }
  float off = (float)label * 1218.0f;
  float ox1 = cb0 + off, oy1 = cb1 + off;
  float ox2 = cb2 + off, oy2 = cb3 + off;
  float area = (ox2 - ox1) * (oy2 - oy1);
  sX1[t] = ox1; sY1[t] = oy1; sX2[t] = ox2; sY2[t] = oy2; sAR[t] = area;
  keepL[t] = valid ? 1 : 0;
  __syncthreads();

  int wid = t >> 6, lane = t & 63;
  for (int tile = 0; tile < 16; tile++) {
    if (wid == 0) {
      int idx = tile*64 + lane;
      bool kp = keepL[idx] != 0;
      float bx1 = sX1[idx], by1 = sY1[idx], bx2 = sX2[idx], by2 = sY2[idx], ba = sAR[idx];
      u64 alive = __ballot(kp);
      #pragma unroll 1
      for (int i = 0; i < 63; i++) {
        if ((alive >> i) & 1ull) {
          int ii = tile*64 + i;
          float ltx = fmaxf(sX1[ii], bx1), lty = fmaxf(sY1[ii], by1);
          float rbx = fminf(sX2[ii], bx2), rby = fminf(sY2[ii], by2);
          float iw = fmaxf(rbx - ltx, 0.f), ih = fmaxf(rby - lty, 0.f);
          float inter = iw * ih;
          float iou = inter / (sAR[ii] + ba - inter + 1e-9f);
          if (lane > i && iou > 0.5f) kp = false;
        }
        alive = __ballot(kp);
      }
      keepL[idx] = kp ? 1 : 0;
    }
    __syncthreads();
    if (t >= (tile+1)*64) {
      bool kp = keepL[t] != 0;
      if (kp) {
        #pragma unroll 1
        for (int i = tile*64; i < tile*64 + 64; i++) {
          if (keepL[i]) {
            float ltx = fmaxf(sX1[i], ox1), lty = fmaxf(sY1[i], oy1);
            float rbx = fminf(sX2[i], ox2), rby = fminf(sY2[i], oy2);
            float iw = fmaxf(rbx - ltx, 0.f), ih = fmaxf(rby - lty, 0.f);
            float inter = iw * ih;
            float iou = inter / (sAR[i] + area - inter + 1e-9f);
            if (iou > 0.5f) { kp = false; }
          }
        }
        if (!kp) keepL[t] = 0;
      }
    }
    __syncthreads();
  }

  bool keep = keepL[t] != 0;
  u64 bal = __ballot(keep);
  int wpre = __popcll(bal & ((1ull << lane) - 1ull));
  if (lane == 0) wsum[wid] = __popcll(bal);
  __syncthreads();
  int offn = 0, KT = 0;
  for (int q = 0; q < 16; q++) {
    int v = wsum[q];
    if (q < wid) offn += v;
    KT += v;
  }
  int rank = offn + wpre;
  float* outB = out;
  float* outS = out + 1600;
  float* outL = out + 2000;
  if (keep && rank < 100) {
    size_t s = (size_t)b*100 + rank;
    outB[s*4+0] = cb0; outB[s*4+1] = cb1;
    outB[s*4+2] = cb2; outB[s*4+3] = cb3;
    outS[s] = score; outL[s] = (float)label;
  }
  if (t < 100 && t >= KT) {
    size_t s = (size_t)b*100 + t;
    outB[s*4+0] = 0.f; outB[s*4+1] = 0.f; outB[s*4+2] = 0.f; outB[s*4+3] = 0.f;
    outS[s] = 0.f; outL[s] = 0.f;
  }
}

extern "C" void kernel_launch(void* const* d_in, const int* in_sizes, int n_in,
                              void* d_out, int out_size, void* d_ws, size_t ws_size,
                              hipStream_t stream) {
  (void)in_sizes; (void)n_in; (void)out_size; (void)ws_size;
  const float* feat  = (const float*)d_in[0];
  const float* props = (const float*)d_in[1];
  const float* W6 = (const float*)d_in[2];
  const float* b6 = (const float*)d_in[3];
  const float* W7 = (const float*)d_in[4];
  const float* b7 = (const float*)d_in[5];
  const float* Wc = (const float*)d_in[6];
  const float* bc = (const float*)d_in[7];
  const float* Wb = (const float*)d_in[8];
  const float* bb = (const float*)d_in[9];
  float* out = (float*)d_out;
  char* ws = (char*)d_ws;

  // workspace (peak 113,639,424 B == proven budget):
  //   phase A: featT [0, 62.26MB) + Xs2 [62.26MB, 113.64MB)
  //   phase B: part [0, 32MB) (featT dead) + Y1s2/Y2/... in [32MB, 47MB)
  float* featT  = (float*)(ws);                        // 62,259,200 B
  u16*   Xs2    = (u16*)  (ws + 62259200);             // 51,380,224 B (tiled)
  float* part   = (float*)(ws);                        // 33,554,432 B (8 slices)
  u16*   Y1s2   = (u16*)  (ws + 33554432);             //  4,194,304 B (tiled)
  float* Y2     = (float*)(ws + 37748736);             //  4,194,304 B
  float* logitsP= (float*)(ws + 41943040);
  float* deltasP= (float*)(ws + 42467328);
  float* cboxes = (float*)(ws + 44040192);
  u64*   keys   = (u64*)  (ws + 45613056);
  u64*   sorted = (u64*)  (ws + 46399488);

  dim3 gT(475, 8, 4);
  k_transpose<<<gT, 256, 0, stream>>>(feat, featT);
  k_roialign<<<1024, 256, 0, stream>>>(featT, props, Xs2);

  // FC6: K=12544 (kg=1568), split-K=8, 49 steps/slice, 512 blocks (2/CU)
  k_gemm_f16<<<512, 256, 0, stream>>>(Xs2, W6, part, DIN/8, 49);
  k_reduce_split<<<512, 256, 0, stream>>>(part, b6, Y1s2);
  // FC7: K=1024 (kg=128), split-K=8, 4 steps/slice
  k_gemm_f16<<<512, 256, 0, stream>>>(Y1s2, W7, part, 1024/8, 4);
  k_reduce_f32<<<4096, 256, 0, stream>>>(part, b7, Y2);

  dim3 gc(2, 16), gb(6, 16);
  k_gemm64<<<gc, 256, 0, stream>>>(Y2, 1024, Wc,  91, bc, logitsP,  91,  91, 1024);
  k_gemm64<<<gb, 256, 0, stream>>>(Y2, 1024, Wb, 364, bb, deltasP, 364, 364, 1024);

  k_decode<<<1024, 128, 0, stream>>>(logitsP, deltasP, props, cboxes, keys);
  k_sort<<<8, 1024, 0, stream>>>(keys, sorted);
  k_nms<<<4, 1024, 0, stream>>>(sorted, cboxes, out);
}

// Round 5
// 377.575 us; speedup vs baseline: 2.9766x; 1.4391x over previous
//
#include <hip/hip_runtime.h>
#include <hip/hip_bf16.h>
#include <stdint.h>

#define B_    4
#define N_    256
#define C_    256
#define FH_   100
#define FW_   152
#define P_HW  (FH_*FW_)      // 15200
#define NCLS  91
#define CAND  23040          // N_*90
#define DIN   12544
#define PRE   1024

typedef unsigned long long u64;
typedef unsigned int u32;
typedef unsigned short u16;
typedef __attribute__((ext_vector_type(8))) _Float16 half8;
typedef __attribute__((ext_vector_type(8))) short short8;
typedef __attribute__((ext_vector_type(4))) float f32x4;

__device__ inline u16 h2bits(_Float16 h) { return *reinterpret_cast<u16*>(&h); }

// split v (already prescaled) into fp16 h0 + h1, exact-residual style
__device__ inline void split2(float v, u16& b0, u16& b1) {
  _Float16 h0 = (_Float16)v;
  float r = v - (float)h0;
  _Float16 h1 = (_Float16)r;
  b0 = h2bits(h0); b1 = h2bits(h1);
}

__device__ inline void gload_lds16(const void* g, void* l) {
  __builtin_amdgcn_global_load_lds(
      (const __attribute__((address_space(1))) void*)g,
      (__attribute__((address_space(3))) void*)l, 16, 0, 0);
}

// ---------------- feature transpose (B,C,H,W) -> (B,H,W,C) ----------------
__global__ void k_transpose(const float* __restrict__ in, float* __restrict__ out) {
  __shared__ float t[32][33];
  int b  = blockIdx.z;
  int c0 = blockIdx.y * 32;
  int p0 = blockIdx.x * 32;
  int tx = threadIdx.x & 31, ty = threadIdx.x >> 5;
  const float* inb = in  + (size_t)b * C_ * P_HW;
  float*       ob  = out + (size_t)b * P_HW * C_;
  #pragma unroll
  for (int q = 0; q < 4; q++)
    t[ty + q*8][tx] = inb[(size_t)(c0 + ty + q*8) * P_HW + p0 + tx];
  __syncthreads();
  #pragma unroll
  for (int q = 0; q < 4; q++)
    ob[(size_t)(p0 + ty + q*8) * C_ + c0 + tx] = t[tx][ty + q*8];
}

// ------- roi align -> Xt [2 planes][DIN/8][1024 rows][8] fp16 of (X*16) ----
__global__ __launch_bounds__(256) void k_roialign(const float* __restrict__ featT,
                                                  const float* __restrict__ props,
                                                  u16* __restrict__ Xs) {
  __shared__ float cellv[49*256];
  int r = blockIdx.x;
  int b = r >> 8;
  int c = threadIdx.x;
  float x1 = props[r*4+0], y1 = props[r*4+1];
  float x2 = props[r*4+2], y2 = props[r*4+3];
  float x1s = x1 * 0.125f, y1s = y1 * 0.125f;
  float x2s = x2 * 0.125f, y2s = y2 * 0.125f;
  float rw = fmaxf(x2s - x1s, 1.0f);
  float rh = fmaxf(y2s - y1s, 1.0f);
  float rwd = rw / 7.0f, rhd = rh / 7.0f;
  const float* fb = featT + (size_t)b * P_HW * C_ + c;
  for (int py = 0; py < 7; py++) {
    for (int px = 0; px < 7; px++) {
      float acc = 0.f;
      #pragma unroll
      for (int s = 0; s < 4; s++) {
        int sy = s >> 1, sx = s & 1;
        float gqy = (float)py + 0.25f + 0.5f * (float)sy;
        float gqx = (float)px + 0.25f + 0.5f * (float)sx;
        float gy = fminf(fmaxf(y1s + rhd * gqy, 0.0f), 99.0f);
        float gx = fminf(fmaxf(x1s + rwd * gqx, 0.0f), 151.0f);
        float y0f = floorf(gy), x0f = floorf(gx);
        float ly = gy - y0f, lx = gx - x0f;
        int y0i = (int)y0f;
        int y1i = (int)fminf(y0f + 1.0f, 99.0f);
        int x0i = (int)x0f;
        int x1i = (int)fminf(x0f + 1.0f, 151.0f);
        float v00 = fb[((size_t)(y0i * FW_ + x0i)) * C_];
        float v01 = fb[((size_t)(y0i * FW_ + x1i)) * C_];
        float v10 = fb[((size_t)(y1i * FW_ + x0i)) * C_];
        float v11 = fb[((size_t)(y1i * FW_ + x1i)) * C_];
        acc += (1.f-ly)*(1.f-lx)*v00 + (1.f-ly)*lx*v01
             + ly*(1.f-lx)*v10 + ly*lx*v11;
      }
      cellv[(py*7+px)*256 + c] = acc * 4.0f;   // 0.25 (avg) * 16 (prescale)
    }
  }
  __syncthreads();
  const int KG = DIN/8;                       // 1568 chunk-groups
  const size_t PLS = (size_t)KG * 1024 * 8;   // plane stride in elems
  for (int it = 0; it < 7; it++) {
    int cg = threadIdx.x + it*256;
    if (cg < KG) {
      int k0 = cg * 8;
      short8 v0, v1;
      #pragma unroll
      for (int e = 0; e < 8; e++) {
        int k = k0 + e;
        int ch = k / 49;
        int cell = k - ch*49;
        float v = cellv[cell*256 + ch];
        u16 h0, h1;
        split2(v, h0, h1);
        v0[e] = (short)h0; v1[e] = (short)h1;
      }
      size_t base = ((size_t)cg * 1024 + r) * 8;
      *reinterpret_cast<short8*>(Xs + base)       = v0;
      *reinterpret_cast<short8*>(Xs + PLS + base) = v1;
    }
  }
}

// -------- MFMA GEMM, fp32 via fp16 2-plane exact 4-pass, 128x128 tile ------
// As: tiled [2][kg][1024][8] fp16 of (A*16). Bw: [K][outw] fp32 (x128 split
// in-kernel). part: [8][1024][outw] fp32 partials of (A@B)*2048.
// grid = nct*rowtiles*8: z = bid&7 (K-slice), xy = bid>>3.
__global__ __launch_bounds__(256) void k_gemm_f16(
    const u16* __restrict__ As, const float* __restrict__ Bw,
    float* __restrict__ part, int kg, int nsteps, int nct, int outw,
    size_t sstride) {
  __shared__ __align__(16) char lds[32768];   // A 16KB (2 planes), B 16KB fp32
  u16*   Alds = (u16*)lds;
  float* Blds = (float*)(lds + 16384);
  int tid = threadIdx.x;
  int wid = tid >> 6, lane = tid & 63;
  int l15 = lane & 15, lq = lane >> 4;
  int bid = blockIdx.x;
  int z = bid & 7, xy = bid >> 3;
  int col0 = (xy % nct) * 128, row0 = (xy / nct) * 128;
  int wr = wid >> 1, wc = wid & 1;             // 4 waves: 2x2, wave tile 64x64
  int kbase0 = z * nsteps * 32;

  f32x4 acc[4][4];
  #pragma unroll
  for (int i = 0; i < 4; i++)
    #pragma unroll
    for (int j = 0; j < 4; j++)
      #pragma unroll
      for (int q = 0; q < 4; q++) acc[i][j][q] = 0.f;

  for (int s = 0; s < nsteps; s++) {
    int kb = kbase0 + s * 32;
    __syncthreads();
    // stage 2048 16B chunks: A = [0,1024) coalesced, B = [1024,2048)
    #pragma unroll
    for (int j = 0; j < 8; j++) {
      int cid = tid + j*256;
      const char* src;
      if (j < 4) {
        int pl = cid >> 9;
        int kc = (cid >> 7) & 3, r = cid & 127;
        src = (const char*)(As + ((size_t)(pl*kg + (kb>>3) + kc)*1024 + row0 + r)*8);
      } else {
        int cid2 = cid - 1024;
        int kk = cid2 >> 5, c4 = cid2 & 31;
        int col = (c4*4) ^ (((kk >> 3) & 1) << 4);
        src = (const char*)(Bw + (size_t)(kb + kk)*outw + col0 + col);
      }
      gload_lds16(src, lds + (size_t)cid*16);
    }
    __syncthreads();

    // A fragments: 2 planes x 4 row-frags
    half8 af[2][4];
    #pragma unroll
    for (int pl = 0; pl < 2; pl++)
      #pragma unroll
      for (int fr = 0; fr < 4; fr++) {
        int chunk = (pl*4 + lq)*128 + wr*64 + fr*16 + l15;
        af[pl][fr] = *reinterpret_cast<const half8*>(&Alds[(size_t)chunk*8]);
      }
    int cxor = (lq & 1) << 4;
    #pragma unroll
    for (int fc = 0; fc < 4; fc++) {
      int colx = (wc*64 + fc*16 + l15) ^ cxor;
      half8 b0, b1;
      #pragma unroll
      for (int j = 0; j < 8; j++) {
        float w = Blds[(lq*8 + j)*128 + colx] * 128.0f;
        _Float16 h0 = (_Float16)w;
        float r = w - (float)h0;
        b0[j] = h0; b1[j] = (_Float16)r;
      }
      #pragma unroll
      for (int fr = 0; fr < 4; fr++) {
        acc[fr][fc] = __builtin_amdgcn_mfma_f32_16x16x32_f16(af[0][fr], b0, acc[fr][fc], 0, 0, 0);
        acc[fr][fc] = __builtin_amdgcn_mfma_f32_16x16x32_f16(af[1][fr], b0, acc[fr][fc], 0, 0, 0);
        acc[fr][fc] = __builtin_amdgcn_mfma_f32_16x16x32_f16(af[0][fr], b1, acc[fr][fc], 0, 0, 0);
        acc[fr][fc] = __builtin_amdgcn_mfma_f32_16x16x32_f16(af[1][fr], b1, acc[fr][fc], 0, 0, 0);
      }
    }
  }
  float* pp = part + (size_t)z * sstride;
  #pragma unroll
  for (int fr = 0; fr < 4; fr++)
    #pragma unroll
    for (int fc = 0; fc < 4; fc++) {
      int col = col0 + wc*64 + fc*16 + l15;
      #pragma unroll
      for (int rr = 0; rr < 4; rr++) {
        int row = row0 + wr*64 + fr*16 + lq*4 + rr;
        pp[(size_t)row*outw + col] = acc[fr][fc][rr];
      }
    }
}

// -------- reduce split-K -> tiled fp16 planes (coalesced reads) ------------
__global__ void k_reduce_split(const float* __restrict__ part,
                               const float* __restrict__ bias,
                               u16* __restrict__ ys) {
  int idx = blockIdx.x * 256 + threadIdx.x;   // 131072 = 1024 rows * 128 cg
  int row = idx >> 7, cg = idx & 127;
  float4 s0 = {0,0,0,0}, s1 = {0,0,0,0};
  #pragma unroll
  for (int s = 0; s < 8; s++) {
    const float4* p = (const float4*)(part + (size_t)s*1048576 + (size_t)row*1024 + cg*8);
    float4 a = p[0], b = p[1];
    s0.x += a.x; s0.y += a.y; s0.z += a.z; s0.w += a.w;
    s1.x += b.x; s1.y += b.y; s1.z += b.z; s1.w += b.w;
  }
  float v[8] = {s0.x, s0.y, s0.z, s0.w, s1.x, s1.y, s1.z, s1.w};
  short8 o0, o1;
  #pragma unroll
  for (int e = 0; e < 8; e++) {
    float x = v[e] * (1.0f/2048.0f) + bias[cg*8 + e];
    x = fmaxf(x, 0.f) * 16.0f;                // prescale for next layer
    u16 h0, h1;
    split2(x, h0, h1);
    o0[e] = (short)h0; o1[e] = (short)h1;
  }
  size_t base = ((size_t)cg * 1024 + row) * 8;   // kg = 128 for K=1024
  *reinterpret_cast<short8*>(ys + base)               = o0;
  *reinterpret_cast<short8*>(ys + (size_t)1048576 + base) = o1;
}

// -------- pack Wc|Wb -> Wcat [1024][512] fp32 (pad 455..511 = 0), bcat -----
__global__ void k_packW(const float* __restrict__ Wc, const float* __restrict__ Wb,
                        const float* __restrict__ bc, const float* __restrict__ bb,
                        float* __restrict__ Wcat, float* __restrict__ bcat) {
  int idx = blockIdx.x * 256 + threadIdx.x;   // 524288
  int k = idx >> 9, col = idx & 511;
  float v = 0.f;
  if (col < 91)       v = Wc[(size_t)k*91 + col];
  else if (col < 455) v = Wb[(size_t)k*364 + (col - 91)];
  Wcat[idx] = v;
  if (idx < 512) {
    float bv = 0.f;
    if (idx < 91)       bv = bc[idx];
    else if (idx < 455) bv = bb[idx - 91];
    bcat[idx] = bv;
  }
}

// -------- heads reduce: sum 8 slices, +bcat, scatter to logits/deltas ------
__global__ void k_reduce_heads(const float* __restrict__ part,
                               const float* __restrict__ bcat,
                               float* __restrict__ logits,
                               float* __restrict__ deltas) {
  int idx = blockIdx.x * 256 + threadIdx.x;   // 524288 = 1024 * 512
  int row = idx >> 9, col = idx & 511;
  float v = 0.f;
  #pragma unroll
  for (int s = 0; s < 8; s++) v += part[idx + (size_t)s*524288];
  v = v * (1.0f/2048.0f) + bcat[col];
  if (col < 91)       logits[(size_t)row*91 + col] = v;
  else if (col < 455) deltas[(size_t)row*364 + (col - 91)] = v;
}

// -------- softmax + box decode + candidate keys ----------------------------
__global__ void k_decode(const float* __restrict__ logits,
                         const float* __restrict__ deltas,
                         const float* __restrict__ props,
                         float* __restrict__ cboxes,
                         u64* __restrict__ keys) {
  int r = blockIdx.x;
  int j = threadIdx.x;   // 128
  __shared__ float red[128];
  float lg = (j < NCLS) ? logits[r*NCLS + j] : -3.4e38f;
  red[j] = lg;
  __syncthreads();
  for (int s = 64; s > 0; s >>= 1) {
    if (j < s) red[j] = fmaxf(red[j], red[j+s]);
    __syncthreads();
  }
  float mx = red[0];
  __syncthreads();
  float e = (j < NCLS) ? expf(lg - mx) : 0.f;
  red[j] = e;
  __syncthreads();
  for (int s = 64; s > 0; s >>= 1) {
    if (j < s) red[j] += red[j+s];
    __syncthreads();
  }
  float p = e / red[0];
  if (j >= 1 && j < NCLS) {
    float px1 = props[r*4+0], py1 = props[r*4+1];
    float px2 = props[r*4+2], py2 = props[r*4+3];
    float w = px2 - px1, h = py2 - py1;
    float cx = px1 + 0.5f*w, cy = py1 + 0.5f*h;
    float d0 = deltas[r*364 + j*4 + 0];
    float d1 = deltas[r*364 + j*4 + 1];
    float d2 = deltas[r*364 + j*4 + 2];
    float d3 = deltas[r*364 + j*4 + 3];
    float dx = d0 / 10.0f, dy = d1 / 10.0f;
    float dw = fminf(d2 / 5.0f, 4.135166556742356f);
    float dh = fminf(d3 / 5.0f, 4.135166556742356f);
    float pcx = dx*w + cx, pcy = dy*h + cy;
    float pw = expf(dw)*w, ph = expf(dh)*h;
    float bx1 = fminf(fmaxf(pcx - 0.5f*pw, 0.f), 1216.f);
    float by1 = fminf(fmaxf(pcy - 0.5f*ph, 0.f),  800.f);
    float bx2 = fminf(fmaxf(pcx + 0.5f*pw, 0.f), 1216.f);
    float by2 = fminf(fmaxf(pcy + 0.5f*ph, 0.f),  800.f);
    bool valid = (p > 0.05f) && ((bx2 - bx1) >= 0.01f) && ((by2 - by1) >= 0.01f);
    int b = r >> 8, n = r & 255;
    int cidx = n*90 + (j-1);
    size_t cb = (size_t)b*CAND + cidx;
    cboxes[cb*4+0] = bx1; cboxes[cb*4+1] = by1;
    cboxes[cb*4+2] = bx2; cboxes[cb*4+3] = by2;
    u64 key = 0ull;
    if (valid)
      key = (((u64)__float_as_uint(p)) << 32) | (u32)(~(u32)cidx);
    keys[cb] = key;
  }
}

// -------- per (batch,half): compact valid + bitonic sort desc, top1024 -----
#define SORTN 4096
__global__ __launch_bounds__(1024) void k_sort(const u64* __restrict__ keys,
                                               u64* __restrict__ sorted) {
  __shared__ u64 sk[SORTN];
  __shared__ int cnt;
  int t = threadIdx.x;
  int b = blockIdx.x >> 1, h = blockIdx.x & 1;
  if (t == 0) cnt = 0;
  __syncthreads();
  const u64* kb = keys + (size_t)b*CAND + (size_t)h*(CAND/2);
  for (int q = 0; q < 12; q++) {
    int idx = t + q*1024;
    if (idx < CAND/2) {
      u64 k = kb[idx];
      if (k) { int pos = atomicAdd(&cnt, 1); sk[pos] = k; }
    }
  }
  __syncthreads();
  int total = cnt;
  for (int s = t; s < SORTN; s += 1024)
    if (s >= total) sk[s] = 0ull;
  __syncthreads();
  for (int k = 2; k <= SORTN; k <<= 1) {
    for (int jj = k >> 1; jj > 0; jj >>= 1) {
      for (int i = t; i < SORTN; i += 1024) {
        int ixj = i ^ jj;
        if (ixj > i) {
          u64 a = sk[i], bb = sk[ixj];
          bool up = ((i & k) == 0);
          if (up ? (a < bb) : (a > bb)) { sk[i] = bb; sk[ixj] = a; }
        }
      }
      __syncthreads();
    }
  }
  sorted[((size_t)b*2 + h)*1024 + t] = sk[t];
}

// -------- per batch: merge halves, tiled greedy NMS, emit final 100 --------
__global__ __launch_bounds__(1024) void k_nms(const u64* __restrict__ sorted,
                                              const float* __restrict__ cboxes,
                                              float* __restrict__ out) {
  __shared__ u64 m[2048];
  __shared__ float sX1[1024], sY1[1024], sX2[1024], sY2[1024], sAR[1024];
  __shared__ int keepL[1024];
  __shared__ int wsum[16];
  int t = threadIdx.x;
  int b = blockIdx.x;
  m[t]        = sorted[((size_t)b*2 + 0)*1024 + t];
  m[2047 - t] = sorted[((size_t)b*2 + 1)*1024 + t];
  __syncthreads();
  for (int lg = 10; lg >= 0; lg--) {
    int jj = 1 << lg;
    int pos = ((t >> lg) << (lg+1)) + (t & (jj-1));
    u64 a = m[pos], bb = m[pos + jj];
    if (a < bb) { m[pos] = bb; m[pos + jj] = a; }
    __syncthreads();
  }
  u64 key = m[t];
  bool valid = key != 0ull;
  float score = __uint_as_float((u32)(key >> 32));
  u32 cidx = ~((u32)(key & 0xFFFFFFFFu));
  int label = valid ? (int)(cidx % 90u) + 1 : 0;
  float cb0 = 0.f, cb1 = 0.f, cb2 = 0.f, cb3 = 0.f;
  if (valid) {
    size_t cb = ((size_t)b*CAND + cidx) * 4;
    cb0 = cboxes[cb+0]; cb1 = cboxes[cb+1];
    cb2 = cboxes[cb+2]; cb3 = cboxes[cb+3];
  }
  float off = (float)label * 1218.0f;
  float ox1 = cb0 + off, oy1 = cb1 + off;
  float ox2 = cb2 + off, oy2 = cb3 + off;
  float area = (ox2 - ox1) * (oy2 - oy1);
  sX1[t] = ox1; sY1[t] = oy1; sX2[t] = ox2; sY2[t] = oy2; sAR[t] = area;
  keepL[t] = valid ? 1 : 0;
  __syncthreads();

  int wid = t >> 6, lane = t & 63;
  for (int tile = 0; tile < 16; tile++) {
    if (wid == 0) {
      int idx = tile*64 + lane;
      bool kp = keepL[idx] != 0;
      float bx1 = sX1[idx], by1 = sY1[idx], bx2 = sX2[idx], by2 = sY2[idx], ba = sAR[idx];
      u64 alive = __ballot(kp);
      #pragma unroll 1
      for (int i = 0; i < 63; i++) {
        if ((alive >> i) & 1ull) {
          int ii = tile*64 + i;
          float ltx = fmaxf(sX1[ii], bx1), lty = fmaxf(sY1[ii], by1);
          float rbx = fminf(sX2[ii], bx2), rby = fminf(sY2[ii], by2);
          float iw = fmaxf(rbx - ltx, 0.f), ih = fmaxf(rby - lty, 0.f);
          float inter = iw * ih;
          float iou = inter / (sAR[ii] + ba - inter + 1e-9f);
          if (lane > i && iou > 0.5f) kp = false;
        }
        alive = __ballot(kp);
      }
      keepL[idx] = kp ? 1 : 0;
    }
    __syncthreads();
    if (t >= (tile+1)*64) {
      bool kp = keepL[t] != 0;
      if (kp) {
        #pragma unroll 1
        for (int i = tile*64; i < tile*64 + 64; i++) {
          if (keepL[i]) {
            float ltx = fmaxf(sX1[i], ox1), lty = fmaxf(sY1[i], oy1);
            float rbx = fminf(sX2[i], ox2), rby = fminf(sY2[i], oy2);
            float iw = fmaxf(rbx - ltx, 0.f), ih = fmaxf(rby - lty, 0.f);
            float inter = iw * ih;
            float iou = inter / (sAR[i] + area - inter + 1e-9f);
            if (iou > 0.5f) { kp = false; }
          }
        }
        if (!kp) keepL[t] = 0;
      }
    }
    __syncthreads();
  }

  bool keep = keepL[t] != 0;
  u64 bal = __ballot(keep);
  int wpre = __popcll(bal & ((1ull << lane) - 1ull));
  if (lane == 0) wsum[wid] = __popcll(bal);
  __syncthreads();
  int offn = 0, KT = 0;
  for (int q = 0; q < 16; q++) {
    int v = wsum[q];
    if (q < wid) offn += v;
    KT += v;
  }
  int rank = offn + wpre;
  float* outB = out;
  float* outS = out + 1600;
  float* outL = out + 2000;
  if (keep && rank < 100) {
    size_t s = (size_t)b*100 + rank;
    outB[s*4+0] = cb0; outB[s*4+1] = cb1;
    outB[s*4+2] = cb2; outB[s*4+3] = cb3;
    outS[s] = score; outL[s] = (float)label;
  }
  if (t < 100 && t >= KT) {
    size_t s = (size_t)b*100 + t;
    outB[s*4+0] = 0.f; outB[s*4+1] = 0.f; outB[s*4+2] = 0.f; outB[s*4+3] = 0.f;
    outS[s] = 0.f; outL[s] = 0.f;
  }
}

extern "C" void kernel_launch(void* const* d_in, const int* in_sizes, int n_in,
                              void* d_out, int out_size, void* d_ws, size_t ws_size,
                              hipStream_t stream) {
  (void)in_sizes; (void)n_in; (void)out_size; (void)ws_size;
  const float* feat  = (const float*)d_in[0];
  const float* props = (const float*)d_in[1];
  const float* W6 = (const float*)d_in[2];
  const float* b6 = (const float*)d_in[3];
  const float* W7 = (const float*)d_in[4];
  const float* b7 = (const float*)d_in[5];
  const float* Wc = (const float*)d_in[6];
  const float* bc = (const float*)d_in[7];
  const float* Wb = (const float*)d_in[8];
  const float* bb = (const float*)d_in[9];
  float* out = (float*)d_out;
  char* ws = (char*)d_ws;

  // workspace (peak 113,639,424 B == proven budget):
  //   phase A: featT [0, 62.26MB) + Xs2 [62.26MB, 113.64MB)
  //   phase B (featT dead): part [0, 32MB) + everything else in [32MB, 50MB)
  float* featT  = (float*)(ws);                        // 62,259,200 B
  u16*   Xs2    = (u16*)  (ws + 62259200);             // 51,380,224 B (tiled)
  float* part   = (float*)(ws);                        // 33,554,432 B (8 slices)
  u16*   Y1s2   = (u16*)  (ws + 33554432);             //  4,194,304 B (tiled)
  u16*   Y2s2   = (u16*)  (ws + 37748736);             //  4,194,304 B (tiled)
  float* Wcat   = (float*)(ws + 41943040);             //  2,097,152 B
  float* bcat   = (float*)(ws + 44040192);             //      2,048 B
  float* logitsP= (float*)(ws + 44564480);             //    372,736 B
  float* deltasP= (float*)(ws + 45088768);             //  1,490,944 B
  float* cboxes = (float*)(ws + 46661632);             //  1,474,560 B
  u64*   keys   = (u64*)  (ws + 48234496);             //    737,280 B
  u64*   sorted = (u64*)  (ws + 49020928);             //     65,536 B

  dim3 gT(475, 8, 4);
  k_transpose<<<gT, 256, 0, stream>>>(feat, featT);
  k_roialign<<<1024, 256, 0, stream>>>(featT, props, Xs2);
  k_packW<<<2048, 256, 0, stream>>>(Wc, Wb, bc, bb, Wcat, bcat);

  // FC6: K=12544 (kg=1568), split-K=8, 49 steps/slice, 512 blocks (2/CU)
  k_gemm_f16<<<512, 256, 0, stream>>>(Xs2, W6, part, DIN/8, 49, 8, 1024, 1048576);
  k_reduce_split<<<512, 256, 0, stream>>>(part, b6, Y1s2);
  // FC7: K=1024 (kg=128), split-K=8, 4 steps/slice
  k_gemm_f16<<<512, 256, 0, stream>>>(Y1s2, W7, part, 128, 4, 8, 1024, 1048576);
  k_reduce_split<<<512, 256, 0, stream>>>(part, b7, Y2s2);
  // heads: M=1024, N=512(padded 455), K=1024, split-K=8, 256 blocks
  k_gemm_f16<<<256, 256, 0, stream>>>(Y2s2, Wcat, part, 128, 4, 4, 512, 524288);
  k_reduce_heads<<<2048, 256, 0, stream>>>(part, bcat, logitsP, deltasP);

  k_decode<<<1024, 128, 0, stream>>>(logitsP, deltasP, props, cboxes, keys);
  k_sort<<<8, 1024, 0, stream>>>(keys, sorted);
  k_nms<<<4, 1024, 0, stream>>>(sorted, cboxes, out);
}

// Round 6
// 374.579 us; speedup vs baseline: 3.0005x; 1.0080x over previous
//
#include <hip/hip_runtime.h>
#include <hip/hip_bf16.h>
#include <stdint.h>

#define B_    4
#define N_    256
#define C_    256
#define FH_   100
#define FW_   152
#define P_HW  (FH_*FW_)      // 15200
#define NCLS  91
#define CAND  23040          // N_*90
#define DIN   12544
#define PRE   1024

typedef unsigned long long u64;
typedef unsigned int u32;
typedef unsigned short u16;
typedef __attribute__((ext_vector_type(8))) _Float16 half8;
typedef __attribute__((ext_vector_type(8))) short short8;
typedef __attribute__((ext_vector_type(4))) float f32x4;

__device__ inline u16 h2bits(_Float16 h) { return *reinterpret_cast<u16*>(&h); }

// split v (already prescaled) into fp16 h0 + h1, exact-residual style
__device__ inline void split2(float v, u16& b0, u16& b1) {
  _Float16 h0 = (_Float16)v;
  float r = v - (float)h0;
  _Float16 h1 = (_Float16)r;
  b0 = h2bits(h0); b1 = h2bits(h1);
}

__device__ inline void gload_lds16(const void* g, void* l) {
  __builtin_amdgcn_global_load_lds(
      (const __attribute__((address_space(1))) void*)g,
      (__attribute__((address_space(3))) void*)l, 16, 0, 0);
}

// ---------------- feature transpose (B,C,H,W) -> (B,H,W,C) ----------------
__global__ void k_transpose(const float* __restrict__ in, float* __restrict__ out) {
  __shared__ float t[32][33];
  int b  = blockIdx.z;
  int c0 = blockIdx.y * 32;
  int p0 = blockIdx.x * 32;
  int tx = threadIdx.x & 31, ty = threadIdx.x >> 5;
  const float* inb = in  + (size_t)b * C_ * P_HW;
  float*       ob  = out + (size_t)b * P_HW * C_;
  #pragma unroll
  for (int q = 0; q < 4; q++)
    t[ty + q*8][tx] = inb[(size_t)(c0 + ty + q*8) * P_HW + p0 + tx];
  __syncthreads();
  #pragma unroll
  for (int q = 0; q < 4; q++)
    ob[(size_t)(p0 + ty + q*8) * C_ + c0 + tx] = t[tx][ty + q*8];
}

// ------- roi align -> Xt [2 planes][DIN/8][1024 rows][8] fp16 of (X*16) ----
// blockIdx remapped so each XCD (blockIdx%8) serves ONE batch (2 XCDs/batch):
// per-XCD feature working set 15.5MB instead of 62MB -> better L2/L3 behavior.
__global__ __launch_bounds__(256) void k_roialign(const float* __restrict__ featT,
                                                  const float* __restrict__ props,
                                                  u16* __restrict__ Xs) {
  __shared__ float cellv[49*256];
  int bid = blockIdx.x;
  int xcd = bid & 7;
  int b = xcd >> 1;
  int n = ((bid >> 3) << 1) | (xcd & 1);
  int r = (b << 8) | n;                 // bijective 0..1023
  int c = threadIdx.x;
  float x1 = props[r*4+0], y1 = props[r*4+1];
  float x2 = props[r*4+2], y2 = props[r*4+3];
  float x1s = x1 * 0.125f, y1s = y1 * 0.125f;
  float x2s = x2 * 0.125f, y2s = y2 * 0.125f;
  float rw = fmaxf(x2s - x1s, 1.0f);
  float rh = fmaxf(y2s - y1s, 1.0f);
  float rwd = rw / 7.0f, rhd = rh / 7.0f;
  const float* fb = featT + (size_t)b * P_HW * C_ + c;
  for (int py = 0; py < 7; py++) {
    for (int px = 0; px < 7; px++) {
      float acc = 0.f;
      #pragma unroll
      for (int s = 0; s < 4; s++) {
        int sy = s >> 1, sx = s & 1;
        float gqy = (float)py + 0.25f + 0.5f * (float)sy;
        float gqx = (float)px + 0.25f + 0.5f * (float)sx;
        float gy = fminf(fmaxf(y1s + rhd * gqy, 0.0f), 99.0f);
        float gx = fminf(fmaxf(x1s + rwd * gqx, 0.0f), 151.0f);
        float y0f = floorf(gy), x0f = floorf(gx);
        float ly = gy - y0f, lx = gx - x0f;
        int y0i = (int)y0f;
        int y1i = (int)fminf(y0f + 1.0f, 99.0f);
        int x0i = (int)x0f;
        int x1i = (int)fminf(x0f + 1.0f, 151.0f);
        float v00 = fb[((size_t)(y0i * FW_ + x0i)) * C_];
        float v01 = fb[((size_t)(y0i * FW_ + x1i)) * C_];
        float v10 = fb[((size_t)(y1i * FW_ + x0i)) * C_];
        float v11 = fb[((size_t)(y1i * FW_ + x1i)) * C_];
        acc += (1.f-ly)*(1.f-lx)*v00 + (1.f-ly)*lx*v01
             + ly*(1.f-lx)*v10 + ly*lx*v11;
      }
      cellv[(py*7+px)*256 + c] = acc * 4.0f;   // 0.25 (avg) * 16 (prescale)
    }
  }
  __syncthreads();
  const int KG = DIN/8;                       // 1568 chunk-groups
  const size_t PLS = (size_t)KG * 1024 * 8;   // plane stride in elems
  for (int it = 0; it < 7; it++) {
    int cg = threadIdx.x + it*256;
    if (cg < KG) {
      int k0 = cg * 8;
      short8 v0, v1;
      #pragma unroll
      for (int e = 0; e < 8; e++) {
        int k = k0 + e;
        int ch = k / 49;
        int cell = k - ch*49;
        float v = cellv[cell*256 + ch];
        u16 h0, h1;
        split2(v, h0, h1);
        v0[e] = (short)h0; v1[e] = (short)h1;
      }
      size_t base = ((size_t)cg * 1024 + r) * 8;
      *reinterpret_cast<short8*>(Xs + base)       = v0;
      *reinterpret_cast<short8*>(Xs + PLS + base) = v1;
    }
  }
}

// -------- MFMA GEMM, fp32 via fp16 2-plane exact 4-pass, 128x128 tile ------
// Double-buffered LDS pipeline (T3-min 2-phase, counted vmcnt):
//   STAGE(next) -> vmcnt(8) -> barrier -> compute(cur) -> lgkmcnt(0) -> barrier
// As: tiled [2][kg][1024][8] fp16 of (A*16). Bw: [K][outw] fp32 (x128 split
// in-kernel). part: [8][1024][outw] fp32 partials of (A@B)*2048.
__global__ __launch_bounds__(256) void k_gemm_f16(
    const u16* __restrict__ As, const float* __restrict__ Bw,
    float* __restrict__ part, int kg, int nsteps, int outw,
    size_t sstride) {
  __shared__ __align__(16) char lds[65536];   // 2 x (A 16KB + B 16KB)
  int tid = threadIdx.x;
  int wid = tid >> 6, lane = tid & 63;
  int l15 = lane & 15, lq = lane >> 4;
  int bid = blockIdx.x;
  int z = bid & 7, xy = bid >> 3;              // one K-slice per XCD
  int col0 = (xy & 7) * 128, row0 = (xy >> 3) * 128;
  int wr = wid >> 1, wc = wid & 1;             // 4 waves: 2x2, wave tile 64x64
  int kbase0 = z * nsteps * 32;

  // stage tile for step s into buffer bsel (8 gload_lds16 per thread)
  auto STAGE = [&](int s, int bsel) {
    int kb = kbase0 + s * 32;
    char* dst = lds + bsel * 32768;
    #pragma unroll
    for (int j = 0; j < 8; j++) {
      int cid = tid + j*256;
      const char* src;
      if (j < 4) {
        int pl = cid >> 9;
        int kc = (cid >> 7) & 3, rr = cid & 127;
        src = (const char*)(As + ((size_t)(pl*kg + (kb>>3) + kc)*1024 + row0 + rr)*8);
      } else {
        int cid2 = cid - 1024;
        int kk = cid2 >> 5, c4 = cid2 & 31;
        int col = (c4*4) ^ (((kk >> 3) & 1) << 4);
        src = (const char*)(Bw + (size_t)(kb + kk)*outw + col0 + col);
      }
      gload_lds16(src, dst + (size_t)cid*16);
    }
  };

  f32x4 acc[4][4];
  #pragma unroll
  for (int i = 0; i < 4; i++)
    #pragma unroll
    for (int j = 0; j < 4; j++)
      #pragma unroll
      for (int q = 0; q < 4; q++) acc[i][j][q] = 0.f;

  STAGE(0, 0);
  for (int s = 0; s < nsteps; s++) {
    int cur = s & 1;
    if (s + 1 < nsteps) {
      STAGE(s + 1, cur ^ 1);
      asm volatile("s_waitcnt vmcnt(8)" ::: "memory");   // cur buf complete
    } else {
      asm volatile("s_waitcnt vmcnt(0)" ::: "memory");
    }
    __builtin_amdgcn_s_barrier();
    __builtin_amdgcn_sched_barrier(0);   // no LDS reads above the barrier

    const u16*   Alds = (const u16*)(lds + cur * 32768);
    const float* Blds = (const float*)(lds + cur * 32768 + 16384);

    half8 af[2][4];
    #pragma unroll
    for (int pl = 0; pl < 2; pl++)
      #pragma unroll
      for (int fr = 0; fr < 4; fr++) {
        int chunk = (pl*4 + lq)*128 + wr*64 + fr*16 + l15;
        af[pl][fr] = *reinterpret_cast<const half8*>(&Alds[(size_t)chunk*8]);
      }
    int cxor = (lq & 1) << 4;
    #pragma unroll
    for (int fc = 0; fc < 4; fc++) {
      int colx = (wc*64 + fc*16 + l15) ^ cxor;
      half8 b0, b1;
      #pragma unroll
      for (int j = 0; j < 8; j++) {
        float w = Blds[(lq*8 + j)*128 + colx] * 128.0f;
        _Float16 h0 = (_Float16)w;
        float rres = w - (float)h0;
        b0[j] = h0; b1[j] = (_Float16)rres;
      }
      #pragma unroll
      for (int fr = 0; fr < 4; fr++) {
        acc[fr][fc] = __builtin_amdgcn_mfma_f32_16x16x32_f16(af[0][fr], b0, acc[fr][fc], 0, 0, 0);
        acc[fr][fc] = __builtin_amdgcn_mfma_f32_16x16x32_f16(af[1][fr], b0, acc[fr][fc], 0, 0, 0);
        acc[fr][fc] = __builtin_amdgcn_mfma_f32_16x16x32_f16(af[0][fr], b1, acc[fr][fc], 0, 0, 0);
        acc[fr][fc] = __builtin_amdgcn_mfma_f32_16x16x32_f16(af[1][fr], b1, acc[fr][fc], 0, 0, 0);
      }
    }
    // all LDS reads of cur buf must complete before next STAGE overwrites it
    __builtin_amdgcn_sched_barrier(0);
    asm volatile("s_waitcnt lgkmcnt(0)" ::: "memory");
    __builtin_amdgcn_s_barrier();
  }

  float* pp = part + (size_t)z * sstride;
  #pragma unroll
  for (int fr = 0; fr < 4; fr++)
    #pragma unroll
    for (int fc = 0; fc < 4; fc++) {
      int col = col0 + wc*64 + fc*16 + l15;
      #pragma unroll
      for (int rr = 0; rr < 4; rr++) {
        int row = row0 + wr*64 + fr*16 + lq*4 + rr;
        pp[(size_t)row*outw + col] = acc[fr][fc][rr];
      }
    }
}

// -------- reduce split-K -> tiled fp16 planes (coalesced reads) ------------
__global__ void k_reduce_split(const float* __restrict__ part,
                               const float* __restrict__ bias,
                               u16* __restrict__ ys) {
  int idx = blockIdx.x * 256 + threadIdx.x;   // 131072 = 1024 rows * 128 cg
  int row = idx >> 7, cg = idx & 127;
  float4 s0 = {0,0,0,0}, s1 = {0,0,0,0};
  #pragma unroll
  for (int s = 0; s < 8; s++) {
    const float4* p = (const float4*)(part + (size_t)s*1048576 + (size_t)row*1024 + cg*8);
    float4 a = p[0], b = p[1];
    s0.x += a.x; s0.y += a.y; s0.z += a.z; s0.w += a.w;
    s1.x += b.x; s1.y += b.y; s1.z += b.z; s1.w += b.w;
  }
  float v[8] = {s0.x, s0.y, s0.z, s0.w, s1.x, s1.y, s1.z, s1.w};
  short8 o0, o1;
  #pragma unroll
  for (int e = 0; e < 8; e++) {
    float x = v[e] * (1.0f/2048.0f) + bias[cg*8 + e];
    x = fmaxf(x, 0.f) * 16.0f;                // prescale for next layer
    u16 h0, h1;
    split2(x, h0, h1);
    o0[e] = (short)h0; o1[e] = (short)h1;
  }
  size_t base = ((size_t)cg * 1024 + row) * 8;   // kg = 128 for K=1024
  *reinterpret_cast<short8*>(ys + base)               = o0;
  *reinterpret_cast<short8*>(ys + (size_t)1048576 + base) = o1;
}

// -------- pack Wc|Wb -> Wcat [1024][512] fp32 (pad 455..511 = 0), bcat -----
__global__ void k_packW(const float* __restrict__ Wc, const float* __restrict__ Wb,
                        const float* __restrict__ bc, const float* __restrict__ bb,
                        float* __restrict__ Wcat, float* __restrict__ bcat) {
  int idx = blockIdx.x * 256 + threadIdx.x;   // 524288
  int k = idx >> 9, col = idx & 511;
  float v = 0.f;
  if (col < 91)       v = Wc[(size_t)k*91 + col];
  else if (col < 455) v = Wb[(size_t)k*364 + (col - 91)];
  Wcat[idx] = v;
  if (idx < 512) {
    float bv = 0.f;
    if (idx < 91)       bv = bc[idx];
    else if (idx < 455) bv = bb[idx - 91];
    bcat[idx] = bv;
  }
}

// -------- heads reduce: sum 8 slices, +bcat, scatter to logits/deltas ------
__global__ void k_reduce_heads(const float* __restrict__ part,
                               const float* __restrict__ bcat,
                               float* __restrict__ logits,
                               float* __restrict__ deltas) {
  int idx = blockIdx.x * 256 + threadIdx.x;   // 524288 = 1024 * 512
  int row = idx >> 9, col = idx & 511;
  float v = 0.f;
  #pragma unroll
  for (int s = 0; s < 8; s++) v += part[idx + (size_t)s*524288];
  v = v * (1.0f/2048.0f) + bcat[col];
  if (col < 91)       logits[(size_t)row*91 + col] = v;
  else if (col < 455) deltas[(size_t)row*364 + (col - 91)] = v;
}

// -------- softmax + box decode + candidate keys ----------------------------
__global__ void k_decode(const float* __restrict__ logits,
                         const float* __restrict__ deltas,
                         const float* __restrict__ props,
                         float* __restrict__ cboxes,
                         u64* __restrict__ keys) {
  int r = blockIdx.x;
  int j = threadIdx.x;   // 128
  __shared__ float red[128];
  float lg = (j < NCLS) ? logits[r*NCLS + j] : -3.4e38f;
  red[j] = lg;
  __syncthreads();
  for (int s = 64; s > 0; s >>= 1) {
    if (j < s) red[j] = fmaxf(red[j], red[j+s]);
    __syncthreads();
  }
  float mx = red[0];
  __syncthreads();
  float e = (j < NCLS) ? expf(lg - mx) : 0.f;
  red[j] = e;
  __syncthreads();
  for (int s = 64; s > 0; s >>= 1) {
    if (j < s) red[j] += red[j+s];
    __syncthreads();
  }
  float p = e / red[0];
  if (j >= 1 && j < NCLS) {
    float px1 = props[r*4+0], py1 = props[r*4+1];
    float px2 = props[r*4+2], py2 = props[r*4+3];
    float w = px2 - px1, h = py2 - py1;
    float cx = px1 + 0.5f*w, cy = py1 + 0.5f*h;
    float d0 = deltas[r*364 + j*4 + 0];
    float d1 = deltas[r*364 + j*4 + 1];
    float d2 = deltas[r*364 + j*4 + 2];
    float d3 = deltas[r*364 + j*4 + 3];
    float dx = d0 / 10.0f, dy = d1 / 10.0f;
    float dw = fminf(d2 / 5.0f, 4.135166556742356f);
    float dh = fminf(d3 / 5.0f, 4.135166556742356f);
    float pcx = dx*w + cx, pcy = dy*h + cy;
    float pw = expf(dw)*w, ph = expf(dh)*h;
    float bx1 = fminf(fmaxf(pcx - 0.5f*pw, 0.f), 1216.f);
    float by1 = fminf(fmaxf(pcy - 0.5f*ph, 0.f),  800.f);
    float bx2 = fminf(fmaxf(pcx + 0.5f*pw, 0.f), 1216.f);
    float by2 = fminf(fmaxf(pcy + 0.5f*ph, 0.f),  800.f);
    bool valid = (p > 0.05f) && ((bx2 - bx1) >= 0.01f) && ((by2 - by1) >= 0.01f);
    int b = r >> 8, n = r & 255;
    int cidx = n*90 + (j-1);
    size_t cb = (size_t)b*CAND + cidx;
    cboxes[cb*4+0] = bx1; cboxes[cb*4+1] = by1;
    cboxes[cb*4+2] = bx2; cboxes[cb*4+3] = by2;
    u64 key = 0ull;
    if (valid)
      key = (((u64)__float_as_uint(p)) << 32) | (u32)(~(u32)cidx);
    keys[cb] = key;
  }
}

// -------- per (batch,half): compact valid + bitonic sort desc, top1024 -----
#define SORTN 4096
__global__ __launch_bounds__(1024) void k_sort(const u64* __restrict__ keys,
                                               u64* __restrict__ sorted) {
  __shared__ u64 sk[SORTN];
  __shared__ int cnt;
  int t = threadIdx.x;
  int b = blockIdx.x >> 1, h = blockIdx.x & 1;
  if (t == 0) cnt = 0;
  __syncthreads();
  const u64* kb = keys + (size_t)b*CAND + (size_t)h*(CAND/2);
  for (int q = 0; q < 12; q++) {
    int idx = t + q*1024;
    if (idx < CAND/2) {
      u64 k = kb[idx];
      if (k) { int pos = atomicAdd(&cnt, 1); sk[pos] = k; }
    }
  }
  __syncthreads();
  int total = cnt;
  for (int s = t; s < SORTN; s += 1024)
    if (s >= total) sk[s] = 0ull;
  __syncthreads();
  for (int k = 2; k <= SORTN; k <<= 1) {
    for (int jj = k >> 1; jj > 0; jj >>= 1) {
      for (int i = t; i < SORTN; i += 1024) {
        int ixj = i ^ jj;
        if (ixj > i) {
          u64 a = sk[i], bb = sk[ixj];
          bool up = ((i & k) == 0);
          if (up ? (a < bb) : (a > bb)) { sk[i] = bb; sk[ixj] = a; }
        }
      }
      __syncthreads();
    }
  }
  sorted[((size_t)b*2 + h)*1024 + t] = sk[t];
}

// -------- per batch: merge halves, tiled greedy NMS, emit final 100 --------
__global__ __launch_bounds__(1024) void k_nms(const u64* __restrict__ sorted,
                                              const float* __restrict__ cboxes,
                                              float* __restrict__ out) {
  __shared__ u64 m[2048];
  __shared__ float sX1[1024], sY1[1024], sX2[1024], sY2[1024], sAR[1024];
  __shared__ int keepL[1024];
  __shared__ int wsum[16];
  int t = threadIdx.x;
  int b = blockIdx.x;
  m[t]        = sorted[((size_t)b*2 + 0)*1024 + t];
  m[2047 - t] = sorted[((size_t)b*2 + 1)*1024 + t];
  __syncthreads();
  for (int lg = 10; lg >= 0; lg--) {
    int jj = 1 << lg;
    int pos = ((t >> lg) << (lg+1)) + (t & (jj-1));
    u64 a = m[pos], bb = m[pos + jj];
    if (a < bb) { m[pos] = bb; m[pos + jj] = a; }
    __syncthreads();
  }
  u64 key = m[t];
  bool valid = key != 0ull;
  float score = __uint_as_float((u32)(key >> 32));
  u32 cidx = ~((u32)(key & 0xFFFFFFFFu));
  int label = valid ? (int)(cidx % 90u) + 1 : 0;
  float cb0 = 0.f, cb1 = 0.f, cb2 = 0.f, cb3 = 0.f;
  if (valid) {
    size_t cb = ((size_t)b*CAND + cidx) * 4;
    cb0 = cboxes[cb+0]; cb1 = cboxes[cb+1];
    cb2 = cboxes[cb+2]; cb3 = cboxes[cb+3];
  }
  float off = (float)label * 1218.0f;
  float ox1 = cb0 + off, oy1 = cb1 + off;
  float ox2 = cb2 + off, oy2 = cb3 + off;
  float area = (ox2 - ox1) * (oy2 - oy1);
  sX1[t] = ox1; sY1[t] = oy1; sX2[t] = ox2; sY2[t] = oy2; sAR[t] = area;
  keepL[t] = valid ? 1 : 0;
  __syncthreads();

  int wid = t >> 6, lane = t & 63;
  for (int tile = 0; tile < 16; tile++) {
    if (wid == 0) {
      int idx = tile*64 + lane;
      bool kp = keepL[idx] != 0;
      float bx1 = sX1[idx], by1 = sY1[idx], bx2 = sX2[idx], by2 = sY2[idx], ba = sAR[idx];
      u64 alive = __ballot(kp);
      #pragma unroll 1
      for (int i = 0; i < 63; i++) {
        if ((alive >> i) & 1ull) {
          int ii = tile*64 + i;
          float ltx = fmaxf(sX1[ii], bx1), lty = fmaxf(sY1[ii], by1);
          float rbx = fminf(sX2[ii], bx2), rby = fminf(sY2[ii], by2);
          float iw = fmaxf(rbx - ltx, 0.f), ih = fmaxf(rby - lty, 0.f);
          float inter = iw * ih;
          float iou = inter / (sAR[ii] + ba - inter + 1e-9f);
          if (lane > i && iou > 0.5f) kp = false;
        }
        alive = __ballot(kp);
      }
      keepL[idx] = kp ? 1 : 0;
    }
    __syncthreads();
    if (t >= (tile+1)*64) {
      bool kp = keepL[t] != 0;
      if (kp) {
        #pragma unroll 1
        for (int i = tile*64; i < tile*64 + 64; i++) {
          if (keepL[i]) {
            float ltx = fmaxf(sX1[i], ox1), lty = fmaxf(sY1[i], oy1);
            float rbx = fminf(sX2[i], ox2), rby = fminf(sY2[i], oy2);
            float iw = fmaxf(rbx - ltx, 0.f), ih = fmaxf(rby - lty, 0.f);
            float inter = iw * ih;
            float iou = inter / (sAR[i] + area - inter + 1e-9f);
            if (iou > 0.5f) { kp = false; }
          }
        }
        if (!kp) keepL[t] = 0;
      }
    }
    __syncthreads();
  }

  bool keep = keepL[t] != 0;
  u64 bal = __ballot(keep);
  int wpre = __popcll(bal & ((1ull << lane) - 1ull));
  if (lane == 0) wsum[wid] = __popcll(bal);
  __syncthreads();
  int offn = 0, KT = 0;
  for (int q = 0; q < 16; q++) {
    int v = wsum[q];
    if (q < wid) offn += v;
    KT += v;
  }
  int rank = offn + wpre;
  float* outB = out;
  float* outS = out + 1600;
  float* outL = out + 2000;
  if (keep && rank < 100) {
    size_t s = (size_t)b*100 + rank;
    outB[s*4+0] = cb0; outB[s*4+1] = cb1;
    outB[s*4+2] = cb2; outB[s*4+3] = cb3;
    outS[s] = score; outL[s] = (float)label;
  }
  if (t < 100 && t >= KT) {
    size_t s = (size_t)b*100 + t;
    outB[s*4+0] = 0.f; outB[s*4+1] = 0.f; outB[s*4+2] = 0.f; outB[s*4+3] = 0.f;
    outS[s] = 0.f; outL[s] = 0.f;
  }
}

extern "C" void kernel_launch(void* const* d_in, const int* in_sizes, int n_in,
                              void* d_out, int out_size, void* d_ws, size_t ws_size,
                              hipStream_t stream) {
  (void)in_sizes; (void)n_in; (void)out_size; (void)ws_size;
  const float* feat  = (const float*)d_in[0];
  const float* props = (const float*)d_in[1];
  const float* W6 = (const float*)d_in[2];
  const float* b6 = (const float*)d_in[3];
  const float* W7 = (const float*)d_in[4];
  const float* b7 = (const float*)d_in[5];
  const float* Wc = (const float*)d_in[6];
  const float* bc = (const float*)d_in[7];
  const float* Wb = (const float*)d_in[8];
  const float* bb = (const float*)d_in[9];
  float* out = (float*)d_out;
  char* ws = (char*)d_ws;

  // workspace (peak 113,639,424 B == proven budget):
  //   phase A: featT [0, 62.26MB) + Xs2 [62.26MB, 113.64MB)
  //   phase B (featT dead): part [0, 32MB) + everything else in [32MB, 50MB)
  float* featT  = (float*)(ws);                        // 62,259,200 B
  u16*   Xs2    = (u16*)  (ws + 62259200);             // 51,380,224 B (tiled)
  float* part   = (float*)(ws);                        // 33,554,432 B (8 slices)
  u16*   Y1s2   = (u16*)  (ws + 33554432);             //  4,194,304 B (tiled)
  u16*   Y2s2   = (u16*)  (ws + 37748736);             //  4,194,304 B (tiled)
  float* Wcat   = (float*)(ws + 41943040);             //  2,097,152 B
  float* bcat   = (float*)(ws + 44040192);             //      2,048 B
  float* logitsP= (float*)(ws + 44564480);             //    372,736 B
  float* deltasP= (float*)(ws + 45088768);             //  1,490,944 B
  float* cboxes = (float*)(ws + 46661632);             //  1,474,560 B
  u64*   keys   = (u64*)  (ws + 48234496);             //    737,280 B
  u64*   sorted = (u64*)  (ws + 49020928);             //     65,536 B

  dim3 gT(475, 8, 4);
  k_transpose<<<gT, 256, 0, stream>>>(feat, featT);
  k_roialign<<<1024, 256, 0, stream>>>(featT, props, Xs2);
  k_packW<<<2048, 256, 0, stream>>>(Wc, Wb, bc, bb, Wcat, bcat);

  // FC6: K=12544 (kg=1568), split-K=8, 49 steps/slice, 512 blocks (2/CU)
  k_gemm_f16<<<512, 256, 0, stream>>>(Xs2, W6, part, DIN/8, 49, 1024, 1048576);
  k_reduce_split<<<512, 256, 0, stream>>>(part, b6, Y1s2);
  // FC7: K=1024 (kg=128), split-K=8, 4 steps/slice
  k_gemm_f16<<<512, 256, 0, stream>>>(Y1s2, W7, part, 128, 4, 1024, 1048576);
  k_reduce_split<<<512, 256, 0, stream>>>(part, b7, Y2s2);
  // heads: M=1024, N=512(padded 455), K=1024, split-K=8, 256 blocks
  k_gemm_f16<<<256, 256, 0, stream>>>(Y2s2, Wcat, part, 128, 4, 512, 524288);
  k_reduce_heads<<<2048, 256, 0, stream>>>(part, bcat, logitsP, deltasP);

  k_decode<<<1024, 128, 0, stream>>>(logitsP, deltasP, props, cboxes, keys);
  k_sort<<<8, 1024, 0, stream>>>(keys, sorted);
  k_nms<<<4, 1024, 0, stream>>>(sorted, cboxes, out);
}

// Round 7
// 360.635 us; speedup vs baseline: 3.1165x; 1.0387x over previous
//
#include <hip/hip_runtime.h>
#include <hip/hip_bf16.h>
#include <stdint.h>

#define B_    4
#define N_    256
#define C_    256
#define FH_   100
#define FW_   152
#define P_HW  (FH_*FW_)      // 15200
#define NCLS  91
#define CAND  23040          // N_*90
#define DIN   12544
#define PRE   1024

typedef unsigned long long u64;
typedef unsigned int u32;
typedef unsigned short u16;
typedef __attribute__((ext_vector_type(8))) _Float16 half8;
typedef __attribute__((ext_vector_type(8))) short short8;
typedef __attribute__((ext_vector_type(4))) float f32x4;

__device__ inline u16 h2bits(_Float16 h) { return *reinterpret_cast<u16*>(&h); }

// split v (already prescaled) into fp16 h0 + h1, exact-residual style
__device__ inline void split2(float v, u16& b0, u16& b1) {
  _Float16 h0 = (_Float16)v;
  float r = v - (float)h0;
  _Float16 h1 = (_Float16)r;
  b0 = h2bits(h0); b1 = h2bits(h1);
}

__device__ inline void gload_lds16(const void* g, void* l) {
  __builtin_amdgcn_global_load_lds(
      (const __attribute__((address_space(1))) void*)g,
      (__attribute__((address_space(3))) void*)l, 16, 0, 0);
}

// ---------------- feature transpose (B,C,H,W) -> (B,H,W,C) ----------------
__global__ void k_transpose(const float* __restrict__ in, float* __restrict__ out) {
  __shared__ float t[32][33];
  int b  = blockIdx.z;
  int c0 = blockIdx.y * 32;
  int p0 = blockIdx.x * 32;
  int tx = threadIdx.x & 31, ty = threadIdx.x >> 5;
  const float* inb = in  + (size_t)b * C_ * P_HW;
  float*       ob  = out + (size_t)b * P_HW * C_;
  #pragma unroll
  for (int q = 0; q < 4; q++)
    t[ty + q*8][tx] = inb[(size_t)(c0 + ty + q*8) * P_HW + p0 + tx];
  __syncthreads();
  #pragma unroll
  for (int q = 0; q < 4; q++)
    ob[(size_t)(p0 + ty + q*8) * C_ + c0 + tx] = t[tx][ty + q*8];
}

// ------- roi align -> Xt [2 planes][DIN/8][1024 rows][8] fp16 of (X*16) ----
// Low-LDS restructure: geometry (4 corner offsets + 4 weights per sample)
// precomputed once into LDS; channels processed in 8 groups of 32 so the
// staging buffer is 32x51 floats. LDS ~13KB -> up to 8 blocks/CU of gather TLP.
__global__ __launch_bounds__(256, 8) void k_roialign(const float* __restrict__ featT,
                                                     const float* __restrict__ props,
                                                     u16* __restrict__ Xs) {
  __shared__ float sPW[196][8];     // {p00,p01,p10,p11,w00,w01,w10,w11} as bits
  __shared__ float cellv[32][51];   // [ch-in-group][cell], stride 51 (coprime 32)
  int bid = blockIdx.x;
  int xcd = bid & 7;
  int b = xcd >> 1;
  int n = ((bid >> 3) << 1) | (xcd & 1);
  int r = (b << 8) | n;                 // bijective 0..1023, XCD-batch affine
  int tid = threadIdx.x;

  float x1 = props[r*4+0], y1 = props[r*4+1];
  float x2 = props[r*4+2], y2 = props[r*4+3];
  float x1s = x1 * 0.125f, y1s = y1 * 0.125f;
  float x2s = x2 * 0.125f, y2s = y2 * 0.125f;
  float rw = fmaxf(x2s - x1s, 1.0f);
  float rh = fmaxf(y2s - y1s, 1.0f);
  float rwd = rw / 7.0f, rhd = rh / 7.0f;

  // phase 0: precompute geometry for 196 (cell,sample) pairs
  if (tid < 196) {
    int cell = tid >> 2, s = tid & 3;
    int py = cell / 7, px = cell % 7;
    int sy = s >> 1, sx = s & 1;
    float gqy = (float)py + 0.25f + 0.5f * (float)sy;
    float gqx = (float)px + 0.25f + 0.5f * (float)sx;
    float gy = fminf(fmaxf(y1s + rhd * gqy, 0.0f), 99.0f);
    float gx = fminf(fmaxf(x1s + rwd * gqx, 0.0f), 151.0f);
    float y0f = floorf(gy), x0f = floorf(gx);
    float ly = gy - y0f, lx = gx - x0f;
    int y0i = (int)y0f;
    int y1i = (int)fminf(y0f + 1.0f, 99.0f);
    int x0i = (int)x0f;
    int x1i = (int)fminf(x0f + 1.0f, 151.0f);
    sPW[tid][0] = __int_as_float((y0i * FW_ + x0i) * 256);
    sPW[tid][1] = __int_as_float((y0i * FW_ + x1i) * 256);
    sPW[tid][2] = __int_as_float((y1i * FW_ + x0i) * 256);
    sPW[tid][3] = __int_as_float((y1i * FW_ + x1i) * 256);
    sPW[tid][4] = (1.f-ly)*(1.f-lx);
    sPW[tid][5] = (1.f-ly)*lx;
    sPW[tid][6] = ly*(1.f-lx);
    sPW[tid][7] = ly*lx;
  }
  __syncthreads();

  int c32 = tid & 31;        // channel within group
  int slot = tid >> 5;       // 0..7 cell stride
  const size_t PLS = (size_t)(DIN/8) * 1024 * 8;   // plane stride in elems

  for (int g = 0; g < 8; g++) {
    const float* fb = featT + (size_t)b * P_HW * C_ + g*32 + c32;
    for (int cell = slot; cell < 49; cell += 8) {
      float acc = 0.f;
      #pragma unroll
      for (int s = 0; s < 4; s++) {
        int cs = cell*4 + s;
        float4 pv = *(const float4*)&sPW[cs][0];
        float4 wv = *(const float4*)&sPW[cs][4];
        acc += wv.x * fb[__float_as_int(pv.x)]
             + wv.y * fb[__float_as_int(pv.y)]
             + wv.z * fb[__float_as_int(pv.z)]
             + wv.w * fb[__float_as_int(pv.w)];
      }
      cellv[c32][cell] = acc * 4.0f;   // 0.25 (avg) * 16 (prescale)
    }
    __syncthreads();
    // emit 196 chunks for this group's k-range [g*1568, (g+1)*1568)
    if (tid < 196) {
      short8 v0, v1;
      #pragma unroll
      for (int e = 0; e < 8; e++) {
        int kl = tid*8 + e;            // local k in [0,1568)
        int chl = kl / 49;
        int cell = kl - chl*49;
        float v = cellv[chl][cell];
        u16 h0, h1;
        split2(v, h0, h1);
        v0[e] = (short)h0; v1[e] = (short)h1;
      }
      size_t cg = (size_t)g*196 + tid;
      size_t base = (cg * 1024 + r) * 8;
      *reinterpret_cast<short8*>(Xs + base)       = v0;
      *reinterpret_cast<short8*>(Xs + PLS + base) = v1;
    }
    __syncthreads();
  }
}

// -------- MFMA GEMM, fp32 via fp16 2-plane exact 4-pass, 128x128 tile ------
// 8 waves (512 thr) per tile -> 4 waves/SIMD at 2 blocks/CU for overlap.
// Double-buffered LDS, counted vmcnt(4).
// As: tiled [2][kg][1024][8] fp16 of (A*16). Bw: [K][outw] fp32 (x128 split
// in-kernel). part: [8][M][outw] fp32 partials of (A@B)*2048.
__global__ __launch_bounds__(512) void k_gemm_f16(
    const u16* __restrict__ As, const float* __restrict__ Bw,
    float* __restrict__ part, int kg, int nsteps, int nct, int outw,
    size_t sstride) {
  __shared__ __align__(16) char lds[65536];   // 2 x (A 16KB + B 16KB)
  int tid = threadIdx.x;
  int wid = tid >> 6, lane = tid & 63;
  int l15 = lane & 15, lq = lane >> 4;
  int bid = blockIdx.x;
  int z = bid & 7, xy = bid >> 3;              // one K-slice per XCD
  int col0 = (xy % nct) * 128, row0 = (xy / nct) * 128;
  int wr = wid >> 2, wc = wid & 3;             // 8 waves: 2 row x 4 col, 64x32
  int kbase0 = z * nsteps * 32;

  auto STAGE = [&](int s, int bsel) {
    int kb = kbase0 + s * 32;
    char* dst = lds + bsel * 32768;
    #pragma unroll
    for (int j = 0; j < 4; j++) {
      int cid = tid + j*512;
      const char* src;
      if (j < 2) {
        int pl = cid >> 9;
        int kc = (cid >> 7) & 3, rr = cid & 127;
        src = (const char*)(As + ((size_t)(pl*kg + (kb>>3) + kc)*1024 + row0 + rr)*8);
      } else {
        int cid2 = cid - 1024;
        int kk = cid2 >> 5, c4 = cid2 & 31;
        int col = (c4*4) ^ (((kk >> 3) & 1) << 4);
        src = (const char*)(Bw + (size_t)(kb + kk)*outw + col0 + col);
      }
      gload_lds16(src, dst + (size_t)cid*16);
    }
  };

  f32x4 acc[4][2];
  #pragma unroll
  for (int i = 0; i < 4; i++)
    #pragma unroll
    for (int j = 0; j < 2; j++)
      #pragma unroll
      for (int q = 0; q < 4; q++) acc[i][j][q] = 0.f;

  STAGE(0, 0);
  for (int s = 0; s < nsteps; s++) {
    int cur = s & 1;
    if (s + 1 < nsteps) {
      STAGE(s + 1, cur ^ 1);
      asm volatile("s_waitcnt vmcnt(4)" ::: "memory");   // cur buf complete
    } else {
      asm volatile("s_waitcnt vmcnt(0)" ::: "memory");
    }
    __builtin_amdgcn_s_barrier();
    __builtin_amdgcn_sched_barrier(0);   // no LDS reads above the barrier

    const u16*   Alds = (const u16*)(lds + cur * 32768);
    const float* Blds = (const float*)(lds + cur * 32768 + 16384);

    half8 af[2][4];
    #pragma unroll
    for (int pl = 0; pl < 2; pl++)
      #pragma unroll
      for (int fr = 0; fr < 4; fr++) {
        int chunk = (pl*4 + lq)*128 + wr*64 + fr*16 + l15;
        af[pl][fr] = *reinterpret_cast<const half8*>(&Alds[(size_t)chunk*8]);
      }
    int cxor = (lq & 1) << 4;
    #pragma unroll
    for (int fc = 0; fc < 2; fc++) {
      int colx = (wc*32 + fc*16 + l15) ^ cxor;
      half8 b0, b1;
      #pragma unroll
      for (int j = 0; j < 8; j++) {
        float w = Blds[(lq*8 + j)*128 + colx] * 128.0f;
        _Float16 h0 = (_Float16)w;
        float rres = w - (float)h0;
        b0[j] = h0; b1[j] = (_Float16)rres;
      }
      #pragma unroll
      for (int fr = 0; fr < 4; fr++) {
        acc[fr][fc] = __builtin_amdgcn_mfma_f32_16x16x32_f16(af[0][fr], b0, acc[fr][fc], 0, 0, 0);
        acc[fr][fc] = __builtin_amdgcn_mfma_f32_16x16x32_f16(af[1][fr], b0, acc[fr][fc], 0, 0, 0);
        acc[fr][fc] = __builtin_amdgcn_mfma_f32_16x16x32_f16(af[0][fr], b1, acc[fr][fc], 0, 0, 0);
        acc[fr][fc] = __builtin_amdgcn_mfma_f32_16x16x32_f16(af[1][fr], b1, acc[fr][fc], 0, 0, 0);
      }
    }
    // all LDS reads of cur buf must complete before next STAGE overwrites it
    __builtin_amdgcn_sched_barrier(0);
    asm volatile("s_waitcnt lgkmcnt(0)" ::: "memory");
    __builtin_amdgcn_s_barrier();
  }

  float* pp = part + (size_t)z * sstride;
  #pragma unroll
  for (int fr = 0; fr < 4; fr++)
    #pragma unroll
    for (int fc = 0; fc < 2; fc++) {
      int col = col0 + wc*32 + fc*16 + l15;
      #pragma unroll
      for (int rr = 0; rr < 4; rr++) {
        int row = row0 + wr*64 + fr*16 + lq*4 + rr;
        pp[(size_t)row*outw + col] = acc[fr][fc][rr];
      }
    }
}

// -------- reduce split-K -> tiled fp16 planes (coalesced reads) ------------
__global__ void k_reduce_split(const float* __restrict__ part,
                               const float* __restrict__ bias,
                               u16* __restrict__ ys) {
  int idx = blockIdx.x * 256 + threadIdx.x;   // 131072 = 1024 rows * 128 cg
  int row = idx >> 7, cg = idx & 127;
  float4 s0 = {0,0,0,0}, s1 = {0,0,0,0};
  #pragma unroll
  for (int s = 0; s < 8; s++) {
    const float4* p = (const float4*)(part + (size_t)s*1048576 + (size_t)row*1024 + cg*8);
    float4 a = p[0], b = p[1];
    s0.x += a.x; s0.y += a.y; s0.z += a.z; s0.w += a.w;
    s1.x += b.x; s1.y += b.y; s1.z += b.z; s1.w += b.w;
  }
  float v[8] = {s0.x, s0.y, s0.z, s0.w, s1.x, s1.y, s1.z, s1.w};
  short8 o0, o1;
  #pragma unroll
  for (int e = 0; e < 8; e++) {
    float x = v[e] * (1.0f/2048.0f) + bias[cg*8 + e];
    x = fmaxf(x, 0.f) * 16.0f;                // prescale for next layer
    u16 h0, h1;
    split2(x, h0, h1);
    o0[e] = (short)h0; o1[e] = (short)h1;
  }
  size_t base = ((size_t)cg * 1024 + row) * 8;   // kg = 128 for K=1024
  *reinterpret_cast<short8*>(ys + base)               = o0;
  *reinterpret_cast<short8*>(ys + (size_t)1048576 + base) = o1;
}

// -------- pack Wc|Wb -> Wcat [1024][512] fp32 (pad 455..511 = 0), bcat -----
__global__ void k_packW(const float* __restrict__ Wc, const float* __restrict__ Wb,
                        const float* __restrict__ bc, const float* __restrict__ bb,
                        float* __restrict__ Wcat, float* __restrict__ bcat) {
  int idx = blockIdx.x * 256 + threadIdx.x;   // 524288
  int k = idx >> 9, col = idx & 511;
  float v = 0.f;
  if (col < 91)       v = Wc[(size_t)k*91 + col];
  else if (col < 455) v = Wb[(size_t)k*364 + (col - 91)];
  Wcat[idx] = v;
  if (idx < 512) {
    float bv = 0.f;
    if (idx < 91)       bv = bc[idx];
    else if (idx < 455) bv = bb[idx - 91];
    bcat[idx] = bv;
  }
}

// -------- heads reduce: sum 8 slices, +bcat, scatter to logits/deltas ------
__global__ void k_reduce_heads(const float* __restrict__ part,
                               const float* __restrict__ bcat,
                               float* __restrict__ logits,
                               float* __restrict__ deltas) {
  int idx = blockIdx.x * 256 + threadIdx.x;   // 524288 = 1024 * 512
  int row = idx >> 9, col = idx & 511;
  float v = 0.f;
  #pragma unroll
  for (int s = 0; s < 8; s++) v += part[idx + (size_t)s*524288];
  v = v * (1.0f/2048.0f) + bcat[col];
  if (col < 91)       logits[(size_t)row*91 + col] = v;
  else if (col < 455) deltas[(size_t)row*364 + (col - 91)] = v;
}

// -------- softmax + box decode + candidate keys ----------------------------
__global__ void k_decode(const float* __restrict__ logits,
                         const float* __restrict__ deltas,
                         const float* __restrict__ props,
                         float* __restrict__ cboxes,
                         u64* __restrict__ keys) {
  int r = blockIdx.x;
  int j = threadIdx.x;   // 128
  __shared__ float red[128];
  float lg = (j < NCLS) ? logits[r*NCLS + j] : -3.4e38f;
  red[j] = lg;
  __syncthreads();
  for (int s = 64; s > 0; s >>= 1) {
    if (j < s) red[j] = fmaxf(red[j], red[j+s]);
    __syncthreads();
  }
  float mx = red[0];
  __syncthreads();
  float e = (j < NCLS) ? expf(lg - mx) : 0.f;
  red[j] = e;
  __syncthreads();
  for (int s = 64; s > 0; s >>= 1) {
    if (j < s) red[j] += red[j+s];
    __syncthreads();
  }
  float p = e / red[0];
  if (j >= 1 && j < NCLS) {
    float px1 = props[r*4+0], py1 = props[r*4+1];
    float px2 = props[r*4+2], py2 = props[r*4+3];
    float w = px2 - px1, h = py2 - py1;
    float cx = px1 + 0.5f*w, cy = py1 + 0.5f*h;
    float d0 = deltas[r*364 + j*4 + 0];
    float d1 = deltas[r*364 + j*4 + 1];
    float d2 = deltas[r*364 + j*4 + 2];
    float d3 = deltas[r*364 + j*4 + 3];
    float dx = d0 / 10.0f, dy = d1 / 10.0f;
    float dw = fminf(d2 / 5.0f, 4.135166556742356f);
    float dh = fminf(d3 / 5.0f, 4.135166556742356f);
    float pcx = dx*w + cx, pcy = dy*h + cy;
    float pw = expf(dw)*w, ph = expf(dh)*h;
    float bx1 = fminf(fmaxf(pcx - 0.5f*pw, 0.f), 1216.f);
    float by1 = fminf(fmaxf(pcy - 0.5f*ph, 0.f),  800.f);
    float bx2 = fminf(fmaxf(pcx + 0.5f*pw, 0.f), 1216.f);
    float by2 = fminf(fmaxf(pcy + 0.5f*ph, 0.f),  800.f);
    bool valid = (p > 0.05f) && ((bx2 - bx1) >= 0.01f) && ((by2 - by1) >= 0.01f);
    int b = r >> 8, n = r & 255;
    int cidx = n*90 + (j-1);
    size_t cb = (size_t)b*CAND + cidx;
    cboxes[cb*4+0] = bx1; cboxes[cb*4+1] = by1;
    cboxes[cb*4+2] = bx2; cboxes[cb*4+3] = by2;
    u64 key = 0ull;
    if (valid)
      key = (((u64)__float_as_uint(p)) << 32) | (u32)(~(u32)cidx);
    keys[cb] = key;
  }
}

// -------- per (batch,half): compact valid + bitonic sort desc, top1024 -----
#define SORTN 4096
__global__ __launch_bounds__(1024) void k_sort(const u64* __restrict__ keys,
                                               u64* __restrict__ sorted) {
  __shared__ u64 sk[SORTN];
  __shared__ int cnt;
  int t = threadIdx.x;
  int b = blockIdx.x >> 1, h = blockIdx.x & 1;
  if (t == 0) cnt = 0;
  __syncthreads();
  const u64* kb = keys + (size_t)b*CAND + (size_t)h*(CAND/2);
  for (int q = 0; q < 12; q++) {
    int idx = t + q*1024;
    if (idx < CAND/2) {
      u64 k = kb[idx];
      if (k) { int pos = atomicAdd(&cnt, 1); sk[pos] = k; }
    }
  }
  __syncthreads();
  int total = cnt;
  for (int s = t; s < SORTN; s += 1024)
    if (s >= total) sk[s] = 0ull;
  __syncthreads();
  for (int k = 2; k <= SORTN; k <<= 1) {
    for (int jj = k >> 1; jj > 0; jj >>= 1) {
      for (int i = t; i < SORTN; i += 1024) {
        int ixj = i ^ jj;
        if (ixj > i) {
          u64 a = sk[i], bb = sk[ixj];
          bool up = ((i & k) == 0);
          if (up ? (a < bb) : (a > bb)) { sk[i] = bb; sk[ixj] = a; }
        }
      }
      __syncthreads();
    }
  }
  sorted[((size_t)b*2 + h)*1024 + t] = sk[t];
}

// -------- per batch: merge halves, tiled greedy NMS, emit final 100 --------
__global__ __launch_bounds__(1024) void k_nms(const u64* __restrict__ sorted,
                                              const float* __restrict__ cboxes,
                                              float* __restrict__ out) {
  __shared__ u64 m[2048];
  __shared__ float sX1[1024], sY1[1024], sX2[1024], sY2[1024], sAR[1024];
  __shared__ int keepL[1024];
  __shared__ int wsum[16];
  int t = threadIdx.x;
  int b = blockIdx.x;
  m[t]        = sorted[((size_t)b*2 + 0)*1024 + t];
  m[2047 - t] = sorted[((size_t)b*2 + 1)*1024 + t];
  __syncthreads();
  for (int lg = 10; lg >= 0; lg--) {
    int jj = 1 << lg;
    int pos = ((t >> lg) << (lg+1)) + (t & (jj-1));
    u64 a = m[pos], bb = m[pos + jj];
    if (a < bb) { m[pos] = bb; m[pos + jj] = a; }
    __syncthreads();
  }
  u64 key = m[t];
  bool valid = key != 0ull;
  float score = __uint_as_float((u32)(key >> 32));
  u32 cidx = ~((u32)(key & 0xFFFFFFFFu));
  int label = valid ? (int)(cidx % 90u) + 1 : 0;
  float cb0 = 0.f, cb1 = 0.f, cb2 = 0.f, cb3 = 0.f;
  if (valid) {
    size_t cb = ((size_t)b*CAND + cidx) * 4;
    cb0 = cboxes[cb+0]; cb1 = cboxes[cb+1];
    cb2 = cboxes[cb+2]; cb3 = cboxes[cb+3];
  }
  float off = (float)label * 1218.0f;
  float ox1 = cb0 + off, oy1 = cb1 + off;
  float ox2 = cb2 + off, oy2 = cb3 + off;
  float area = (ox2 - ox1) * (oy2 - oy1);
  sX1[t] = ox1; sY1[t] = oy1; sX2[t] = ox2; sY2[t] = oy2; sAR[t] = area;
  keepL[t] = valid ? 1 : 0;
  __syncthreads();

  int wid = t >> 6, lane = t & 63;
  for (int tile = 0; tile < 16; tile++) {
    if (wid == 0) {
      int idx = tile*64 + lane;
      bool kp = keepL[idx] != 0;
      float bx1 = sX1[idx], by1 = sY1[idx], bx2 = sX2[idx], by2 = sY2[idx], ba = sAR[idx];
      u64 alive = __ballot(kp);
      #pragma unroll 1
      for (int i = 0; i < 63; i++) {
        if ((alive >> i) & 1ull) {
          int ii = tile*64 + i;
          float ltx = fmaxf(sX1[ii], bx1), lty = fmaxf(sY1[ii], by1);
          float rbx = fminf(sX2[ii], bx2), rby = fminf(sY2[ii], by2);
          float iw = fmaxf(rbx - ltx, 0.f), ih = fmaxf(rby - lty, 0.f);
          float inter = iw * ih;
          float iou = inter / (sAR[ii] + ba - inter + 1e-9f);
          if (lane > i && iou > 0.5f) kp = false;
        }
        alive = __ballot(kp);
      }
      keepL[idx] = kp ? 1 : 0;
    }
    __syncthreads();
    if (t >= (tile+1)*64) {
      bool kp = keepL[t] != 0;
      if (kp) {
        #pragma unroll 1
        for (int i = tile*64; i < tile*64 + 64; i++) {
          if (keepL[i]) {
            float ltx = fmaxf(sX1[i], ox1), lty = fmaxf(sY1[i], oy1);
            float rbx = fminf(sX2[i], ox2), rby = fminf(sY2[i], oy2);
            float iw = fmaxf(rbx - ltx, 0.f), ih = fmaxf(rby - lty, 0.f);
            float inter = iw * ih;
            float iou = inter / (sAR[i] + area - inter + 1e-9f);
            if (iou > 0.5f) { kp = false; }
          }
        }
        if (!kp) keepL[t] = 0;
      }
    }
    __syncthreads();
  }

  bool keep = keepL[t] != 0;
  u64 bal = __ballot(keep);
  int wpre = __popcll(bal & ((1ull << lane) - 1ull));
  if (lane == 0) wsum[wid] = __popcll(bal);
  __syncthreads();
  int offn = 0, KT = 0;
  for (int q = 0; q < 16; q++) {
    int v = wsum[q];
    if (q < wid) offn += v;
    KT += v;
  }
  int rank = offn + wpre;
  float* outB = out;
  float* outS = out + 1600;
  float* outL = out + 2000;
  if (keep && rank < 100) {
    size_t s = (size_t)b*100 + rank;
    outB[s*4+0] = cb0; outB[s*4+1] = cb1;
    outB[s*4+2] = cb2; outB[s*4+3] = cb3;
    outS[s] = score; outL[s] = (float)label;
  }
  if (t < 100 && t >= KT) {
    size_t s = (size_t)b*100 + t;
    outB[s*4+0] = 0.f; outB[s*4+1] = 0.f; outB[s*4+2] = 0.f; outB[s*4+3] = 0.f;
    outS[s] = 0.f; outL[s] = 0.f;
  }
}

extern "C" void kernel_launch(void* const* d_in, const int* in_sizes, int n_in,
                              void* d_out, int out_size, void* d_ws, size_t ws_size,
                              hipStream_t stream) {
  (void)in_sizes; (void)n_in; (void)out_size; (void)ws_size;
  const float* feat  = (const float*)d_in[0];
  const float* props = (const float*)d_in[1];
  const float* W6 = (const float*)d_in[2];
  const float* b6 = (const float*)d_in[3];
  const float* W7 = (const float*)d_in[4];
  const float* b7 = (const float*)d_in[5];
  const float* Wc = (const float*)d_in[6];
  const float* bc = (const float*)d_in[7];
  const float* Wb = (const float*)d_in[8];
  const float* bb = (const float*)d_in[9];
  float* out = (float*)d_out;
  char* ws = (char*)d_ws;

  // workspace (peak 113,639,424 B == proven budget):
  //   phase A: featT [0, 62.26MB) + Xs2 [62.26MB, 113.64MB)
  //   phase B (featT dead): part [0, 32MB) + everything else in [32MB, 50MB)
  float* featT  = (float*)(ws);                        // 62,259,200 B
  u16*   Xs2    = (u16*)  (ws + 62259200);             // 51,380,224 B (tiled)
  float* part   = (float*)(ws);                        // 33,554,432 B (8 slices)
  u16*   Y1s2   = (u16*)  (ws + 33554432);             //  4,194,304 B (tiled)
  u16*   Y2s2   = (u16*)  (ws + 37748736);             //  4,194,304 B (tiled)
  float* Wcat   = (float*)(ws + 41943040);             //  2,097,152 B
  float* bcat   = (float*)(ws + 44040192);             //      2,048 B
  float* logitsP= (float*)(ws + 44564480);             //    372,736 B
  float* deltasP= (float*)(ws + 45088768);             //  1,490,944 B
  float* cboxes = (float*)(ws + 46661632);             //  1,474,560 B
  u64*   keys   = (u64*)  (ws + 48234496);             //    737,280 B
  u64*   sorted = (u64*)  (ws + 49020928);             //     65,536 B

  dim3 gT(475, 8, 4);
  k_transpose<<<gT, 256, 0, stream>>>(feat, featT);
  k_roialign<<<1024, 256, 0, stream>>>(featT, props, Xs2);
  k_packW<<<2048, 256, 0, stream>>>(Wc, Wb, bc, bb, Wcat, bcat);

  // FC6: K=12544 (kg=1568), split-K=8, 49 steps/slice, 512 blocks (2/CU)
  k_gemm_f16<<<512, 512, 0, stream>>>(Xs2, W6, part, DIN/8, 49, 8, 1024, 1048576);
  k_reduce_split<<<512, 256, 0, stream>>>(part, b6, Y1s2);
  // FC7: K=1024 (kg=128), split-K=8, 4 steps/slice
  k_gemm_f16<<<512, 512, 0, stream>>>(Y1s2, W7, part, 128, 4, 8, 1024, 1048576);
  k_reduce_split<<<512, 256, 0, stream>>>(part, b7, Y2s2);
  // heads: M=1024, N=512(padded 455), K=1024, split-K=8, 256 blocks, nct=4
  k_gemm_f16<<<256, 512, 0, stream>>>(Y2s2, Wcat, part, 128, 4, 4, 512, 524288);
  k_reduce_heads<<<2048, 256, 0, stream>>>(part, bcat, logitsP, deltasP);

  k_decode<<<1024, 128, 0, stream>>>(logitsP, deltasP, props, cboxes, keys);
  k_sort<<<8, 1024, 0, stream>>>(keys, sorted);
  k_nms<<<4, 1024, 0, stream>>>(sorted, cboxes, out);
}

// Round 8
// 348.326 us; speedup vs baseline: 3.2266x; 1.0353x over previous
//
#include <hip/hip_runtime.h>
#include <hip/hip_bf16.h>
#include <stdint.h>

#define B_    4
#define N_    256
#define C_    256
#define FH_   100
#define FW_   152
#define P_HW  (FH_*FW_)      // 15200
#define NCLS  91
#define CAND  23040          // N_*90
#define DIN   12544
#define PRE   1024

typedef unsigned long long u64;
typedef unsigned int u32;
typedef unsigned short u16;
typedef __attribute__((ext_vector_type(8))) _Float16 half8;
typedef __attribute__((ext_vector_type(8))) short short8;
typedef __attribute__((ext_vector_type(4))) float f32x4;

__device__ inline u16 h2bits(_Float16 h) { return *reinterpret_cast<u16*>(&h); }

// split v (already prescaled) into fp16 h0 + h1, exact-residual style
__device__ inline void split2(float v, u16& b0, u16& b1) {
  _Float16 h0 = (_Float16)v;
  float r = v - (float)h0;
  _Float16 h1 = (_Float16)r;
  b0 = h2bits(h0); b1 = h2bits(h1);
}

__device__ inline void gload_lds16(const void* g, void* l) {
  __builtin_amdgcn_global_load_lds(
      (const __attribute__((address_space(1))) void*)g,
      (__attribute__((address_space(3))) void*)l, 16, 0, 0);
}

// ---------------- feature transpose (B,C,H,W) -> (B,H,W,C) ----------------
__global__ void k_transpose(const float* __restrict__ in, float* __restrict__ out) {
  __shared__ float t[32][33];
  int b  = blockIdx.z;
  int c0 = blockIdx.y * 32;
  int p0 = blockIdx.x * 32;
  int tx = threadIdx.x & 31, ty = threadIdx.x >> 5;
  const float* inb = in  + (size_t)b * C_ * P_HW;
  float*       ob  = out + (size_t)b * P_HW * C_;
  #pragma unroll
  for (int q = 0; q < 4; q++)
    t[ty + q*8][tx] = inb[(size_t)(c0 + ty + q*8) * P_HW + p0 + tx];
  __syncthreads();
  #pragma unroll
  for (int q = 0; q < 4; q++)
    ob[(size_t)(p0 + ty + q*8) * C_ + c0 + tx] = t[tx][ty + q*8];
}

// ------- roi align -> Xt [2 planes][DIN/8][1024 rows][8] fp16 of (X*16) ----
// Geometry precomputed into LDS; channels in 8 groups of 32; ~13KB LDS ->
// high blocks/CU of gather TLP.
__global__ __launch_bounds__(256, 8) void k_roialign(const float* __restrict__ featT,
                                                     const float* __restrict__ props,
                                                     u16* __restrict__ Xs) {
  __shared__ float sPW[196][8];     // {p00,p01,p10,p11,w00,w01,w10,w11}
  __shared__ float cellv[32][51];   // [ch-in-group][cell]
  int bid = blockIdx.x;
  int xcd = bid & 7;
  int b = xcd >> 1;
  int n = ((bid >> 3) << 1) | (xcd & 1);
  int r = (b << 8) | n;                 // bijective 0..1023, XCD-batch affine
  int tid = threadIdx.x;

  float x1 = props[r*4+0], y1 = props[r*4+1];
  float x2 = props[r*4+2], y2 = props[r*4+3];
  float x1s = x1 * 0.125f, y1s = y1 * 0.125f;
  float x2s = x2 * 0.125f, y2s = y2 * 0.125f;
  float rw = fmaxf(x2s - x1s, 1.0f);
  float rh = fmaxf(y2s - y1s, 1.0f);
  float rwd = rw / 7.0f, rhd = rh / 7.0f;

  if (tid < 196) {
    int cell = tid >> 2, s = tid & 3;
    int py = cell / 7, px = cell % 7;
    int sy = s >> 1, sx = s & 1;
    float gqy = (float)py + 0.25f + 0.5f * (float)sy;
    float gqx = (float)px + 0.25f + 0.5f * (float)sx;
    float gy = fminf(fmaxf(y1s + rhd * gqy, 0.0f), 99.0f);
    float gx = fminf(fmaxf(x1s + rwd * gqx, 0.0f), 151.0f);
    float y0f = floorf(gy), x0f = floorf(gx);
    float ly = gy - y0f, lx = gx - x0f;
    int y0i = (int)y0f;
    int y1i = (int)fminf(y0f + 1.0f, 99.0f);
    int x0i = (int)x0f;
    int x1i = (int)fminf(x0f + 1.0f, 151.0f);
    sPW[tid][0] = __int_as_float((y0i * FW_ + x0i) * 256);
    sPW[tid][1] = __int_as_float((y0i * FW_ + x1i) * 256);
    sPW[tid][2] = __int_as_float((y1i * FW_ + x0i) * 256);
    sPW[tid][3] = __int_as_float((y1i * FW_ + x1i) * 256);
    sPW[tid][4] = (1.f-ly)*(1.f-lx);
    sPW[tid][5] = (1.f-ly)*lx;
    sPW[tid][6] = ly*(1.f-lx);
    sPW[tid][7] = ly*lx;
  }
  __syncthreads();

  int c32 = tid & 31;
  int slot = tid >> 5;
  const size_t PLS = (size_t)(DIN/8) * 1024 * 8;

  for (int g = 0; g < 8; g++) {
    const float* fb = featT + (size_t)b * P_HW * C_ + g*32 + c32;
    for (int cell = slot; cell < 49; cell += 8) {
      float acc = 0.f;
      #pragma unroll
      for (int s = 0; s < 4; s++) {
        int cs = cell*4 + s;
        float4 pv = *(const float4*)&sPW[cs][0];
        float4 wv = *(const float4*)&sPW[cs][4];
        acc += wv.x * fb[__float_as_int(pv.x)]
             + wv.y * fb[__float_as_int(pv.y)]
             + wv.z * fb[__float_as_int(pv.z)]
             + wv.w * fb[__float_as_int(pv.w)];
      }
      cellv[c32][cell] = acc * 4.0f;   // 0.25 (avg) * 16 (prescale)
    }
    __syncthreads();
    if (tid < 196) {
      short8 v0, v1;
      #pragma unroll
      for (int e = 0; e < 8; e++) {
        int kl = tid*8 + e;
        int chl = kl / 49;
        int cell = kl - chl*49;
        float v = cellv[chl][cell];
        u16 h0, h1;
        split2(v, h0, h1);
        v0[e] = (short)h0; v1[e] = (short)h1;
      }
      size_t cg = (size_t)g*196 + tid;
      size_t base = (cg * 1024 + r) * 8;
      *reinterpret_cast<short8*>(Xs + base)       = v0;
      *reinterpret_cast<short8*>(Xs + PLS + base) = v1;
    }
    __syncthreads();
  }
}

// -------- MFMA GEMM, fp32 via fp16 2-plane 3-pass (a0b0+a1b0+a0b1) --------
// Dropped a1*b1 term: <=2^-22 relative, same order as the 2-plane
// representation error and fp32 accumulation noise.
// 128x128 tile, 8 waves, double-buffered LDS, counted vmcnt(4).
__global__ __launch_bounds__(512) void k_gemm_f16(
    const u16* __restrict__ As, const float* __restrict__ Bw,
    float* __restrict__ part, int kg, int nsteps, int nct, int outw,
    size_t sstride) {
  __shared__ __align__(16) char lds[65536];   // 2 x (A 16KB + B 16KB)
  int tid = threadIdx.x;
  int wid = tid >> 6, lane = tid & 63;
  int l15 = lane & 15, lq = lane >> 4;
  int bid = blockIdx.x;
  int z = bid & 7, xy = bid >> 3;              // one K-slice per XCD
  int col0 = (xy % nct) * 128, row0 = (xy / nct) * 128;
  int wr = wid >> 2, wc = wid & 3;             // 8 waves: 2 row x 4 col, 64x32
  int kbase0 = z * nsteps * 32;

  auto STAGE = [&](int s, int bsel) {
    int kb = kbase0 + s * 32;
    char* dst = lds + bsel * 32768;
    #pragma unroll
    for (int j = 0; j < 4; j++) {
      int cid = tid + j*512;
      const char* src;
      if (j < 2) {
        int pl = cid >> 9;
        int kc = (cid >> 7) & 3, rr = cid & 127;
        src = (const char*)(As + ((size_t)(pl*kg + (kb>>3) + kc)*1024 + row0 + rr)*8);
      } else {
        int cid2 = cid - 1024;
        int kk = cid2 >> 5, c4 = cid2 & 31;
        int col = (c4*4) ^ (((kk >> 3) & 1) << 4);
        src = (const char*)(Bw + (size_t)(kb + kk)*outw + col0 + col);
      }
      gload_lds16(src, dst + (size_t)cid*16);
    }
  };

  f32x4 acc[4][2];
  #pragma unroll
  for (int i = 0; i < 4; i++)
    #pragma unroll
    for (int j = 0; j < 2; j++)
      #pragma unroll
      for (int q = 0; q < 4; q++) acc[i][j][q] = 0.f;

  STAGE(0, 0);
  for (int s = 0; s < nsteps; s++) {
    int cur = s & 1;
    if (s + 1 < nsteps) {
      STAGE(s + 1, cur ^ 1);
      asm volatile("s_waitcnt vmcnt(4)" ::: "memory");   // cur buf complete
    } else {
      asm volatile("s_waitcnt vmcnt(0)" ::: "memory");
    }
    __builtin_amdgcn_s_barrier();
    __builtin_amdgcn_sched_barrier(0);   // no LDS reads above the barrier

    const u16*   Alds = (const u16*)(lds + cur * 32768);
    const float* Blds = (const float*)(lds + cur * 32768 + 16384);

    half8 af[2][4];
    #pragma unroll
    for (int pl = 0; pl < 2; pl++)
      #pragma unroll
      for (int fr = 0; fr < 4; fr++) {
        int chunk = (pl*4 + lq)*128 + wr*64 + fr*16 + l15;
        af[pl][fr] = *reinterpret_cast<const half8*>(&Alds[(size_t)chunk*8]);
      }
    int cxor = (lq & 1) << 4;
    #pragma unroll
    for (int fc = 0; fc < 2; fc++) {
      int colx = (wc*32 + fc*16 + l15) ^ cxor;
      half8 b0, b1;
      #pragma unroll
      for (int j = 0; j < 8; j++) {
        float w = Blds[(lq*8 + j)*128 + colx] * 128.0f;
        _Float16 h0 = (_Float16)w;
        float rres = w - (float)h0;
        b0[j] = h0; b1[j] = (_Float16)rres;
      }
      #pragma unroll
      for (int fr = 0; fr < 4; fr++) {
        acc[fr][fc] = __builtin_amdgcn_mfma_f32_16x16x32_f16(af[0][fr], b0, acc[fr][fc], 0, 0, 0);
        acc[fr][fc] = __builtin_amdgcn_mfma_f32_16x16x32_f16(af[1][fr], b0, acc[fr][fc], 0, 0, 0);
        acc[fr][fc] = __builtin_amdgcn_mfma_f32_16x16x32_f16(af[0][fr], b1, acc[fr][fc], 0, 0, 0);
      }
    }
    // all LDS reads of cur buf must complete before next STAGE overwrites it
    __builtin_amdgcn_sched_barrier(0);
    asm volatile("s_waitcnt lgkmcnt(0)" ::: "memory");
    __builtin_amdgcn_s_barrier();
  }

  float* pp = part + (size_t)z * sstride;
  #pragma unroll
  for (int fr = 0; fr < 4; fr++)
    #pragma unroll
    for (int fc = 0; fc < 2; fc++) {
      int col = col0 + wc*32 + fc*16 + l15;
      #pragma unroll
      for (int rr = 0; rr < 4; rr++) {
        int row = row0 + wr*64 + fr*16 + lq*4 + rr;
        pp[(size_t)row*outw + col] = acc[fr][fc][rr];
      }
    }
}

// -------- reduce split-K -> tiled fp16 planes (coalesced reads) ------------
__global__ void k_reduce_split(const float* __restrict__ part,
                               const float* __restrict__ bias,
                               u16* __restrict__ ys) {
  int idx = blockIdx.x * 256 + threadIdx.x;   // 131072 = 1024 rows * 128 cg
  int row = idx >> 7, cg = idx & 127;
  float4 s0 = {0,0,0,0}, s1 = {0,0,0,0};
  #pragma unroll
  for (int s = 0; s < 8; s++) {
    const float4* p = (const float4*)(part + (size_t)s*1048576 + (size_t)row*1024 + cg*8);
    float4 a = p[0], b = p[1];
    s0.x += a.x; s0.y += a.y; s0.z += a.z; s0.w += a.w;
    s1.x += b.x; s1.y += b.y; s1.z += b.z; s1.w += b.w;
  }
  float v[8] = {s0.x, s0.y, s0.z, s0.w, s1.x, s1.y, s1.z, s1.w};
  short8 o0, o1;
  #pragma unroll
  for (int e = 0; e < 8; e++) {
    float x = v[e] * (1.0f/2048.0f) + bias[cg*8 + e];
    x = fmaxf(x, 0.f) * 16.0f;                // prescale for next layer
    u16 h0, h1;
    split2(x, h0, h1);
    o0[e] = (short)h0; o1[e] = (short)h1;
  }
  size_t base = ((size_t)cg * 1024 + row) * 8;   // kg = 128 for K=1024
  *reinterpret_cast<short8*>(ys + base)               = o0;
  *reinterpret_cast<short8*>(ys + (size_t)1048576 + base) = o1;
}

// -------- pack Wc|Wb -> Wcat [1024][512] fp32 (pad 455..511 = 0), bcat -----
__global__ void k_packW(const float* __restrict__ Wc, const float* __restrict__ Wb,
                        const float* __restrict__ bc, const float* __restrict__ bb,
                        float* __restrict__ Wcat, float* __restrict__ bcat) {
  int idx = blockIdx.x * 256 + threadIdx.x;   // 524288
  int k = idx >> 9, col = idx & 511;
  float v = 0.f;
  if (col < 91)       v = Wc[(size_t)k*91 + col];
  else if (col < 455) v = Wb[(size_t)k*364 + (col - 91)];
  Wcat[idx] = v;
  if (idx < 512) {
    float bv = 0.f;
    if (idx < 91)       bv = bc[idx];
    else if (idx < 455) bv = bb[idx - 91];
    bcat[idx] = bv;
  }
}

// -------- heads reduce: sum 8 slices, +bcat, scatter to logits/deltas ------
__global__ void k_reduce_heads(const float* __restrict__ part,
                               const float* __restrict__ bcat,
                               float* __restrict__ logits,
                               float* __restrict__ deltas) {
  int idx = blockIdx.x * 256 + threadIdx.x;   // 524288 = 1024 * 512
  int row = idx >> 9, col = idx & 511;
  float v = 0.f;
  #pragma unroll
  for (int s = 0; s < 8; s++) v += part[idx + (size_t)s*524288];
  v = v * (1.0f/2048.0f) + bcat[col];
  if (col < 91)       logits[(size_t)row*91 + col] = v;
  else if (col < 455) deltas[(size_t)row*364 + (col - 91)] = v;
}

// -------- softmax + box decode + candidate keys ----------------------------
__global__ void k_decode(const float* __restrict__ logits,
                         const float* __restrict__ deltas,
                         const float* __restrict__ props,
                         float* __restrict__ cboxes,
                         u64* __restrict__ keys) {
  int r = blockIdx.x;
  int j = threadIdx.x;   // 128
  __shared__ float red[128];
  float lg = (j < NCLS) ? logits[r*NCLS + j] : -3.4e38f;
  red[j] = lg;
  __syncthreads();
  for (int s = 64; s > 0; s >>= 1) {
    if (j < s) red[j] = fmaxf(red[j], red[j+s]);
    __syncthreads();
  }
  float mx = red[0];
  __syncthreads();
  float e = (j < NCLS) ? expf(lg - mx) : 0.f;
  red[j] = e;
  __syncthreads();
  for (int s = 64; s > 0; s >>= 1) {
    if (j < s) red[j] += red[j+s];
    __syncthreads();
  }
  float p = e / red[0];
  if (j >= 1 && j < NCLS) {
    float px1 = props[r*4+0], py1 = props[r*4+1];
    float px2 = props[r*4+2], py2 = props[r*4+3];
    float w = px2 - px1, h = py2 - py1;
    float cx = px1 + 0.5f*w, cy = py1 + 0.5f*h;
    float d0 = deltas[r*364 + j*4 + 0];
    float d1 = deltas[r*364 + j*4 + 1];
    float d2 = deltas[r*364 + j*4 + 2];
    float d3 = deltas[r*364 + j*4 + 3];
    float dx = d0 / 10.0f, dy = d1 / 10.0f;
    float dw = fminf(d2 / 5.0f, 4.135166556742356f);
    float dh = fminf(d3 / 5.0f, 4.135166556742356f);
    float pcx = dx*w + cx, pcy = dy*h + cy;
    float pw = expf(dw)*w, ph = expf(dh)*h;
    float bx1 = fminf(fmaxf(pcx - 0.5f*pw, 0.f), 1216.f);
    float by1 = fminf(fmaxf(pcy - 0.5f*ph, 0.f),  800.f);
    float bx2 = fminf(fmaxf(pcx + 0.5f*pw, 0.f), 1216.f);
    float by2 = fminf(fmaxf(pcy + 0.5f*ph, 0.f),  800.f);
    bool valid = (p > 0.05f) && ((bx2 - bx1) >= 0.01f) && ((by2 - by1) >= 0.01f);
    int b = r >> 8, n = r & 255;
    int cidx = n*90 + (j-1);
    size_t cb = (size_t)b*CAND + cidx;
    cboxes[cb*4+0] = bx1; cboxes[cb*4+1] = by1;
    cboxes[cb*4+2] = bx2; cboxes[cb*4+3] = by2;
    u64 key = 0ull;
    if (valid)
      key = (((u64)__float_as_uint(p)) << 32) | (u32)(~(u32)cidx);
    keys[cb] = key;
  }
}

// -------- per (batch,half): compact valid + bitonic sort desc, top1024 -----
#define SORTN 4096
__global__ __launch_bounds__(1024) void k_sort(const u64* __restrict__ keys,
                                               u64* __restrict__ sorted) {
  __shared__ u64 sk[SORTN];
  __shared__ int cnt;
  int t = threadIdx.x;
  int b = blockIdx.x >> 1, h = blockIdx.x & 1;
  if (t == 0) cnt = 0;
  __syncthreads();
  const u64* kb = keys + (size_t)b*CAND + (size_t)h*(CAND/2);
  for (int q = 0; q < 12; q++) {
    int idx = t + q*1024;
    if (idx < CAND/2) {
      u64 k = kb[idx];
      if (k) { int pos = atomicAdd(&cnt, 1); sk[pos] = k; }
    }
  }
  __syncthreads();
  int total = cnt;
  for (int s = t; s < SORTN; s += 1024)
    if (s >= total) sk[s] = 0ull;
  __syncthreads();
  for (int k = 2; k <= SORTN; k <<= 1) {
    for (int jj = k >> 1; jj > 0; jj >>= 1) {
      for (int i = t; i < SORTN; i += 1024) {
        int ixj = i ^ jj;
        if (ixj > i) {
          u64 a = sk[i], bb = sk[ixj];
          bool up = ((i & k) == 0);
          if (up ? (a < bb) : (a > bb)) { sk[i] = bb; sk[ixj] = a; }
        }
      }
      __syncthreads();
    }
  }
  sorted[((size_t)b*2 + h)*1024 + t] = sk[t];
}

// -------- per batch: merge halves, tiled greedy NMS, emit final 100 --------
__global__ __launch_bounds__(1024) void k_nms(const u64* __restrict__ sorted,
                                              const float* __restrict__ cboxes,
                                              float* __restrict__ out) {
  __shared__ u64 m[2048];
  __shared__ float sX1[1024], sY1[1024], sX2[1024], sY2[1024], sAR[1024];
  __shared__ int keepL[1024];
  __shared__ int wsum[16];
  int t = threadIdx.x;
  int b = blockIdx.x;
  m[t]        = sorted[((size_t)b*2 + 0)*1024 + t];
  m[2047 - t] = sorted[((size_t)b*2 + 1)*1024 + t];
  __syncthreads();
  for (int lg = 10; lg >= 0; lg--) {
    int jj = 1 << lg;
    int pos = ((t >> lg) << (lg+1)) + (t & (jj-1));
    u64 a = m[pos], bb = m[pos + jj];
    if (a < bb) { m[pos] = bb; m[pos + jj] = a; }
    __syncthreads();
  }
  u64 key = m[t];
  bool valid = key != 0ull;
  float score = __uint_as_float((u32)(key >> 32));
  u32 cidx = ~((u32)(key & 0xFFFFFFFFu));
  int label = valid ? (int)(cidx % 90u) + 1 : 0;
  float cb0 = 0.f, cb1 = 0.f, cb2 = 0.f, cb3 = 0.f;
  if (valid) {
    size_t cb = ((size_t)b*CAND + cidx) * 4;
    cb0 = cboxes[cb+0]; cb1 = cboxes[cb+1];
    cb2 = cboxes[cb+2]; cb3 = cboxes[cb+3];
  }
  float off = (float)label * 1218.0f;
  float ox1 = cb0 + off, oy1 = cb1 + off;
  float ox2 = cb2 + off, oy2 = cb3 + off;
  float area = (ox2 - ox1) * (oy2 - oy1);
  sX1[t] = ox1; sY1[t] = oy1; sX2[t] = ox2; sY2[t] = oy2; sAR[t] = area;
  keepL[t] = valid ? 1 : 0;
  __syncthreads();

  int wid = t >> 6, lane = t & 63;
  for (int tile = 0; tile < 16; tile++) {
    if (wid == 0) {
      int idx = tile*64 + lane;
      bool kp = keepL[idx] != 0;
      float bx1 = sX1[idx], by1 = sY1[idx], bx2 = sX2[idx], by2 = sY2[idx], ba = sAR[idx];
      u64 alive = __ballot(kp);
      #pragma unroll 1
      for (int i = 0; i < 63; i++) {
        if ((alive >> i) & 1ull) {
          int ii = tile*64 + i;
          float ltx = fmaxf(sX1[ii], bx1), lty = fmaxf(sY1[ii], by1);
          float rbx = fminf(sX2[ii], bx2), rby = fminf(sY2[ii], by2);
          float iw = fmaxf(rbx - ltx, 0.f), ih = fmaxf(rby - lty, 0.f);
          float inter = iw * ih;
          float iou = inter / (sAR[ii] + ba - inter + 1e-9f);
          if (lane > i && iou > 0.5f) kp = false;
        }
        alive = __ballot(kp);
      }
      keepL[idx] = kp ? 1 : 0;
    }
    __syncthreads();
    if (t >= (tile+1)*64) {
      bool kp = keepL[t] != 0;
      if (kp) {
        #pragma unroll 1
        for (int i = tile*64; i < tile*64 + 64; i++) {
          if (keepL[i]) {
            float ltx = fmaxf(sX1[i], ox1), lty = fmaxf(sY1[i], oy1);
            float rbx = fminf(sX2[i], ox2), rby = fminf(sY2[i], oy2);
            float iw = fmaxf(rbx - ltx, 0.f), ih = fmaxf(rby - lty, 0.f);
            float inter = iw * ih;
            float iou = inter / (sAR[i] + area - inter + 1e-9f);
            if (iou > 0.5f) { kp = false; }
          }
        }
        if (!kp) keepL[t] = 0;
      }
    }
    __syncthreads();
  }

  bool keep = keepL[t] != 0;
  u64 bal = __ballot(keep);
  int wpre = __popcll(bal & ((1ull << lane) - 1ull));
  if (lane == 0) wsum[wid] = __popcll(bal);
  __syncthreads();
  int offn = 0, KT = 0;
  for (int q = 0; q < 16; q++) {
    int v = wsum[q];
    if (q < wid) offn += v;
    KT += v;
  }
  int rank = offn + wpre;
  float* outB = out;
  float* outS = out + 1600;
  float* outL = out + 2000;
  if (keep && rank < 100) {
    size_t s = (size_t)b*100 + rank;
    outB[s*4+0] = cb0; outB[s*4+1] = cb1;
    outB[s*4+2] = cb2; outB[s*4+3] = cb3;
    outS[s] = score; outL[s] = (float)label;
  }
  if (t < 100 && t >= KT) {
    size_t s = (size_t)b*100 + t;
    outB[s*4+0] = 0.f; outB[s*4+1] = 0.f; outB[s*4+2] = 0.f; outB[s*4+3] = 0.f;
    outS[s] = 0.f; outL[s] = 0.f;
  }
}

extern "C" void kernel_launch(void* const* d_in, const int* in_sizes, int n_in,
                              void* d_out, int out_size, void* d_ws, size_t ws_size,
                              hipStream_t stream) {
  (void)in_sizes; (void)n_in; (void)out_size; (void)ws_size;
  const float* feat  = (const float*)d_in[0];
  const float* props = (const float*)d_in[1];
  const float* W6 = (const float*)d_in[2];
  const float* b6 = (const float*)d_in[3];
  const float* W7 = (const float*)d_in[4];
  const float* b7 = (const float*)d_in[5];
  const float* Wc = (const float*)d_in[6];
  const float* bc = (const float*)d_in[7];
  const float* Wb = (const float*)d_in[8];
  const float* bb = (const float*)d_in[9];
  float* out = (float*)d_out;
  char* ws = (char*)d_ws;

  // workspace (peak 113,639,424 B == proven budget):
  //   phase A: featT [0, 62.26MB) + Xs2 [62.26MB, 113.64MB)
  //   phase B (featT dead): part [0, 32MB) + everything else in [32MB, 50MB)
  float* featT  = (float*)(ws);                        // 62,259,200 B
  u16*   Xs2    = (u16*)  (ws + 62259200);             // 51,380,224 B (tiled)
  float* part   = (float*)(ws);                        // 33,554,432 B (8 slices)
  u16*   Y1s2   = (u16*)  (ws + 33554432);             //  4,194,304 B (tiled)
  u16*   Y2s2   = (u16*)  (ws + 37748736);             //  4,194,304 B (tiled)
  float* Wcat   = (float*)(ws + 41943040);             //  2,097,152 B
  float* bcat   = (float*)(ws + 44040192);             //      2,048 B
  float* logitsP= (float*)(ws + 44564480);             //    372,736 B
  float* deltasP= (float*)(ws + 45088768);             //  1,490,944 B
  float* cboxes = (float*)(ws + 46661632);             //  1,474,560 B
  u64*   keys   = (u64*)  (ws + 48234496);             //    737,280 B
  u64*   sorted = (u64*)  (ws + 49020928);             //     65,536 B

  dim3 gT(475, 8, 4);
  k_transpose<<<gT, 256, 0, stream>>>(feat, featT);
  k_roialign<<<1024, 256, 0, stream>>>(featT, props, Xs2);
  k_packW<<<2048, 256, 0, stream>>>(Wc, Wb, bc, bb, Wcat, bcat);

  // FC6: K=12544 (kg=1568), split-K=8, 49 steps/slice, 512 blocks (2/CU)
  k_gemm_f16<<<512, 512, 0, stream>>>(Xs2, W6, part, DIN/8, 49, 8, 1024, 1048576);
  k_reduce_split<<<512, 256, 0, stream>>>(part, b6, Y1s2);
  // FC7: K=1024 (kg=128), split-K=8, 4 steps/slice
  k_gemm_f16<<<512, 512, 0, stream>>>(Y1s2, W7, part, 128, 4, 8, 1024, 1048576);
  k_reduce_split<<<512, 256, 0, stream>>>(part, b7, Y2s2);
  // heads: M=1024, N=512(padded 455), K=1024, split-K=8, 256 blocks, nct=4
  k_gemm_f16<<<256, 512, 0, stream>>>(Y2s2, Wcat, part, 128, 4, 4, 512, 524288);
  k_reduce_heads<<<2048, 256, 0, stream>>>(part, bcat, logitsP, deltasP);

  k_decode<<<1024, 128, 0, stream>>>(logitsP, deltasP, props, cboxes, keys);
  k_sort<<<8, 1024, 0, stream>>>(keys, sorted);
  k_nms<<<4, 1024, 0, stream>>>(sorted, cboxes, out);
}